// Round 10
// baseline (646.991 us; speedup 1.0000x reference)
//
#include <hip/hip_runtime.h>
#include <hip/hip_bf16.h>
#include <math.h>

#define GG 4096
#define PP 4096
#define HH 64
#define BB 4
#define E1N 81920
#define E2N 81920
#define FFD 512
#define BNEPS 1e-5f
#define LOG2E 1.44269504088896341f
#define QPRE (0.17677669529663687f * LOG2E)

typedef unsigned short ushort_t;
typedef unsigned int uint_t;
using sh8 = __attribute__((ext_vector_type(8))) short;
using sh4 = __attribute__((ext_vector_type(4))) short;
using f4  = __attribute__((ext_vector_type(4))) float;

#if __has_builtin(__builtin_amdgcn_mfma_f32_16x16x16bf16_1k)
#define MFMA16(a, b, c) __builtin_amdgcn_mfma_f32_16x16x16bf16_1k((a), (b), (c), 0, 0, 0)
#elif __has_builtin(__builtin_amdgcn_mfma_f32_16x16x16_bf16)
#define MFMA16(a, b, c) __builtin_amdgcn_mfma_f32_16x16x16_bf16((a), (b), (c), 0, 0, 0)
#else
static __device__ inline f4 mfma16_asm(sh4 a, sh4 b, f4 c) {
    f4 d;
    asm volatile("v_mfma_f32_16x16x16_bf16 %0, %1, %2, %3"
                 : "=v"(d) : "v"(a), "v"(b), "v"(c));
    return d;
}
#define MFMA16(a, b, c) mfma16_asm((a), (b), (c))
#endif

// ---------------- workspace layout (float offsets) ----------------
#define OF_STATS   0          // 6 slots x 256 (raw sum[128] + sumsq[128])
#define OF_DEGCO   2048
#define OF_DEGGO   6144
#define OF_PSLOT   10240
#define OF_ETOT    10752
#define OF_HDC     11008
#define OF_HE      11136
#define OF_AGGCO   12288      // 4096 x 64
#define OF_BASEIN  274432
#define OF_Y1      536576
#define OF_Y2      798720
#define OF_FLAT    1060864    // 16384 x 64
#define OF_RW1     2109440    // 16384 x 128
#define OF_RW2     4206592    // 16384 x 64
#define OF_OUT     5255168    // 16384 x 64   (attn split 3 partial)
#define OF_QKV     6303744    // (attn splits 0..2 partials; ends 9449472)
#define OF_H1      10498048   // 16384 x 64
// bf16 attention buffers (alias dead fp32 regions)
#define OF_QB      OF_AGGCO   // 8*4096*32 ushort = 524288 floats
#define OF_KB      (OF_AGGCO + 524288)
#define OF_VF      OF_FLAT    // 8*64*2048 ushort = 524288 floats (V frag-order)
// attention k-split partials
#define OF_OPA     OF_QKV
#define OF_OPB     OF_OUT
#define OF_LP      OF_RW1     // 4*8*4096 = 131072
#define OPS        1048576    // split stride in opA (8*4096*32)
// FFN bf16 buffers (dead FFO region 9449472..10498048)
#define OF_W1B     9449472    // 512*64 bf16 = 16384 floats
#define OF_W2B     9465856    // 64*512 bf16 = 16384 floats
#define OF_H1B     9482240    // 16384*64 bf16 = 524288 floats (A-frag order)
// fft bf16 (frag order): FLAT..RW2 region, dead post-attn
#define OF_FFT     OF_FLAT

__device__ inline ushort_t f2b(float f) {
    uint_t u = __builtin_bit_cast(uint_t, f);
    u += 0x7FFFu + ((u >> 16) & 1u);
    return (ushort_t)(u >> 16);
}

__device__ inline void gld16(const void* gptr, void* lptr) {
    __builtin_amdgcn_global_load_lds(
        (const __attribute__((address_space(1))) uint_t*)gptr,
        (__attribute__((address_space(3))) uint_t*)lptr, 16, 0, 0);
}

// ================= device sub-kernels for fat launches =================
__device__ void dev_vae_he(int bid, const float* __restrict__ x, const float* __restrict__ W,
                           const float* __restrict__ bias, float* he, float* sh) {
    int b = bid >> 5, i = bid & 31;
    float s = 0.f;
    for (int g = threadIdx.x; g < 4096; g += 256) s += x[b * 4096 + g] * W[i * 4096 + g];
    sh[threadIdx.x] = s;
    __syncthreads();
    for (int o = 128; o > 0; o >>= 1) {
        if (threadIdx.x < o) sh[threadIdx.x] += sh[threadIdx.x + o];
        __syncthreads();
    }
    if (threadIdx.x == 0) he[b * 32 + i] = fmaxf(sh[0] + bias[i], 0.f);
}

__device__ void dev_vae_mid(const float* __restrict__ he,
                            const float* __restrict__ muw, const float* __restrict__ mub,
                            const float* __restrict__ lvw, const float* __restrict__ lvb,
                            const float* __restrict__ d1w, const float* __restrict__ d1b,
                            const float* __restrict__ eps, float* hdc, float* klout, float* zs) {
    int t = threadIdx.x;
    if (t < 64) {
        int b = t >> 4, l = t & 15;
        float mu = mub[l], lv = lvb[l];
        for (int i = 0; i < 32; i++) {
            float hv = he[b * 32 + i];
            mu += hv * muw[l * 32 + i];
            lv += hv * lvw[l * 32 + i];
        }
        zs[t] = mu + eps[t] * expf(0.5f * lv);
        float kterm = 1.f + lv - mu * mu - expf(lv);
        for (int o = 32; o > 0; o >>= 1) kterm += __shfl_xor(kterm, o, 64);
        if (t == 0) klout[0] = -0.5f * kterm * 0.25f;
    }
    __syncthreads();
    if (t < 128) {
        int b = t >> 5, i = t & 31;
        float a = d1b[i];
        for (int l = 0; l < 16; l++) a += zs[b * 16 + l] * d1w[i * 16 + l];
        hdc[t] = fmaxf(a, 0.f);
    }
}

__device__ void dev_edge_deg(int bid, const int* __restrict__ ei, const float* __restrict__ w,
                             float* deg, int E) {
    int e = bid * 256 + threadIdx.x;
    if (e < E) atomicAdd(&deg[ei[E + e]], w[e]);
}

__device__ void dev_cs_part(int bid, const float* __restrict__ X, int N,
                            float* sum, float* sumsq, float* sh) {
    int t = threadIdx.x;
    int col = t & 63, ro = t >> 6;
    int rows = N >> 8;
    int r0 = bid * rows;
    float s = 0.f, q = 0.f;
    for (int r = r0 + ro; r < r0 + rows; r += 4) {
        float v = X[r * 64 + col];
        s += v; q += v * v;
    }
    float* ls = sh; float* lq = sh + 256;
    ls[t] = s; lq[t] = q;
    __syncthreads();
    if (t < 64) {
        for (int j = t + 64; j < 256; j += 64) { s += ls[j]; q += lq[j]; }
        atomicAdd(&sum[t], s);
        atomicAdd(&sumsq[t], q);
    }
}

// coalesced per-edge-wave aggregation: wave handles one edge, 64 lanes = 64 h
__device__ void dev_edge_agg(int bid, const int* __restrict__ ei, const float* __restrict__ w,
                             const float* __restrict__ deg, const float* __restrict__ x,
                             float* agg) {
    int gid = bid * 256 + threadIdx.x;
    int e = gid >> 6, h = gid & 63;
    if (e < E1N) {
        int src = ei[e], dst = ei[E1N + e];
        float norm = rsqrtf(deg[dst]) * w[e] * rsqrtf(deg[src]);
        atomicAdd(&agg[dst * HH + h], norm * x[src * HH + h]);
    }
}

// one block per pert slot: scan dst array, accumulate matching rows into LDS
__device__ void dev_pert_scan(int s, const int* __restrict__ pidx, const int* __restrict__ ei,
                              const float* __restrict__ w, const float* __restrict__ deg,
                              const float* __restrict__ tbl, float* pslot, float* acc) {
    int t = threadIdx.x;
    int n = pidx[s];
    if (t < 64) acc[t] = 0.f;
    __syncthreads();
    float dd = rsqrtf(deg[n]);
    for (int e = t; e < E2N; e += 256) {
        if (ei[E2N + e] == n) {
            int src = ei[e];
            float norm = dd * w[e] * rsqrtf(deg[src]);
            for (int h = 0; h < 64; h++)
                atomicAdd(&acc[h], norm * tbl[src * 64 + h]);
        }
    }
    __syncthreads();
    if (t < 64) pslot[s * 64 + t] = acc[t];
}

// base_in = relu(bn(gene_emb)) + 0.2*((agg + emb_pos/deg) @ Wco^T + bco)
__device__ void dev_base_combine(int bid, const float* __restrict__ gene_emb,
                                 const float* __restrict__ agg, const float* __restrict__ emb_pos,
                                 const float* __restrict__ deg,
                                 const float* __restrict__ W, const float* __restrict__ bias,
                                 const float* __restrict__ bsum, const float* __restrict__ bsq,
                                 const float* __restrict__ bg, const float* __restrict__ bb,
                                 float* out, float* sh) {
    float* Wt = sh;            // [64][65]
    float* a = sh + 4160;      // [4][64]
    int t = threadIdx.x;
    for (int i = t; i < 4096; i += 256) Wt[(i & 63) * 65 + (i >> 6)] = W[i];
    int rr = t >> 6, h = t & 63;
    int g = bid * 4 + rr;
    a[rr * 64 + h] = agg[g * 64 + h] + emb_pos[g * 64 + h] / deg[g];
    __syncthreads();
    float y = bias[h];
    const float* ar = a + rr * 64;
    #pragma unroll 8
    for (int k = 0; k < 64; k++) y += ar[k] * Wt[k * 65 + h];
    const float invN = 1.0f / (float)GG;
    float m = bsum[h] * invN;
    float is_ = rsqrtf(bsq[h] * invN - m * m + BNEPS);
    float v = gene_emb[g * 64 + h];
    v = (v - m) * is_ * bg[h] + bb[h];
    v = fmaxf(v, 0.f);
    out[g * 64 + h] = v + 0.2f * y;
}

__device__ void dev_pert_mlp(const float* __restrict__ pslot, const int* __restrict__ pidx,
                             const float* __restrict__ deg, const float* __restrict__ tbl,
                             const float* __restrict__ gw, const float* __restrict__ gb,
                             const float* __restrict__ w1, const float* __restrict__ b1,
                             const float* __restrict__ g1, const float* __restrict__ be1,
                             const float* __restrict__ w2, const float* __restrict__ b2,
                             const float* __restrict__ g2, const float* __restrict__ be2,
                             float* etot, float* sh) {
    float* pge = sh;
    float* psum = sh + 512;
    float* y = sh + 768;
    float* mh = sh + 1024;
    float* ih = sh + 1088;
    int t = threadIdx.x;
    for (int j = t; j < 512; j += 256) {
        int s = j >> 6, h = j & 63;
        int n = pidx[s];
        float invd = 1.0f / deg[n];
        float acc = gb[h];
        for (int k = 0; k < 64; k++)
            acc += (pslot[s * 64 + k] + tbl[n * 64 + k] * invd) * gw[h * 64 + k];
        pge[j] = acc;
    }
    __syncthreads();
    { int b = t >> 6, h = t & 63; psum[t] = pge[2 * b * 64 + h] + pge[(2 * b + 1) * 64 + h]; }
    __syncthreads();
    { int h = t & 63; int b = t >> 6;
      float acc = b1[h];
      for (int k = 0; k < 64; k++) acc += psum[b * 64 + k] * w1[h * 64 + k];
      y[t] = acc; }
    __syncthreads();
    if (t < 64) {
        float s = 0.f, sq = 0.f;
        for (int b = 0; b < 4; b++) { float v = y[b * 64 + t]; s += v; sq += v * v; }
        float m = s * 0.25f;
        mh[t] = m; ih[t] = rsqrtf(sq * 0.25f - m * m + BNEPS);
    }
    __syncthreads();
    { int h = t & 63;
      float v = (y[t] - mh[h]) * ih[h] * g1[h] + be1[h];
      psum[t] = fmaxf(v, 0.f); }
    __syncthreads();
    { int h = t & 63; int b = t >> 6;
      float acc = b2[h];
      for (int k = 0; k < 64; k++) acc += psum[b * 64 + k] * w2[h * 64 + k];
      y[t] = acc; }
    __syncthreads();
    if (t < 64) {
        float s = 0.f, sq = 0.f;
        for (int b = 0; b < 4; b++) { float v = y[b * 64 + t]; s += v; sq += v * v; }
        float m = s * 0.25f;
        mh[t] = m; ih[t] = rsqrtf(sq * 0.25f - m * m + BNEPS);
    }
    __syncthreads();
    { int h = t & 63;
      etot[t] = (y[t] - mh[h]) * ih[h] * g2[h] + be2[h]; }
}

// ================= fat kernels =================
// K1: zero aggco(256,f4) | zero stats+pslot(3,f4) | deg=1(8,f4) | vae_he(128) | W->bf16(256)
__global__ void k_fat1(float* ws, const float* __restrict__ x,
                       const float* __restrict__ ve1_w, const float* __restrict__ ve1_b,
                       const float* __restrict__ ff1_w, const float* __restrict__ ff2_w) {
    __shared__ float sh[256];
    const float4 z4 = {0.f, 0.f, 0.f, 0.f};
    const float4 o4 = {1.f, 1.f, 1.f, 1.f};
    int bid = blockIdx.x;
    if (bid < 256) {
        int i = bid * 256 + threadIdx.x;
        *(float4*)&ws[OF_AGGCO + i * 4] = z4;
    } else if (bid < 259) {
        int i = (bid - 256) * 256 + threadIdx.x;
        if (i < 512) *(float4*)&ws[OF_STATS + i * 4] = z4;
        else if (i < 640) *(float4*)&ws[OF_PSLOT + (i - 512) * 4] = z4;
    } else if (bid < 267) {
        int i = (bid - 259) * 256 + threadIdx.x;
        *(float4*)&ws[OF_DEGCO + i * 4] = o4;      // degco+deggo contiguous 8192
    } else if (bid < 395) {
        dev_vae_he(bid - 267, x, ve1_w, ve1_b, ws + OF_HE, sh);
    } else {
        int i = (bid - 395) * 256 + threadIdx.x;   // 256 blocks -> 65536
        ushort_t* W1b = (ushort_t*)(ws + OF_W1B);
        ushort_t* W2b = (ushort_t*)(ws + OF_W2B);
        if (i < 32768) W1b[i] = f2b(ff1_w[i]);
        else W2b[i - 32768] = f2b(ff2_w[i - 32768]);
    }
}

// K2: edge_deg co(320) | edge_deg go(320) | cs_part gene_emb(256) | vae_mid(1)
__global__ void k_fat2(float* ws, const int* __restrict__ ei_co, const float* __restrict__ w_co,
                       const int* __restrict__ ei_go, const float* __restrict__ w_go,
                       const float* __restrict__ gene_emb,
                       const float* __restrict__ vmu_w, const float* __restrict__ vmu_b,
                       const float* __restrict__ vlv_w, const float* __restrict__ vlv_b,
                       const float* __restrict__ vd1_w, const float* __restrict__ vd1_b,
                       const float* __restrict__ veps, float* klout) {
    __shared__ float sh[512];
    int bid = blockIdx.x;
    if (bid < 320) dev_edge_deg(bid, ei_co, w_co, ws + OF_DEGCO, E1N);
    else if (bid < 640) dev_edge_deg(bid - 320, ei_go, w_go, ws + OF_DEGGO, E2N);
    else if (bid < 896) dev_cs_part(bid - 640, gene_emb, GG, ws + OF_STATS, ws + OF_STATS + 128, sh);
    else dev_vae_mid(ws + OF_HE, vmu_w, vmu_b, vlv_w, vlv_b, vd1_w, vd1_b, veps,
                     ws + OF_HDC, klout, sh);
}

// K3: edge_agg(20480) | pert slot-scan(8)
__global__ void k_fat3(float* ws, const int* __restrict__ ei_co, const float* __restrict__ w_co,
                       const float* __restrict__ emb_pos, const int* __restrict__ pidx,
                       const int* __restrict__ ei_go, const float* __restrict__ w_go,
                       const float* __restrict__ pert_tbl) {
    __shared__ float acc[64];
    int bid = blockIdx.x;
    if (bid < 20480) dev_edge_agg(bid, ei_co, w_co, ws + OF_DEGCO, emb_pos, ws + OF_AGGCO);
    else dev_pert_scan(bid - 20480, pidx, ei_go, w_go, ws + OF_DEGGO, pert_tbl,
                       ws + OF_PSLOT, acc);
}

// K4: base_combine(1024) | pert_mlp(1)
__global__ void k_fat4(float* ws, const float* __restrict__ gene_emb,
                       const float* __restrict__ emb_pos,
                       const float* __restrict__ sg_co_w, const float* __restrict__ sg_co_b,
                       const float* __restrict__ bn_emb_g, const float* __restrict__ bn_emb_b,
                       const int* __restrict__ pidx, const float* __restrict__ pert_tbl,
                       const float* __restrict__ gw, const float* __restrict__ gb,
                       const float* __restrict__ w1, const float* __restrict__ b1,
                       const float* __restrict__ g1, const float* __restrict__ be1,
                       const float* __restrict__ w2, const float* __restrict__ b2,
                       const float* __restrict__ g2, const float* __restrict__ be2) {
    __shared__ float sh[4416];
    int bid = blockIdx.x;
    if (bid < 1024)
        dev_base_combine(bid, gene_emb, ws + OF_AGGCO, emb_pos, ws + OF_DEGCO,
                         sg_co_w, sg_co_b, ws + OF_STATS, ws + OF_STATS + 128,
                         bn_emb_g, bn_emb_b, ws + OF_BASEIN, sh);
    else
        dev_pert_mlp(ws + OF_PSLOT, pidx, ws + OF_DEGGO, pert_tbl, gw, gb,
                     w1, b1, g1, be1, w2, b2, g2, be2, ws + OF_ETOT, sh);
}

// ================= gemm64 (fp32, for etv/rw chain) =================
__launch_bounds__(256)
__global__ void k_gemm64(const float* __restrict__ X, const float* __restrict__ W,
                         const float* __restrict__ bias, float* __restrict__ Y,
                         int Cin, int Cout,
                         const float* __restrict__ bnsum, const float* __restrict__ bnsq,
                         const float* __restrict__ bng, const float* __restrict__ bnb,
                         float invN, int relu_in,
                         float* __restrict__ outsum, float* __restrict__ outsq) {
    __shared__ float Xs[64][66];
    __shared__ float Ws[64][66];
    __shared__ float bsc[64], bsh[64];
    const int t = threadIdx.x;
    const int row0 = blockIdx.x * 64, cb = blockIdx.y * 64;
    const int tx = t & 15, ty = t >> 4;
    const int c0 = tx * 4, r0 = ty * 4;
    float acc[4][4];
    #pragma unroll
    for (int j = 0; j < 4; j++)
        #pragma unroll
        for (int i = 0; i < 4; i++) acc[j][i] = 0.f;

    for (int k0 = 0; k0 < Cin; k0 += 64) {
        __syncthreads();
        if (t < 64) {
            float sc = 1.f, sh = 0.f;
            if (bnsum) {
                int c = k0 + t;
                float m = bnsum[c] * invN;
                float is_ = rsqrtf(bnsq[c] * invN - m * m + BNEPS);
                sc = is_ * bng[c]; sh = bnb[c] - m * sc;
            }
            bsc[t] = sc; bsh[t] = sh;
        }
        __syncthreads();
        for (int i = t; i < 1024; i += 256) {
            int r = i >> 4, kq = (i & 15) * 4;
            float4 v = *(const float4*)&X[(size_t)(row0 + r) * Cin + k0 + kq];
            float e0 = v.x * bsc[kq] + bsh[kq];
            float e1 = v.y * bsc[kq + 1] + bsh[kq + 1];
            float e2 = v.z * bsc[kq + 2] + bsh[kq + 2];
            float e3 = v.w * bsc[kq + 3] + bsh[kq + 3];
            if (relu_in) {
                e0 = fmaxf(e0, 0.f); e1 = fmaxf(e1, 0.f);
                e2 = fmaxf(e2, 0.f); e3 = fmaxf(e3, 0.f);
            }
            Xs[r][kq] = e0; Xs[r][kq + 1] = e1; Xs[r][kq + 2] = e2; Xs[r][kq + 3] = e3;
            float4 wv = *(const float4*)&W[(size_t)(cb + r) * Cin + k0 + kq];
            Ws[r][kq] = wv.x; Ws[r][kq + 1] = wv.y; Ws[r][kq + 2] = wv.z; Ws[r][kq + 3] = wv.w;
        }
        __syncthreads();
        #pragma unroll 4
        for (int k = 0; k < 64; k += 2) {
            float2 a[4], b[4];
            #pragma unroll
            for (int j = 0; j < 4; j++) a[j] = *(const float2*)&Xs[r0 + j][k];
            #pragma unroll
            for (int i = 0; i < 4; i++) b[i] = *(const float2*)&Ws[c0 + i][k];
            #pragma unroll
            for (int j = 0; j < 4; j++)
                #pragma unroll
                for (int i = 0; i < 4; i++)
                    acc[j][i] += a[j].x * b[i].x + a[j].y * b[i].y;
        }
    }
    float4 bi = *(const float4*)&bias[cb + c0];
    float scol[4] = {0.f, 0.f, 0.f, 0.f}, qcol[4] = {0.f, 0.f, 0.f, 0.f};
    #pragma unroll
    for (int j = 0; j < 4; j++) {
        float4 o;
        o.x = acc[j][0] + bi.x; o.y = acc[j][1] + bi.y;
        o.z = acc[j][2] + bi.z; o.w = acc[j][3] + bi.w;
        *(float4*)&Y[(size_t)(row0 + r0 + j) * Cout + cb + c0] = o;
        scol[0] += o.x; scol[1] += o.y; scol[2] += o.z; scol[3] += o.w;
        qcol[0] += o.x * o.x; qcol[1] += o.y * o.y;
        qcol[2] += o.z * o.z; qcol[3] += o.w * o.w;
    }
    if (outsum) {
        __syncthreads();
        #pragma unroll
        for (int i = 0; i < 4; i++) { Xs[ty][c0 + i] = scol[i]; Ws[ty][c0 + i] = qcol[i]; }
        __syncthreads();
        if (t < 64) {
            float ss = 0.f, qq = 0.f;
            #pragma unroll
            for (int r = 0; r < 16; r++) { ss += Xs[r][t]; qq += Ws[r][t]; }
            atomicAdd(&outsum[cb + t], ss);
            atomicAdd(&outsq[cb + t], qq);
        }
    }
}

// ================= fused QKV gemm: BN(yrw2) @ ain_w^T + b -> bf16 Qb/Kb/Vf =================
__launch_bounds__(256)
__global__ void k_gemm_qkv(const float* __restrict__ X, const float* __restrict__ W,
                           const float* __restrict__ bias,
                           const float* __restrict__ bnsum, const float* __restrict__ bnsq,
                           const float* __restrict__ bng, const float* __restrict__ bnb,
                           ushort_t* __restrict__ Qb, ushort_t* __restrict__ Kb,
                           ushort_t* __restrict__ Vf) {
    __shared__ float Xs[64][66];
    __shared__ float Ws[64][66];
    __shared__ float bsc[64], bsh[64];
    const int t = threadIdx.x;
    const int row0 = blockIdx.x * 64, yb = blockIdx.y, cb = yb * 64;
    const int tx = t & 15, ty = t >> 4;
    const int c0 = tx * 4, r0 = ty * 4;
    const float invN = 1.0f / (float)(BB * GG);
    if (t < 64) {
        float m = bnsum[t] * invN;
        float is_ = rsqrtf(bnsq[t] * invN - m * m + BNEPS);
        float sc = is_ * bng[t];
        bsc[t] = sc; bsh[t] = bnb[t] - m * sc;
    }
    __syncthreads();
    for (int i = t; i < 1024; i += 256) {
        int r = i >> 4, kq = (i & 15) * 4;
        float4 v = *(const float4*)&X[(size_t)(row0 + r) * 64 + kq];
        Xs[r][kq] = v.x * bsc[kq] + bsh[kq];
        Xs[r][kq + 1] = v.y * bsc[kq + 1] + bsh[kq + 1];
        Xs[r][kq + 2] = v.z * bsc[kq + 2] + bsh[kq + 2];
        Xs[r][kq + 3] = v.w * bsc[kq + 3] + bsh[kq + 3];
        float4 wv = *(const float4*)&W[(size_t)(cb + r) * 64 + kq];
        Ws[r][kq] = wv.x; Ws[r][kq + 1] = wv.y; Ws[r][kq + 2] = wv.z; Ws[r][kq + 3] = wv.w;
    }
    __syncthreads();
    float acc[4][4];
    #pragma unroll
    for (int j = 0; j < 4; j++)
        #pragma unroll
        for (int i = 0; i < 4; i++) acc[j][i] = 0.f;
    #pragma unroll 4
    for (int k = 0; k < 64; k += 2) {
        float2 a[4], b[4];
        #pragma unroll
        for (int j = 0; j < 4; j++) a[j] = *(const float2*)&Xs[r0 + j][k];
        #pragma unroll
        for (int i = 0; i < 4; i++) b[i] = *(const float2*)&Ws[c0 + i][k];
        #pragma unroll
        for (int j = 0; j < 4; j++)
            #pragma unroll
            for (int i = 0; i < 4; i++)
                acc[j][i] += a[j].x * b[i].x + a[j].y * b[i].y;
    }
    float4 bi = *(const float4*)&bias[cb + c0];
    const int b2 = row0 >> 12, tile = (row0 & 4095) >> 6;
    if (yb < 2) {
        ushort_t* Dst = (yb == 0) ? Qb : Kb;
        const float sc2 = (yb == 0) ? QPRE : 1.0f;
        const int h = c0 >> 5, d = c0 & 31;
        #pragma unroll
        for (int j = 0; j < 4; j++) {
            union { ushort_t u[4]; uint2 v; } pk;
            pk.u[0] = f2b((acc[j][0] + bi.x) * sc2);
            pk.u[1] = f2b((acc[j][1] + bi.y) * sc2);
            pk.u[2] = f2b((acc[j][2] + bi.z) * sc2);
            pk.u[3] = f2b((acc[j][3] + bi.w) * sc2);
            int g = (row0 & 4095) + r0 + j;
            *(uint2*)&Dst[((size_t)(b2 * 2 + h) * GG + g) * 32 + d] = pk.v;
        }
    } else {
        __syncthreads();
        #pragma unroll
        for (int j = 0; j < 4; j++) {
            Xs[r0 + j][c0] = acc[j][0] + bi.x;
            Xs[r0 + j][c0 + 1] = acc[j][1] + bi.y;
            Xs[r0 + j][c0 + 2] = acc[j][2] + bi.z;
            Xs[r0 + j][c0 + 3] = acc[j][3] + bi.w;
        }
        __syncthreads();
        #pragma unroll
        for (int h = 0; h < 2; h++) {
            union { ushort_t u[8]; uint4 v; } pk;
            #pragma unroll
            for (int j = 0; j < 8; j++) {
                int idx = t * 8 + j;
                int g2 = idx >> 8, L = (idx >> 2) & 63, i = idx & 3;
                int key = (g2 >> 1) * 16 + ((L >> 4) << 2) + i;
                int d = ((g2 & 1) << 4) + (L & 15);
                pk.u[j] = f2b(Xs[key][h * 32 + d]);
            }
            *(uint4*)&Vf[((size_t)((b2 * 2 + h) * 64 + tile)) * 2048 + t * 8] = pk.v;
        }
    }
}

// flat_pre = bn(y2) + etot, fused column stats
__global__ void k_flatpre(const float* __restrict__ y2, const float* __restrict__ etot,
                          const float* __restrict__ bsum, const float* __restrict__ bsq,
                          const float* __restrict__ g2, const float* __restrict__ b2,
                          float* __restrict__ out,
                          float* __restrict__ osum, float* __restrict__ osq) {
    int t = threadIdx.x;
    int h = t & 63, ro = t >> 6;
    int row0 = blockIdx.x * 64;
    const float invN = 1.0f / (float)GG;
    float m = bsum[h] * invN;
    float is_ = rsqrtf(bsq[h] * invN - m * m + BNEPS);
    float sc = is_ * g2[h];
    float sh = b2[h] - m * sc;
    float s = 0.f, q = 0.f;
    for (int r = row0 + ro; r < row0 + 64; r += 4) {
        int b = r >> 12, gh = (r & 4095) * 64 + h;
        float v = y2[gh] * sc + sh + etot[b * 64 + h];
        out[r * 64 + h] = v;
        s += v; q += v * v;
    }
    __shared__ float ls[256], lq[256];
    ls[t] = s; lq[t] = q;
    __syncthreads();
    if (t < 64) {
        s = ls[t] + ls[t + 64] + ls[t + 128] + ls[t + 192];
        q = lq[t] + lq[t + 64] + lq[t + 128] + lq[t + 192];
        atomicAdd(&osum[t], s);
        atomicAdd(&osq[t], q);
    }
}

// ---- MFMA flash attention, 4-bh per block (mask register reuse, 2 blocks/CU) ----
__launch_bounds__(512, 4)
__global__ void k_attn_mfma(const ushort_t* __restrict__ Qb, const ushort_t* __restrict__ Kb,
                            const ushort_t* __restrict__ Vf, const float* __restrict__ mask,
                            float* __restrict__ opA, float* __restrict__ opB,
                            float* __restrict__ Lp) {
    __shared__ ushort_t Kl[2][4][2048];
    __shared__ ushort_t Vl[2][4][2048];
    const int split = blockIdx.y;
    const int bh0 = blockIdx.z * 4;
    const int q0 = blockIdx.x * 64;
    const int kstart = split * (GG / 4), kend = kstart + (GG / 4);
    const int t = threadIdx.x;
    const int lane = t & 63, w = t >> 6;
    const int qg = w >> 1, kh = w & 1;
    const int l15 = lane & 15, quad = lane >> 4;
    const int i2a = kh * 2, i2b = kh * 2 + 1;

    sh8 qf[4];
    #pragma unroll
    for (int bh = 0; bh < 4; bh++)
        qf[bh] = *(const sh8*)&Qb[((size_t)(bh0 + bh) * GG + q0 + qg * 16 + l15) * 32 + quad * 8];
    const float* mrow = mask + (size_t)(q0 + qg * 16 + l15) * GG + quad * 4;

    auto stage = [&](int buf, int k0) {
        #pragma unroll
        for (int s = 0; s < 2; s++) {
            int idx = s * 512 + t;
            int bh = idx >> 8, c = idx & 255;
            int key = ((c >> 6) << 4) + (c & 15);
            int chunk = (c >> 4) & 3;
            gld16(Kb + ((size_t)(bh0 + bh) * GG + k0 + key) * 32 + chunk * 8,
                  &Kl[buf][bh][c * 8]);
            gld16(Vf + ((size_t)((bh0 + bh) * 64 + (k0 >> 6))) * 2048 + c * 8,
                  &Vl[buf][bh][c * 8]);
        }
    };
    stage(0, kstart);

    f4 O0[4], O1[4];
    float ls[4];
    #pragma unroll
    for (int bh = 0; bh < 4; bh++) {
        O0[bh] = f4{0.f, 0.f, 0.f, 0.f};
        O1[bh] = f4{0.f, 0.f, 0.f, 0.f};
        ls[bh] = 0.f;
    }

    for (int k0 = kstart; k0 < kend; k0 += 64) {
        const int cur = ((k0 - kstart) >> 6) & 1;
        __syncthreads();
        if (k0 + 64 < kend) stage(cur ^ 1, k0 + 64);
        float4 mva = *(const float4*)&mrow[k0 + i2a * 16];
        float4 mvb = *(const float4*)&mrow[k0 + i2b * 16];
        #pragma unroll
        for (int bh = 0; bh < 4; bh++) {
            sh8 kfa = *(const sh8*)&Kl[cur][bh][(i2a * 64 + lane) * 8];
            sh8 kfb = *(const sh8*)&Kl[cur][bh][(i2b * 64 + lane) * 8];
            f4 z = {0.f, 0.f, 0.f, 0.f};
            f4 sa = __builtin_amdgcn_mfma_f32_16x16x32_bf16(kfa, qf[bh], z, 0, 0, 0);
            f4 sb = __builtin_amdgcn_mfma_f32_16x16x32_bf16(kfb, qf[bh], z, 0, 0, 0);
            {
                float p0 = exp2f(fmaf(mva.x, LOG2E, sa[0]));
                float p1 = exp2f(fmaf(mva.y, LOG2E, sa[1]));
                float p2 = exp2f(fmaf(mva.z, LOG2E, sa[2]));
                float p3 = exp2f(fmaf(mva.w, LOG2E, sa[3]));
                ls[bh] += (p0 + p1) + (p2 + p3);
                union { __hip_bfloat162 h2[2]; sh4 v; } pkp;
                pkp.h2[0] = __float22bfloat162_rn(float2{p0, p1});
                pkp.h2[1] = __float22bfloat162_rn(float2{p2, p3});
                sh4 vf0 = *(const sh4*)&Vl[cur][bh][((i2a * 2 + 0) * 64 + lane) * 4];
                sh4 vf1 = *(const sh4*)&Vl[cur][bh][((i2a * 2 + 1) * 64 + lane) * 4];
                O0[bh] = MFMA16(pkp.v, vf0, O0[bh]);
                O1[bh] = MFMA16(pkp.v, vf1, O1[bh]);
            }
            {
                float p0 = exp2f(fmaf(mvb.x, LOG2E, sb[0]));
                float p1 = exp2f(fmaf(mvb.y, LOG2E, sb[1]));
                float p2 = exp2f(fmaf(mvb.z, LOG2E, sb[2]));
                float p3 = exp2f(fmaf(mvb.w, LOG2E, sb[3]));
                ls[bh] += (p0 + p1) + (p2 + p3);
                union { __hip_bfloat162 h2[2]; sh4 v; } pkp;
                pkp.h2[0] = __float22bfloat162_rn(float2{p0, p1});
                pkp.h2[1] = __float22bfloat162_rn(float2{p2, p3});
                sh4 vf0 = *(const sh4*)&Vl[cur][bh][((i2b * 2 + 0) * 64 + lane) * 4];
                sh4 vf1 = *(const sh4*)&Vl[cur][bh][((i2b * 2 + 1) * 64 + lane) * 4];
                O0[bh] = MFMA16(pkp.v, vf0, O0[bh]);
                O1[bh] = MFMA16(pkp.v, vf1, O1[bh]);
            }
        }
    }
    #pragma unroll
    for (int bh = 0; bh < 4; bh++) {
        ls[bh] += __shfl_xor(ls[bh], 16, 64);
        ls[bh] += __shfl_xor(ls[bh], 32, 64);
    }
    __syncthreads();
    float* Ox = (float*)&Kl[0][0][0];
    float* Lx = (float*)&Vl[0][0][0];
    if (kh == 0) {
        #pragma unroll
        for (int bh = 0; bh < 4; bh++) {
            #pragma unroll
            for (int r = 0; r < 4; r++) {
                int ql = qg * 16 + quad * 4 + r;
                Ox[(bh * 64 + ql) * 32 + l15] = O0[bh][r];
                Ox[(bh * 64 + ql) * 32 + l15 + 16] = O1[bh][r];
            }
            if (quad == 0) Lx[bh * 64 + qg * 16 + l15] = ls[bh];
        }
    }
    __syncthreads();
    if (kh == 1) {
        float* op = (split < 3) ? (opA + (size_t)split * OPS) : opB;
        #pragma unroll
        for (int bh = 0; bh < 4; bh++) {
            int gbh = bh0 + bh;
            #pragma unroll
            for (int r = 0; r < 4; r++) {
                int ql = qg * 16 + quad * 4 + r;
                size_t o = ((size_t)gbh * GG + q0 + ql) * 32 + l15;
                op[o] = O0[bh][r] + Ox[(bh * 64 + ql) * 32 + l15];
                op[o + 16] = O1[bh][r] + Ox[(bh * 64 + ql) * 32 + l15 + 16];
            }
            if (quad == 0)
                Lp[split * 32768 + gbh * GG + q0 + qg * 16 + l15] =
                    ls[bh] + Lx[bh * 64 + qg * 16 + l15];
        }
    }
}

// combine splits + att = ctx @ Wout^T + b ; h1 = LN(bn(yrw2) + att); also emit h1b frag-bf16
__global__ void k_attn_out_ln(const float* __restrict__ opA, const float* __restrict__ opB,
                              const float* __restrict__ Lp, const float* __restrict__ yrw2,
                              const float* __restrict__ W, const float* __restrict__ bias,
                              const float* __restrict__ bsum, const float* __restrict__ bsq,
                              const float* __restrict__ bg, const float* __restrict__ bb,
                              const float* __restrict__ lg, const float* __restrict__ lb,
                              float* __restrict__ h1, ushort_t* __restrict__ h1b) {
    __shared__ float Wt[64][65];
    __shared__ float Cs[16][65];
    __shared__ ushort_t Hs[16][64];
    int t = threadIdx.x;
    int row0 = blockIdx.x * 16;
    for (int i = t; i < 4096; i += 256) Wt[i & 63][i >> 6] = W[i];
    {
        int col = t & 63, rl = t >> 6;
        int hh = col >> 5, d = col & 31;
        #pragma unroll
        for (int jj = 0; jj < 4; jj++) {
            int row = row0 + rl + jj * 4;
            int b = row >> 12, q = row & 4095;
            int bhq = (b * 2 + hh) * GG + q;
            size_t oi = (size_t)bhq * 32 + d;
            float num = opA[oi] + opA[OPS + oi] + opA[2 * OPS + oi] + opB[oi];
            float den = Lp[bhq] + Lp[32768 + bhq] + Lp[65536 + bhq] + Lp[98304 + bhq];
            Cs[rl + jj * 4][col] = num / den;
        }
    }
    __syncthreads();
    int rr = t >> 6, lane = t & 63;
    const float invN = 1.0f / (float)(BB * GG);
    float m = bsum[lane] * invN;
    float is_ = rsqrtf(bsq[lane] * invN - m * m + BNEPS);
    #pragma unroll
    for (int j = 0; j < 4; j++) {
        int lrow = rr * 4 + j;
        int row = row0 + lrow;
        float acc = bias[lane];
        const float* cr = Cs[lrow];
        #pragma unroll 8
        for (int k = 0; k < 64; k++) acc += cr[k] * Wt[k][lane];
        float ov = (yrw2[row * 64 + lane] - m) * is_ * bg[lane] + bb[lane];
        float v = ov + acc;
        float s = v;
        for (int o = 32; o > 0; o >>= 1) s += __shfl_xor(s, o, 64);
        float mean = s * (1.f / 64.f);
        float d = v - mean;
        float sq = d * d;
        for (int o = 32; o > 0; o >>= 1) sq += __shfl_xor(sq, o, 64);
        float inv = rsqrtf(sq * (1.f / 64.f) + BNEPS);
        float hv = d * inv * lg[lane] + lb[lane];
        h1[row * 64 + lane] = hv;
        Hs[lrow][lane] = f2b(hv);
    }
    __syncthreads();
    if (t < 128) {
        int kt = t >> 6, lane6 = t & 63;
        int q2 = (lane6 >> 4) & 3, r15 = lane6 & 15;
        union { ushort_t u[8]; uint4 v; } pk;
        #pragma unroll
        for (int j = 0; j < 8; j++) pk.u[j] = Hs[r15][kt * 32 + q2 * 8 + j];
        *(uint4*)&h1b[((size_t)blockIdx.x * 2 + kt) * 512 + lane6 * 8] = pk.v;
    }
}

// ================= FFN layer 1: fft = relu(h1 @ W1^T + b1), bf16 MFMA =================
__launch_bounds__(256)
__global__ void k_ffn1(const ushort_t* __restrict__ h1b, const ushort_t* __restrict__ W1b,
                       const float* __restrict__ b1, ushort_t* __restrict__ fft) {
    __shared__ ushort_t Xl[4096];
    __shared__ ushort_t Wl[4096];
    const int t = threadIdx.x;
    const int rowblock = blockIdx.x, colblock = blockIdx.y;
    const int cb = colblock * 64;
    const int lane = t & 63, w = t >> 6;
    const int l15 = lane & 15, quad = lane >> 4;
    #pragma unroll
    for (int kt = 0; kt < 2; kt++) {
        gld16(h1b + (size_t)(((rowblock * 4 + w) * 2 + kt) * 512 + lane * 8),
              &Xl[(w * 2 + kt) * 512 + lane * 8]);
        gld16(W1b + (size_t)((cb + w * 16 + l15) * 64 + kt * 32 + quad * 8),
              &Wl[(w * 2 + kt) * 512 + lane * 8]);
    }
    __syncthreads();
    sh8 xf0 = *(const sh8*)&Xl[(w * 2 + 0) * 512 + lane * 8];
    sh8 xf1 = *(const sh8*)&Xl[(w * 2 + 1) * 512 + lane * 8];
    #pragma unroll
    for (int c = 0; c < 4; c++) {
        sh8 wf0 = *(const sh8*)&Wl[(c * 2 + 0) * 512 + lane * 8];
        sh8 wf1 = *(const sh8*)&Wl[(c * 2 + 1) * 512 + lane * 8];
        f4 z = {0.f, 0.f, 0.f, 0.f};
        f4 acc = __builtin_amdgcn_mfma_f32_16x16x32_bf16(wf0, xf0, z, 0, 0, 0);
        acc = __builtin_amdgcn_mfma_f32_16x16x32_bf16(wf1, xf1, acc, 0, 0, 0);
        float4 bv = *(const float4*)&b1[cb + c * 16 + quad * 4];
        union { ushort_t u[4]; uint2 v; } pk;
        pk.u[0] = f2b(fmaxf(acc[0] + bv.x, 0.f));
        pk.u[1] = f2b(fmaxf(acc[1] + bv.y, 0.f));
        pk.u[2] = f2b(fmaxf(acc[2] + bv.z, 0.f));
        pk.u[3] = f2b(fmaxf(acc[3] + bv.w, 0.f));
        int kt512 = colblock * 2 + (c >> 1);
        int quadp = (c & 1) * 2 + (quad >> 1);
        int j0 = (quad & 1) * 4;
        size_t o = ((size_t)(((rowblock * 4 + w) * 16 + kt512) * 64 + quadp * 16 + l15)) * 8 + j0;
        *(uint2*)&fft[o] = pk.v;
    }
}

// ================= FFN layer 2 + LN2 + per-gene head + recon (fused final) =================
__launch_bounds__(256)
__global__ void k_ffn2(const ushort_t* __restrict__ fft, const ushort_t* __restrict__ W2b,
                       const float* __restrict__ b2, const float* __restrict__ h1,
                       const float* __restrict__ lg, const float* __restrict__ lb,
                       const float* __restrict__ indvw, const float* __restrict__ indvb,
                       const float* __restrict__ hdc, const float* __restrict__ d2w,
                       const float* __restrict__ d2b, const float* __restrict__ x,
                       float* __restrict__ outp) {
    __shared__ ushort_t Xl[2][4096];
    __shared__ ushort_t Wl[2][4096];
    const int t = threadIdx.x;
    const int rowblock = blockIdx.x;
    const int lane = t & 63, w = t >> 6;
    const int l15 = lane & 15, quad = lane >> 4;

    #pragma unroll
    for (int kt = 0; kt < 2; kt++) {
        gld16(fft + (size_t)((((rowblock * 4 + w) * 16) + kt) * 64 + lane) * 8,
              &Xl[0][(w * 2 + kt) * 512 + lane * 8]);
        gld16(W2b + (size_t)((w * 16 + l15) * 512 + kt * 32 + quad * 8),
              &Wl[0][(w * 2 + kt) * 512 + lane * 8]);
    }
    f4 acc[4];
    #pragma unroll
    for (int c = 0; c < 4; c++) acc[c] = f4{0.f, 0.f, 0.f, 0.f};

    for (int k0 = 0; k0 < 512; k0 += 64) {
        const int cur = (k0 >> 6) & 1;
        __syncthreads();
        if (k0 + 64 < 512) {
            const int nxt = cur ^ 1;
            const int ktb = (k0 + 64) >> 5;
            #pragma unroll
            for (int kt = 0; kt < 2; kt++) {
                gld16(fft + (size_t)((((rowblock * 4 + w) * 16) + ktb + kt) * 64 + lane) * 8,
                      &Xl[nxt][(w * 2 + kt) * 512 + lane * 8]);
                gld16(W2b + (size_t)((w * 16 + l15) * 512 + k0 + 64 + kt * 32 + quad * 8),
                      &Wl[nxt][(w * 2 + kt) * 512 + lane * 8]);
            }
        }
        #pragma unroll
        for (int kt = 0; kt < 2; kt++) {
            sh8 xf = *(const sh8*)&Xl[cur][(w * 2 + kt) * 512 + lane * 8];
            #pragma unroll
            for (int c = 0; c < 4; c++) {
                sh8 wf = *(const sh8*)&Wl[cur][(c * 2 + kt) * 512 + lane * 8];
                acc[c] = __builtin_amdgcn_mfma_f32_16x16x32_bf16(wf, xf, acc[c], 0, 0, 0);
            }
        }
    }
    const int row = rowblock * 64 + w * 16 + l15;
    const int b = row >> 12, g = row & 4095;
    float v[4][4];
    float s = 0.f, sq = 0.f;
    #pragma unroll
    for (int c = 0; c < 4; c++) {
        float4 bv = *(const float4*)&b2[c * 16 + quad * 4];
        float4 hv = *(const float4*)&h1[(size_t)row * 64 + c * 16 + quad * 4];
        v[c][0] = hv.x + acc[c][0] + bv.x;
        v[c][1] = hv.y + acc[c][1] + bv.y;
        v[c][2] = hv.z + acc[c][2] + bv.z;
        v[c][3] = hv.w + acc[c][3] + bv.w;
        #pragma unroll
        for (int i = 0; i < 4; i++) { s += v[c][i]; sq += v[c][i] * v[c][i]; }
    }
    s += __shfl_xor(s, 16, 64);  s += __shfl_xor(s, 32, 64);
    sq += __shfl_xor(sq, 16, 64); sq += __shfl_xor(sq, 32, 64);
    float mean = s * (1.f / 64.f);
    float inv = rsqrtf(sq * (1.f / 64.f) - mean * mean + BNEPS);
    float pd = 0.f;
    #pragma unroll
    for (int c = 0; c < 4; c++) {
        float4 lgv = *(const float4*)&lg[c * 16 + quad * 4];
        float4 lbv = *(const float4*)&lb[c * 16 + quad * 4];
        float4 iwv = *(const float4*)&indvw[(size_t)g * 64 + c * 16 + quad * 4];
        pd += ((v[c][0] - mean) * inv * lgv.x + lbv.x) * iwv.x;
        pd += ((v[c][1] - mean) * inv * lgv.y + lbv.y) * iwv.y;
        pd += ((v[c][2] - mean) * inv * lgv.z + lbv.z) * iwv.z;
        pd += ((v[c][3] - mean) * inv * lgv.w + lbv.w) * iwv.w;
    }
    float rc = 0.f;
    #pragma unroll
    for (int i = 0; i < 8; i++)
        rc += hdc[b * 32 + quad * 8 + i] * d2w[(size_t)g * 32 + quad * 8 + i];
    pd += __shfl_xor(pd, 16, 64); pd += __shfl_xor(pd, 32, 64);
    rc += __shfl_xor(rc, 16, 64); rc += __shfl_xor(rc, 32, 64);
    if (quad == 0) {
        float recon = rc + d2b[g];
        if (x[row] == 0.f) recon = 0.f;
        outp[row] = pd + indvb[g] + recon;
    }
}

extern "C" void kernel_launch(void* const* d_in, const int* in_sizes, int n_in,
                              void* d_out, int out_size, void* d_ws, size_t ws_size,
                              hipStream_t stream) {
    const float* x        = (const float*)d_in[0];
    const int*   pert_idx = (const int*)  d_in[1];
    const float* mask     = (const float*)d_in[2];
    const int*   ei_co    = (const int*)  d_in[3];
    const float* w_co     = (const float*)d_in[4];
    const int*   ei_go    = (const int*)  d_in[5];
    const float* w_go     = (const float*)d_in[6];
    const float* gene_emb = (const float*)d_in[7];
    const float* emb_pos  = (const float*)d_in[8];
    const float* pert_tbl = (const float*)d_in[9];
    const float* sg_co_w  = (const float*)d_in[10];
    const float* sg_co_b  = (const float*)d_in[11];
    const float* sg_go_w  = (const float*)d_in[12];
    const float* sg_go_b  = (const float*)d_in[13];
    const float* bn_emb_g = (const float*)d_in[14];
    const float* bn_emb_b = (const float*)d_in[15];
    const float* etv1_w   = (const float*)d_in[16];
    const float* etv1_b   = (const float*)d_in[17];
    const float* etv1_g   = (const float*)d_in[18];
    const float* etv1_be  = (const float*)d_in[19];
    const float* etv2_w   = (const float*)d_in[20];
    const float* etv2_b   = (const float*)d_in[21];
    const float* etv2_g   = (const float*)d_in[22];
    const float* etv2_be  = (const float*)d_in[23];
    const float* pf1_w    = (const float*)d_in[24];
    const float* pf1_b    = (const float*)d_in[25];
    const float* pf1_g    = (const float*)d_in[26];
    const float* pf1_be   = (const float*)d_in[27];
    const float* pf2_w    = (const float*)d_in[28];
    const float* pf2_b    = (const float*)d_in[29];
    const float* pf2_g    = (const float*)d_in[30];
    const float* pf2_be   = (const float*)d_in[31];
    const float* rw1_w    = (const float*)d_in[32];
    const float* rw1_b    = (const float*)d_in[33];
    const float* rw1_g    = (const float*)d_in[34];
    const float* rw1_be   = (const float*)d_in[35];
    const float* rw2_w    = (const float*)d_in[36];
    const float* rw2_b    = (const float*)d_in[37];
    const float* rw2_g    = (const float*)d_in[38];
    const float* rw2_be   = (const float*)d_in[39];
    const float* bnpb_g   = (const float*)d_in[40];
    const float* bnpb_b   = (const float*)d_in[41];
    const float* ain_w    = (const float*)d_in[42];
    const float* ain_b    = (const float*)d_in[43];
    const float* aout_w   = (const float*)d_in[44];
    const float* aout_b   = (const float*)d_in[45];
    const float* ln1_g    = (const float*)d_in[46];
    const float* ln1_b    = (const float*)d_in[47];
    const float* ff1_w    = (const float*)d_in[48];
    const float* ff1_b    = (const float*)d_in[49];
    const float* ff2_w    = (const float*)d_in[50];
    const float* ff2_b    = (const float*)d_in[51];
    const float* ln2_g    = (const float*)d_in[52];
    const float* ln2_b    = (const float*)d_in[53];
    const float* indv_w   = (const float*)d_in[54];
    const float* indv_b   = (const float*)d_in[55];
    const float* ve1_w    = (const float*)d_in[56];
    const float* ve1_b    = (const float*)d_in[57];
    const float* vmu_w    = (const float*)d_in[58];
    const float* vmu_b    = (const float*)d_in[59];
    const float* vlv_w    = (const float*)d_in[60];
    const float* vlv_b    = (const float*)d_in[61];
    const float* vd1_w    = (const float*)d_in[62];
    const float* vd1_b    = (const float*)d_in[63];
    const float* vd2_w    = (const float*)d_in[64];
    const float* vd2_b    = (const float*)d_in[65];
    const float* veps     = (const float*)d_in[66];

    float* ws   = (float*)d_ws;
    float* outp = (float*)d_out;

    float* stm1 = ws + OF_STATS + 1 * 256; float* sti1 = stm1 + 128;
    float* stm2 = ws + OF_STATS + 2 * 256; float* sti2 = stm2 + 128;
    float* stm3 = ws + OF_STATS + 3 * 256; float* sti3 = stm3 + 128;
    float* stm4 = ws + OF_STATS + 4 * 256; float* sti4 = stm4 + 128;
    float* stm5 = ws + OF_STATS + 5 * 256; float* sti5 = stm5 + 128;

    float* basein = ws + OF_BASEIN;
    float* y1     = ws + OF_Y1;
    float* y2     = ws + OF_Y2;
    float* flat   = ws + OF_FLAT;
    float* yrw1   = ws + OF_RW1;
    float* yrw2   = ws + OF_RW2;
    float* h1     = ws + OF_H1;
    float* opA    = ws + OF_OPA;
    float* opB    = ws + OF_OPB;
    float* Lp     = ws + OF_LP;
    ushort_t* Qb  = (ushort_t*)(ws + OF_QB);
    ushort_t* Kb  = (ushort_t*)(ws + OF_KB);
    ushort_t* Vf  = (ushort_t*)(ws + OF_VF);
    ushort_t* W1b = (ushort_t*)(ws + OF_W1B);
    ushort_t* W2b = (ushort_t*)(ws + OF_W2B);
    ushort_t* h1b = (ushort_t*)(ws + OF_H1B);
    ushort_t* fft = (ushort_t*)(ws + OF_FFT);

    const int NG = BB * GG; // 16384
    const float iG = 1.0f / (float)GG, iNG = 1.0f / (float)NG;

    // K1: zero ws regions (float4), deg=1, vae_he, FFN weight->bf16
    k_fat1<<<651, 256, 0, stream>>>(ws, x, ve1_w, ve1_b, ff1_w, ff2_w);
    // K2: edge degrees, gene_emb stats, vae_mid
    k_fat2<<<897, 256, 0, stream>>>(ws, ei_co, w_co, ei_go, w_go, gene_emb,
                                    vmu_w, vmu_b, vlv_w, vlv_b, vd1_w, vd1_b,
                                    veps, outp + NG);
    // K3: coalesced co edge aggregation + pert slot-scan
    k_fat3<<<20488, 256, 0, stream>>>(ws, ei_co, w_co, emb_pos, pert_idx,
                                      ei_go, w_go, pert_tbl);
    // K4: base_combine + pert MLP
    k_fat4<<<1025, 256, 0, stream>>>(ws, gene_emb, emb_pos, sg_co_w, sg_co_b,
                                     bn_emb_g, bn_emb_b, pert_idx, pert_tbl,
                                     sg_go_w, sg_go_b,
                                     pf1_w, pf1_b, pf1_g, pf1_be,
                                     pf2_w, pf2_b, pf2_g, pf2_be);
    // etv MLP (stats fused into epilogues)
    k_gemm64<<<dim3(GG / 64, 1), 256, 0, stream>>>(basein, etv1_w, etv1_b, y1, 64, 64,
                                                   nullptr, nullptr, nullptr, nullptr, 0.f, 0,
                                                   stm1, sti1);
    k_gemm64<<<dim3(GG / 64, 1), 256, 0, stream>>>(y1, etv2_w, etv2_b, y2, 64, 64,
                                                   stm1, sti1, etv1_g, etv1_be, iG, 1,
                                                   stm2, sti2);
    // fuse + rw MLP
    k_flatpre<<<NG / 64, 256, 0, stream>>>(y2, ws + OF_ETOT, stm2, sti2, etv2_g, etv2_be,
                                           flat, stm3, sti3);
    k_gemm64<<<dim3(NG / 64, 2), 256, 0, stream>>>(flat, rw1_w, rw1_b, yrw1, 64, 128,
                                                   stm3, sti3, bnpb_g, bnpb_b, iNG, 1,
                                                   stm4, sti4);
    k_gemm64<<<dim3(NG / 64, 1), 256, 0, stream>>>(yrw1, rw2_w, rw2_b, yrw2, 128, 64,
                                                   stm4, sti4, rw1_g, rw1_be, iNG, 1,
                                                   stm5, sti5);
    // transformer
    k_gemm_qkv<<<dim3(NG / 64, 3), 256, 0, stream>>>(yrw2, ain_w, ain_b,
                                                     stm5, sti5, rw2_g, rw2_be,
                                                     Qb, Kb, Vf);
    k_attn_mfma<<<dim3(GG / 64, 4, 2), 512, 0, stream>>>(Qb, Kb, Vf, mask, opA, opB, Lp);
    k_attn_out_ln<<<NG / 16, 256, 0, stream>>>(opA, opB, Lp, yrw2, aout_w, aout_b,
                                               stm5, sti5, rw2_g, rw2_be,
                                               ln1_g, ln1_b, h1, h1b);
    // FFN (bf16 MFMA) + fused final
    k_ffn1<<<dim3(NG / 64, FFD / 64), 256, 0, stream>>>(h1b, W1b, ff1_b, fft);
    k_ffn2<<<NG / 64, 256, 0, stream>>>(fft, W2b, ff2_b, h1, ln2_g, ln2_b,
                                        indv_w, indv_b, ws + OF_HDC, vd2_w, vd2_b,
                                        x, outp);
}

// Round 11
// 527.568 us; speedup vs baseline: 1.2264x; 1.2264x over previous
//
#include <hip/hip_runtime.h>
#include <hip/hip_bf16.h>
#include <math.h>

#define GG 4096
#define PP 4096
#define HH 64
#define BB 4
#define E1N 81920
#define E2N 81920
#define FFD 512
#define BNEPS 1e-5f
#define LOG2E 1.44269504088896341f
#define QPRE (0.17677669529663687f * LOG2E)

typedef unsigned short ushort_t;
typedef unsigned int uint_t;
using sh8 = __attribute__((ext_vector_type(8))) short;
using sh4 = __attribute__((ext_vector_type(4))) short;
using f4  = __attribute__((ext_vector_type(4))) float;

#if __has_builtin(__builtin_amdgcn_mfma_f32_16x16x16bf16_1k)
#define MFMA16(a, b, c) __builtin_amdgcn_mfma_f32_16x16x16bf16_1k((a), (b), (c), 0, 0, 0)
#elif __has_builtin(__builtin_amdgcn_mfma_f32_16x16x16_bf16)
#define MFMA16(a, b, c) __builtin_amdgcn_mfma_f32_16x16x16_bf16((a), (b), (c), 0, 0, 0)
#else
static __device__ inline f4 mfma16_asm(sh4 a, sh4 b, f4 c) {
    f4 d;
    asm volatile("v_mfma_f32_16x16x16_bf16 %0, %1, %2, %3"
                 : "=v"(d) : "v"(a), "v"(b), "v"(c));
    return d;
}
#define MFMA16(a, b, c) mfma16_asm((a), (b), (c))
#endif

// ---------------- workspace layout (float offsets) ----------------
#define OF_STATS   0          // 6 slots x 256 (raw sum[128] + sumsq[128])
#define OF_DEGCO   2048
#define OF_DEGGO   6144
#define OF_PSLOT   10240
#define OF_ETOT    10752
#define OF_HDC     11008
#define OF_HE      11136
#define OF_AGGCO   12288      // 4096 x 64
#define OF_BASEIN  274432
#define OF_Y1      536576
#define OF_Y2      798720
#define OF_FLAT    1060864    // 16384 x 64
#define OF_RW1     2109440    // 16384 x 128
#define OF_RW2     4206592    // 16384 x 64
#define OF_OUT     5255168    // 16384 x 64   (attn split 3 partial)
#define OF_QKV     6303744    // (attn splits 0..2 partials; ends 9449472)
#define OF_H1      10498048   // 16384 x 64
// bf16 attention buffers (alias dead fp32 regions)
#define OF_QB      OF_AGGCO   // 8*4096*32 ushort = 524288 floats
#define OF_KB      (OF_AGGCO + 524288)
#define OF_VF      OF_FLAT    // 8*64*2048 ushort = 524288 floats (V frag-order)
// attention k-split partials
#define OF_OPA     OF_QKV
#define OF_OPB     OF_OUT
#define OF_LP      OF_RW1     // 4*8*4096 = 131072
#define OPS        1048576    // split stride in opA (8*4096*32)
// FFN bf16 buffers (dead FFO region 9449472..10498048)
#define OF_W1B     9449472    // 512*64 bf16 = 16384 floats
#define OF_W2B     9465856    // 64*512 bf16 = 16384 floats
#define OF_H1B     9482240    // 16384*64 bf16 = 524288 floats (A-frag order)
// fft bf16 (frag order): FLAT..RW2 region, dead post-attn
#define OF_FFT     OF_FLAT

__device__ inline ushort_t f2b(float f) {
    uint_t u = __builtin_bit_cast(uint_t, f);
    u += 0x7FFFu + ((u >> 16) & 1u);
    return (ushort_t)(u >> 16);
}

__device__ inline void gld16(const void* gptr, void* lptr) {
    __builtin_amdgcn_global_load_lds(
        (const __attribute__((address_space(1))) uint_t*)gptr,
        (__attribute__((address_space(3))) uint_t*)lptr, 16, 0, 0);
}

// ================= device sub-kernels for fat launches =================
__device__ void dev_vae_he(int bid, const float* __restrict__ x, const float* __restrict__ W,
                           const float* __restrict__ bias, float* he, float* sh) {
    int b = bid >> 5, i = bid & 31;
    float s = 0.f;
    for (int g = threadIdx.x; g < 4096; g += 256) s += x[b * 4096 + g] * W[i * 4096 + g];
    sh[threadIdx.x] = s;
    __syncthreads();
    for (int o = 128; o > 0; o >>= 1) {
        if (threadIdx.x < o) sh[threadIdx.x] += sh[threadIdx.x + o];
        __syncthreads();
    }
    if (threadIdx.x == 0) he[b * 32 + i] = fmaxf(sh[0] + bias[i], 0.f);
}

__device__ void dev_vae_mid(const float* __restrict__ he,
                            const float* __restrict__ muw, const float* __restrict__ mub,
                            const float* __restrict__ lvw, const float* __restrict__ lvb,
                            const float* __restrict__ d1w, const float* __restrict__ d1b,
                            const float* __restrict__ eps, float* hdc, float* klout, float* zs) {
    int t = threadIdx.x;
    if (t < 64) {
        int b = t >> 4, l = t & 15;
        float mu = mub[l], lv = lvb[l];
        for (int i = 0; i < 32; i++) {
            float hv = he[b * 32 + i];
            mu += hv * muw[l * 32 + i];
            lv += hv * lvw[l * 32 + i];
        }
        zs[t] = mu + eps[t] * expf(0.5f * lv);
        float kterm = 1.f + lv - mu * mu - expf(lv);
        for (int o = 32; o > 0; o >>= 1) kterm += __shfl_xor(kterm, o, 64);
        if (t == 0) klout[0] = -0.5f * kterm * 0.25f;
    }
    __syncthreads();
    if (t < 128) {
        int b = t >> 5, i = t & 31;
        float a = d1b[i];
        for (int l = 0; l < 16; l++) a += zs[b * 16 + l] * d1w[i * 16 + l];
        hdc[t] = fmaxf(a, 0.f);
    }
}

__device__ void dev_edge_deg(int bid, const int* __restrict__ ei, const float* __restrict__ w,
                             float* deg, int E) {
    int e = bid * 256 + threadIdx.x;
    if (e < E) atomicAdd(&deg[ei[E + e]], w[e]);
}

__device__ void dev_cs_part(int bid, const float* __restrict__ X, int N,
                            float* sum, float* sumsq, float* sh) {
    int t = threadIdx.x;
    int col = t & 63, ro = t >> 6;
    int rows = N >> 8;
    int r0 = bid * rows;
    float s = 0.f, q = 0.f;
    for (int r = r0 + ro; r < r0 + rows; r += 4) {
        float v = X[r * 64 + col];
        s += v; q += v * v;
    }
    float* ls = sh; float* lq = sh + 256;
    ls[t] = s; lq[t] = q;
    __syncthreads();
    if (t < 64) {
        for (int j = t + 64; j < 256; j += 64) { s += ls[j]; q += lq[j]; }
        atomicAdd(&sum[t], s);
        atomicAdd(&sumsq[t], q);
    }
}

// coalesced per-edge-wave aggregation: wave handles one edge, 64 lanes = 64 h
__device__ void dev_edge_agg(int bid, const int* __restrict__ ei, const float* __restrict__ w,
                             const float* __restrict__ deg, const float* __restrict__ x,
                             float* agg) {
    int gid = bid * 256 + threadIdx.x;
    int e = gid >> 6, h = gid & 63;
    if (e < E1N) {
        int src = ei[e], dst = ei[E1N + e];
        float norm = rsqrtf(deg[dst]) * w[e] * rsqrtf(deg[src]);
        atomicAdd(&agg[dst * HH + h], norm * x[src * HH + h]);
    }
}

// 320-block broadcast scan: each thread owns one edge, compares dst vs 8 pidx
__device__ void dev_pert_edges(int bid, const int* __restrict__ pidx, const int* __restrict__ ei,
                               const float* __restrict__ w, const float* __restrict__ deg,
                               const float* __restrict__ tbl, float* pslot) {
    int e = bid * 256 + threadIdx.x;
    if (e >= E2N) return;
    int dst = ei[E2N + e];
    int src = ei[e];
    for (int s = 0; s < 8; s++) {
        if (pidx[s] == dst) {
            float norm = rsqrtf(deg[dst]) * w[e] * rsqrtf(deg[src]);
            for (int h = 0; h < 64; h++)
                atomicAdd(&pslot[s * 64 + h], norm * tbl[src * 64 + h]);
        }
    }
}

// base_in = relu(bn(gene_emb)) + 0.2*((agg + emb_pos/deg) @ Wco^T + bco)
__device__ void dev_base_combine(int bid, const float* __restrict__ gene_emb,
                                 const float* __restrict__ agg, const float* __restrict__ emb_pos,
                                 const float* __restrict__ deg,
                                 const float* __restrict__ W, const float* __restrict__ bias,
                                 const float* __restrict__ bsum, const float* __restrict__ bsq,
                                 const float* __restrict__ bg, const float* __restrict__ bb,
                                 float* out, float* sh) {
    float* Wt = sh;            // [64][65]
    float* a = sh + 4160;      // [4][64]
    int t = threadIdx.x;
    for (int i = t; i < 4096; i += 256) Wt[(i & 63) * 65 + (i >> 6)] = W[i];
    int rr = t >> 6, h = t & 63;
    int g = bid * 4 + rr;
    a[rr * 64 + h] = agg[g * 64 + h] + emb_pos[g * 64 + h] / deg[g];
    __syncthreads();
    float y = bias[h];
    const float* ar = a + rr * 64;
    #pragma unroll 8
    for (int k = 0; k < 64; k++) y += ar[k] * Wt[k * 65 + h];
    const float invN = 1.0f / (float)GG;
    float m = bsum[h] * invN;
    float is_ = rsqrtf(bsq[h] * invN - m * m + BNEPS);
    float v = gene_emb[g * 64 + h];
    v = (v - m) * is_ * bg[h] + bb[h];
    v = fmaxf(v, 0.f);
    out[g * 64 + h] = v + 0.2f * y;
}

__device__ void dev_pert_mlp(const float* __restrict__ pslot, const int* __restrict__ pidx,
                             const float* __restrict__ deg, const float* __restrict__ tbl,
                             const float* __restrict__ gw, const float* __restrict__ gb,
                             const float* __restrict__ w1, const float* __restrict__ b1,
                             const float* __restrict__ g1, const float* __restrict__ be1,
                             const float* __restrict__ w2, const float* __restrict__ b2,
                             const float* __restrict__ g2, const float* __restrict__ be2,
                             float* etot, float* sh) {
    float* pge = sh;
    float* psum = sh + 512;
    float* y = sh + 768;
    float* mh = sh + 1024;
    float* ih = sh + 1088;
    int t = threadIdx.x;
    for (int j = t; j < 512; j += 256) {
        int s = j >> 6, h = j & 63;
        int n = pidx[s];
        float invd = 1.0f / deg[n];
        float acc = gb[h];
        for (int k = 0; k < 64; k++)
            acc += (pslot[s * 64 + k] + tbl[n * 64 + k] * invd) * gw[h * 64 + k];
        pge[j] = acc;
    }
    __syncthreads();
    { int b = t >> 6, h = t & 63; psum[t] = pge[2 * b * 64 + h] + pge[(2 * b + 1) * 64 + h]; }
    __syncthreads();
    { int h = t & 63; int b = t >> 6;
      float acc = b1[h];
      for (int k = 0; k < 64; k++) acc += psum[b * 64 + k] * w1[h * 64 + k];
      y[t] = acc; }
    __syncthreads();
    if (t < 64) {
        float s = 0.f, sq = 0.f;
        for (int b = 0; b < 4; b++) { float v = y[b * 64 + t]; s += v; sq += v * v; }
        float m = s * 0.25f;
        mh[t] = m; ih[t] = rsqrtf(sq * 0.25f - m * m + BNEPS);
    }
    __syncthreads();
    { int h = t & 63;
      float v = (y[t] - mh[h]) * ih[h] * g1[h] + be1[h];
      psum[t] = fmaxf(v, 0.f); }
    __syncthreads();
    { int h = t & 63; int b = t >> 6;
      float acc = b2[h];
      for (int k = 0; k < 64; k++) acc += psum[b * 64 + k] * w2[h * 64 + k];
      y[t] = acc; }
    __syncthreads();
    if (t < 64) {
        float s = 0.f, sq = 0.f;
        for (int b = 0; b < 4; b++) { float v = y[b * 64 + t]; s += v; sq += v * v; }
        float m = s * 0.25f;
        mh[t] = m; ih[t] = rsqrtf(sq * 0.25f - m * m + BNEPS);
    }
    __syncthreads();
    { int h = t & 63;
      etot[t] = (y[t] - mh[h]) * ih[h] * g2[h] + be2[h]; }
}

// ================= fat kernels =================
// K1: zero aggco(256,f4) | zero stats+pslot(3,f4) | deg=1(8,f4) | vae_he(128) | W->bf16(256)
__global__ void k_fat1(float* ws, const float* __restrict__ x,
                       const float* __restrict__ ve1_w, const float* __restrict__ ve1_b,
                       const float* __restrict__ ff1_w, const float* __restrict__ ff2_w) {
    __shared__ float sh[256];
    const float4 z4 = {0.f, 0.f, 0.f, 0.f};
    const float4 o4 = {1.f, 1.f, 1.f, 1.f};
    int bid = blockIdx.x;
    if (bid < 256) {
        int i = bid * 256 + threadIdx.x;
        *(float4*)&ws[OF_AGGCO + i * 4] = z4;
    } else if (bid < 259) {
        int i = (bid - 256) * 256 + threadIdx.x;
        if (i < 512) *(float4*)&ws[OF_STATS + i * 4] = z4;
        else if (i < 640) *(float4*)&ws[OF_PSLOT + (i - 512) * 4] = z4;
    } else if (bid < 267) {
        int i = (bid - 259) * 256 + threadIdx.x;
        *(float4*)&ws[OF_DEGCO + i * 4] = o4;      // degco+deggo contiguous 8192
    } else if (bid < 395) {
        dev_vae_he(bid - 267, x, ve1_w, ve1_b, ws + OF_HE, sh);
    } else {
        int i = (bid - 395) * 256 + threadIdx.x;   // 256 blocks -> 65536
        ushort_t* W1b = (ushort_t*)(ws + OF_W1B);
        ushort_t* W2b = (ushort_t*)(ws + OF_W2B);
        if (i < 32768) W1b[i] = f2b(ff1_w[i]);
        else W2b[i - 32768] = f2b(ff2_w[i - 32768]);
    }
}

// K2: edge_deg co(320) | edge_deg go(320) | cs_part gene_emb(256) | vae_mid(1)
__global__ void k_fat2(float* ws, const int* __restrict__ ei_co, const float* __restrict__ w_co,
                       const int* __restrict__ ei_go, const float* __restrict__ w_go,
                       const float* __restrict__ gene_emb,
                       const float* __restrict__ vmu_w, const float* __restrict__ vmu_b,
                       const float* __restrict__ vlv_w, const float* __restrict__ vlv_b,
                       const float* __restrict__ vd1_w, const float* __restrict__ vd1_b,
                       const float* __restrict__ veps, float* klout) {
    __shared__ float sh[512];
    int bid = blockIdx.x;
    if (bid < 320) dev_edge_deg(bid, ei_co, w_co, ws + OF_DEGCO, E1N);
    else if (bid < 640) dev_edge_deg(bid - 320, ei_go, w_go, ws + OF_DEGGO, E2N);
    else if (bid < 896) dev_cs_part(bid - 640, gene_emb, GG, ws + OF_STATS, ws + OF_STATS + 128, sh);
    else dev_vae_mid(ws + OF_HE, vmu_w, vmu_b, vlv_w, vlv_b, vd1_w, vd1_b, veps,
                     ws + OF_HDC, klout, sh);
}

// K3: edge_agg(20480) | pert_edges(320)
__global__ void k_fat3(float* ws, const int* __restrict__ ei_co, const float* __restrict__ w_co,
                       const float* __restrict__ emb_pos, const int* __restrict__ pidx,
                       const int* __restrict__ ei_go, const float* __restrict__ w_go,
                       const float* __restrict__ pert_tbl) {
    int bid = blockIdx.x;
    if (bid < 20480) dev_edge_agg(bid, ei_co, w_co, ws + OF_DEGCO, emb_pos, ws + OF_AGGCO);
    else dev_pert_edges(bid - 20480, pidx, ei_go, w_go, ws + OF_DEGGO, pert_tbl, ws + OF_PSLOT);
}

// K4: base_combine(1024) | pert_mlp(1)
__global__ void k_fat4(float* ws, const float* __restrict__ gene_emb,
                       const float* __restrict__ emb_pos,
                       const float* __restrict__ sg_co_w, const float* __restrict__ sg_co_b,
                       const float* __restrict__ bn_emb_g, const float* __restrict__ bn_emb_b,
                       const int* __restrict__ pidx, const float* __restrict__ pert_tbl,
                       const float* __restrict__ gw, const float* __restrict__ gb,
                       const float* __restrict__ w1, const float* __restrict__ b1,
                       const float* __restrict__ g1, const float* __restrict__ be1,
                       const float* __restrict__ w2, const float* __restrict__ b2,
                       const float* __restrict__ g2, const float* __restrict__ be2) {
    __shared__ float sh[4416];
    int bid = blockIdx.x;
    if (bid < 1024)
        dev_base_combine(bid, gene_emb, ws + OF_AGGCO, emb_pos, ws + OF_DEGCO,
                         sg_co_w, sg_co_b, ws + OF_STATS, ws + OF_STATS + 128,
                         bn_emb_g, bn_emb_b, ws + OF_BASEIN, sh);
    else
        dev_pert_mlp(ws + OF_PSLOT, pidx, ws + OF_DEGGO, pert_tbl, gw, gb,
                     w1, b1, g1, be1, w2, b2, g2, be2, ws + OF_ETOT, sh);
}

// ================= gemm64 (fp32, for etv/rw chain) =================
__launch_bounds__(256)
__global__ void k_gemm64(const float* __restrict__ X, const float* __restrict__ W,
                         const float* __restrict__ bias, float* __restrict__ Y,
                         int Cin, int Cout,
                         const float* __restrict__ bnsum, const float* __restrict__ bnsq,
                         const float* __restrict__ bng, const float* __restrict__ bnb,
                         float invN, int relu_in,
                         float* __restrict__ outsum, float* __restrict__ outsq) {
    __shared__ float Xs[64][66];
    __shared__ float Ws[64][66];
    __shared__ float bsc[64], bsh[64];
    const int t = threadIdx.x;
    const int row0 = blockIdx.x * 64, cb = blockIdx.y * 64;
    const int tx = t & 15, ty = t >> 4;
    const int c0 = tx * 4, r0 = ty * 4;
    float acc[4][4];
    #pragma unroll
    for (int j = 0; j < 4; j++)
        #pragma unroll
        for (int i = 0; i < 4; i++) acc[j][i] = 0.f;

    for (int k0 = 0; k0 < Cin; k0 += 64) {
        __syncthreads();
        if (t < 64) {
            float sc = 1.f, sh = 0.f;
            if (bnsum) {
                int c = k0 + t;
                float m = bnsum[c] * invN;
                float is_ = rsqrtf(bnsq[c] * invN - m * m + BNEPS);
                sc = is_ * bng[c]; sh = bnb[c] - m * sc;
            }
            bsc[t] = sc; bsh[t] = sh;
        }
        __syncthreads();
        for (int i = t; i < 1024; i += 256) {
            int r = i >> 4, kq = (i & 15) * 4;
            float4 v = *(const float4*)&X[(size_t)(row0 + r) * Cin + k0 + kq];
            float e0 = v.x * bsc[kq] + bsh[kq];
            float e1 = v.y * bsc[kq + 1] + bsh[kq + 1];
            float e2 = v.z * bsc[kq + 2] + bsh[kq + 2];
            float e3 = v.w * bsc[kq + 3] + bsh[kq + 3];
            if (relu_in) {
                e0 = fmaxf(e0, 0.f); e1 = fmaxf(e1, 0.f);
                e2 = fmaxf(e2, 0.f); e3 = fmaxf(e3, 0.f);
            }
            Xs[r][kq] = e0; Xs[r][kq + 1] = e1; Xs[r][kq + 2] = e2; Xs[r][kq + 3] = e3;
            float4 wv = *(const float4*)&W[(size_t)(cb + r) * Cin + k0 + kq];
            Ws[r][kq] = wv.x; Ws[r][kq + 1] = wv.y; Ws[r][kq + 2] = wv.z; Ws[r][kq + 3] = wv.w;
        }
        __syncthreads();
        #pragma unroll 4
        for (int k = 0; k < 64; k += 2) {
            float2 a[4], b[4];
            #pragma unroll
            for (int j = 0; j < 4; j++) a[j] = *(const float2*)&Xs[r0 + j][k];
            #pragma unroll
            for (int i = 0; i < 4; i++) b[i] = *(const float2*)&Ws[c0 + i][k];
            #pragma unroll
            for (int j = 0; j < 4; j++)
                #pragma unroll
                for (int i = 0; i < 4; i++)
                    acc[j][i] += a[j].x * b[i].x + a[j].y * b[i].y;
        }
    }
    float4 bi = *(const float4*)&bias[cb + c0];
    float scol[4] = {0.f, 0.f, 0.f, 0.f}, qcol[4] = {0.f, 0.f, 0.f, 0.f};
    #pragma unroll
    for (int j = 0; j < 4; j++) {
        float4 o;
        o.x = acc[j][0] + bi.x; o.y = acc[j][1] + bi.y;
        o.z = acc[j][2] + bi.z; o.w = acc[j][3] + bi.w;
        *(float4*)&Y[(size_t)(row0 + r0 + j) * Cout + cb + c0] = o;
        scol[0] += o.x; scol[1] += o.y; scol[2] += o.z; scol[3] += o.w;
        qcol[0] += o.x * o.x; qcol[1] += o.y * o.y;
        qcol[2] += o.z * o.z; qcol[3] += o.w * o.w;
    }
    if (outsum) {
        __syncthreads();
        #pragma unroll
        for (int i = 0; i < 4; i++) { Xs[ty][c0 + i] = scol[i]; Ws[ty][c0 + i] = qcol[i]; }
        __syncthreads();
        if (t < 64) {
            float ss = 0.f, qq = 0.f;
            #pragma unroll
            for (int r = 0; r < 16; r++) { ss += Xs[r][t]; qq += Ws[r][t]; }
            atomicAdd(&outsum[cb + t], ss);
            atomicAdd(&outsq[cb + t], qq);
        }
    }
}

// ================= fused QKV gemm: BN(yrw2) @ ain_w^T + b -> bf16 Qb/Kb/Vf =================
__launch_bounds__(256)
__global__ void k_gemm_qkv(const float* __restrict__ X, const float* __restrict__ W,
                           const float* __restrict__ bias,
                           const float* __restrict__ bnsum, const float* __restrict__ bnsq,
                           const float* __restrict__ bng, const float* __restrict__ bnb,
                           ushort_t* __restrict__ Qb, ushort_t* __restrict__ Kb,
                           ushort_t* __restrict__ Vf) {
    __shared__ float Xs[64][66];
    __shared__ float Ws[64][66];
    __shared__ float bsc[64], bsh[64];
    const int t = threadIdx.x;
    const int row0 = blockIdx.x * 64, yb = blockIdx.y, cb = yb * 64;
    const int tx = t & 15, ty = t >> 4;
    const int c0 = tx * 4, r0 = ty * 4;
    const float invN = 1.0f / (float)(BB * GG);
    if (t < 64) {
        float m = bnsum[t] * invN;
        float is_ = rsqrtf(bnsq[t] * invN - m * m + BNEPS);
        float sc = is_ * bng[t];
        bsc[t] = sc; bsh[t] = bnb[t] - m * sc;
    }
    __syncthreads();
    for (int i = t; i < 1024; i += 256) {
        int r = i >> 4, kq = (i & 15) * 4;
        float4 v = *(const float4*)&X[(size_t)(row0 + r) * 64 + kq];
        Xs[r][kq] = v.x * bsc[kq] + bsh[kq];
        Xs[r][kq + 1] = v.y * bsc[kq + 1] + bsh[kq + 1];
        Xs[r][kq + 2] = v.z * bsc[kq + 2] + bsh[kq + 2];
        Xs[r][kq + 3] = v.w * bsc[kq + 3] + bsh[kq + 3];
        float4 wv = *(const float4*)&W[(size_t)(cb + r) * 64 + kq];
        Ws[r][kq] = wv.x; Ws[r][kq + 1] = wv.y; Ws[r][kq + 2] = wv.z; Ws[r][kq + 3] = wv.w;
    }
    __syncthreads();
    float acc[4][4];
    #pragma unroll
    for (int j = 0; j < 4; j++)
        #pragma unroll
        for (int i = 0; i < 4; i++) acc[j][i] = 0.f;
    #pragma unroll 4
    for (int k = 0; k < 64; k += 2) {
        float2 a[4], b[4];
        #pragma unroll
        for (int j = 0; j < 4; j++) a[j] = *(const float2*)&Xs[r0 + j][k];
        #pragma unroll
        for (int i = 0; i < 4; i++) b[i] = *(const float2*)&Ws[c0 + i][k];
        #pragma unroll
        for (int j = 0; j < 4; j++)
            #pragma unroll
            for (int i = 0; i < 4; i++)
                acc[j][i] += a[j].x * b[i].x + a[j].y * b[i].y;
    }
    float4 bi = *(const float4*)&bias[cb + c0];
    const int b2 = row0 >> 12, tile = (row0 & 4095) >> 6;
    if (yb < 2) {
        ushort_t* Dst = (yb == 0) ? Qb : Kb;
        const float sc2 = (yb == 0) ? QPRE : 1.0f;
        const int h = c0 >> 5, d = c0 & 31;
        #pragma unroll
        for (int j = 0; j < 4; j++) {
            union { ushort_t u[4]; uint2 v; } pk;
            pk.u[0] = f2b((acc[j][0] + bi.x) * sc2);
            pk.u[1] = f2b((acc[j][1] + bi.y) * sc2);
            pk.u[2] = f2b((acc[j][2] + bi.z) * sc2);
            pk.u[3] = f2b((acc[j][3] + bi.w) * sc2);
            int g = (row0 & 4095) + r0 + j;
            *(uint2*)&Dst[((size_t)(b2 * 2 + h) * GG + g) * 32 + d] = pk.v;
        }
    } else {
        __syncthreads();
        #pragma unroll
        for (int j = 0; j < 4; j++) {
            Xs[r0 + j][c0] = acc[j][0] + bi.x;
            Xs[r0 + j][c0 + 1] = acc[j][1] + bi.y;
            Xs[r0 + j][c0 + 2] = acc[j][2] + bi.z;
            Xs[r0 + j][c0 + 3] = acc[j][3] + bi.w;
        }
        __syncthreads();
        #pragma unroll
        for (int h = 0; h < 2; h++) {
            union { ushort_t u[8]; uint4 v; } pk;
            #pragma unroll
            for (int j = 0; j < 8; j++) {
                int idx = t * 8 + j;
                int g2 = idx >> 8, L = (idx >> 2) & 63, i = idx & 3;
                int key = (g2 >> 1) * 16 + ((L >> 4) << 2) + i;
                int d = ((g2 & 1) << 4) + (L & 15);
                pk.u[j] = f2b(Xs[key][h * 32 + d]);
            }
            *(uint4*)&Vf[((size_t)((b2 * 2 + h) * 64 + tile)) * 2048 + t * 8] = pk.v;
        }
    }
}

// flat_pre = bn(y2) + etot, fused column stats
__global__ void k_flatpre(const float* __restrict__ y2, const float* __restrict__ etot,
                          const float* __restrict__ bsum, const float* __restrict__ bsq,
                          const float* __restrict__ g2, const float* __restrict__ b2,
                          float* __restrict__ out,
                          float* __restrict__ osum, float* __restrict__ osq) {
    int t = threadIdx.x;
    int h = t & 63, ro = t >> 6;
    int row0 = blockIdx.x * 64;
    const float invN = 1.0f / (float)GG;
    float m = bsum[h] * invN;
    float is_ = rsqrtf(bsq[h] * invN - m * m + BNEPS);
    float sc = is_ * g2[h];
    float sh = b2[h] - m * sc;
    float s = 0.f, q = 0.f;
    for (int r = row0 + ro; r < row0 + 64; r += 4) {
        int b = r >> 12, gh = (r & 4095) * 64 + h;
        float v = y2[gh] * sc + sh + etot[b * 64 + h];
        out[r * 64 + h] = v;
        s += v; q += v * v;
    }
    __shared__ float ls[256], lq[256];
    ls[t] = s; lq[t] = q;
    __syncthreads();
    if (t < 64) {
        s = ls[t] + ls[t + 64] + ls[t + 128] + ls[t + 192];
        q = lq[t] + lq[t + 64] + lq[t + 128] + lq[t + 192];
        atomicAdd(&osum[t], s);
        atomicAdd(&osq[t], q);
    }
}

// ---- MFMA flash attention, 4-bh per block (mask register reuse, 2 blocks/CU) ----
__launch_bounds__(512, 4)
__global__ void k_attn_mfma(const ushort_t* __restrict__ Qb, const ushort_t* __restrict__ Kb,
                            const ushort_t* __restrict__ Vf, const float* __restrict__ mask,
                            float* __restrict__ opA, float* __restrict__ opB,
                            float* __restrict__ Lp) {
    __shared__ ushort_t Kl[2][4][2048];
    __shared__ ushort_t Vl[2][4][2048];
    const int split = blockIdx.y;
    const int bh0 = blockIdx.z * 4;
    const int q0 = blockIdx.x * 64;
    const int kstart = split * (GG / 4), kend = kstart + (GG / 4);
    const int t = threadIdx.x;
    const int lane = t & 63, w = t >> 6;
    const int qg = w >> 1, kh = w & 1;
    const int l15 = lane & 15, quad = lane >> 4;
    const int i2a = kh * 2, i2b = kh * 2 + 1;

    sh8 qf[4];
    #pragma unroll
    for (int bh = 0; bh < 4; bh++)
        qf[bh] = *(const sh8*)&Qb[((size_t)(bh0 + bh) * GG + q0 + qg * 16 + l15) * 32 + quad * 8];
    const float* mrow = mask + (size_t)(q0 + qg * 16 + l15) * GG + quad * 4;

    auto stage = [&](int buf, int k0) {
        #pragma unroll
        for (int s = 0; s < 2; s++) {
            int idx = s * 512 + t;
            int bh = idx >> 8, c = idx & 255;
            int key = ((c >> 6) << 4) + (c & 15);
            int chunk = (c >> 4) & 3;
            gld16(Kb + ((size_t)(bh0 + bh) * GG + k0 + key) * 32 + chunk * 8,
                  &Kl[buf][bh][c * 8]);
            gld16(Vf + ((size_t)((bh0 + bh) * 64 + (k0 >> 6))) * 2048 + c * 8,
                  &Vl[buf][bh][c * 8]);
        }
    };
    stage(0, kstart);

    f4 O0[4], O1[4];
    float ls[4];
    #pragma unroll
    for (int bh = 0; bh < 4; bh++) {
        O0[bh] = f4{0.f, 0.f, 0.f, 0.f};
        O1[bh] = f4{0.f, 0.f, 0.f, 0.f};
        ls[bh] = 0.f;
    }

    for (int k0 = kstart; k0 < kend; k0 += 64) {
        const int cur = ((k0 - kstart) >> 6) & 1;
        __syncthreads();
        if (k0 + 64 < kend) stage(cur ^ 1, k0 + 64);
        float4 mva = *(const float4*)&mrow[k0 + i2a * 16];
        float4 mvb = *(const float4*)&mrow[k0 + i2b * 16];
        #pragma unroll
        for (int bh = 0; bh < 4; bh++) {
            sh8 kfa = *(const sh8*)&Kl[cur][bh][(i2a * 64 + lane) * 8];
            sh8 kfb = *(const sh8*)&Kl[cur][bh][(i2b * 64 + lane) * 8];
            f4 z = {0.f, 0.f, 0.f, 0.f};
            f4 sa = __builtin_amdgcn_mfma_f32_16x16x32_bf16(kfa, qf[bh], z, 0, 0, 0);
            f4 sb = __builtin_amdgcn_mfma_f32_16x16x32_bf16(kfb, qf[bh], z, 0, 0, 0);
            {
                float p0 = exp2f(fmaf(mva.x, LOG2E, sa[0]));
                float p1 = exp2f(fmaf(mva.y, LOG2E, sa[1]));
                float p2 = exp2f(fmaf(mva.z, LOG2E, sa[2]));
                float p3 = exp2f(fmaf(mva.w, LOG2E, sa[3]));
                ls[bh] += (p0 + p1) + (p2 + p3);
                union { __hip_bfloat162 h2[2]; sh4 v; } pkp;
                pkp.h2[0] = __float22bfloat162_rn(float2{p0, p1});
                pkp.h2[1] = __float22bfloat162_rn(float2{p2, p3});
                sh4 vf0 = *(const sh4*)&Vl[cur][bh][((i2a * 2 + 0) * 64 + lane) * 4];
                sh4 vf1 = *(const sh4*)&Vl[cur][bh][((i2a * 2 + 1) * 64 + lane) * 4];
                O0[bh] = MFMA16(pkp.v, vf0, O0[bh]);
                O1[bh] = MFMA16(pkp.v, vf1, O1[bh]);
            }
            {
                float p0 = exp2f(fmaf(mvb.x, LOG2E, sb[0]));
                float p1 = exp2f(fmaf(mvb.y, LOG2E, sb[1]));
                float p2 = exp2f(fmaf(mvb.z, LOG2E, sb[2]));
                float p3 = exp2f(fmaf(mvb.w, LOG2E, sb[3]));
                ls[bh] += (p0 + p1) + (p2 + p3);
                union { __hip_bfloat162 h2[2]; sh4 v; } pkp;
                pkp.h2[0] = __float22bfloat162_rn(float2{p0, p1});
                pkp.h2[1] = __float22bfloat162_rn(float2{p2, p3});
                sh4 vf0 = *(const sh4*)&Vl[cur][bh][((i2b * 2 + 0) * 64 + lane) * 4];
                sh4 vf1 = *(const sh4*)&Vl[cur][bh][((i2b * 2 + 1) * 64 + lane) * 4];
                O0[bh] = MFMA16(pkp.v, vf0, O0[bh]);
                O1[bh] = MFMA16(pkp.v, vf1, O1[bh]);
            }
        }
    }
    #pragma unroll
    for (int bh = 0; bh < 4; bh++) {
        ls[bh] += __shfl_xor(ls[bh], 16, 64);
        ls[bh] += __shfl_xor(ls[bh], 32, 64);
    }
    __syncthreads();
    float* Ox = (float*)&Kl[0][0][0];
    float* Lx = (float*)&Vl[0][0][0];
    if (kh == 0) {
        #pragma unroll
        for (int bh = 0; bh < 4; bh++) {
            #pragma unroll
            for (int r = 0; r < 4; r++) {
                int ql = qg * 16 + quad * 4 + r;
                Ox[(bh * 64 + ql) * 32 + l15] = O0[bh][r];
                Ox[(bh * 64 + ql) * 32 + l15 + 16] = O1[bh][r];
            }
            if (quad == 0) Lx[bh * 64 + qg * 16 + l15] = ls[bh];
        }
    }
    __syncthreads();
    if (kh == 1) {
        float* op = (split < 3) ? (opA + (size_t)split * OPS) : opB;
        #pragma unroll
        for (int bh = 0; bh < 4; bh++) {
            int gbh = bh0 + bh;
            #pragma unroll
            for (int r = 0; r < 4; r++) {
                int ql = qg * 16 + quad * 4 + r;
                size_t o = ((size_t)gbh * GG + q0 + ql) * 32 + l15;
                op[o] = O0[bh][r] + Ox[(bh * 64 + ql) * 32 + l15];
                op[o + 16] = O1[bh][r] + Ox[(bh * 64 + ql) * 32 + l15 + 16];
            }
            if (quad == 0)
                Lp[split * 32768 + gbh * GG + q0 + qg * 16 + l15] =
                    ls[bh] + Lx[bh * 64 + qg * 16 + l15];
        }
    }
}

// combine splits + att = ctx @ Wout^T + b ; h1 = LN(bn(yrw2) + att); also emit h1b frag-bf16
__global__ void k_attn_out_ln(const float* __restrict__ opA, const float* __restrict__ opB,
                              const float* __restrict__ Lp, const float* __restrict__ yrw2,
                              const float* __restrict__ W, const float* __restrict__ bias,
                              const float* __restrict__ bsum, const float* __restrict__ bsq,
                              const float* __restrict__ bg, const float* __restrict__ bb,
                              const float* __restrict__ lg, const float* __restrict__ lb,
                              float* __restrict__ h1, ushort_t* __restrict__ h1b) {
    __shared__ float Wt[64][65];
    __shared__ float Cs[16][65];
    __shared__ ushort_t Hs[16][64];
    int t = threadIdx.x;
    int row0 = blockIdx.x * 16;
    for (int i = t; i < 4096; i += 256) Wt[i & 63][i >> 6] = W[i];
    {
        int col = t & 63, rl = t >> 6;
        int hh = col >> 5, d = col & 31;
        #pragma unroll
        for (int jj = 0; jj < 4; jj++) {
            int row = row0 + rl + jj * 4;
            int b = row >> 12, q = row & 4095;
            int bhq = (b * 2 + hh) * GG + q;
            size_t oi = (size_t)bhq * 32 + d;
            float num = opA[oi] + opA[OPS + oi] + opA[2 * OPS + oi] + opB[oi];
            float den = Lp[bhq] + Lp[32768 + bhq] + Lp[65536 + bhq] + Lp[98304 + bhq];
            Cs[rl + jj * 4][col] = num / den;
        }
    }
    __syncthreads();
    int rr = t >> 6, lane = t & 63;
    const float invN = 1.0f / (float)(BB * GG);
    float m = bsum[lane] * invN;
    float is_ = rsqrtf(bsq[lane] * invN - m * m + BNEPS);
    #pragma unroll
    for (int j = 0; j < 4; j++) {
        int lrow = rr * 4 + j;
        int row = row0 + lrow;
        float acc = bias[lane];
        const float* cr = Cs[lrow];
        #pragma unroll 8
        for (int k = 0; k < 64; k++) acc += cr[k] * Wt[k][lane];
        float ov = (yrw2[row * 64 + lane] - m) * is_ * bg[lane] + bb[lane];
        float v = ov + acc;
        float s = v;
        for (int o = 32; o > 0; o >>= 1) s += __shfl_xor(s, o, 64);
        float mean = s * (1.f / 64.f);
        float d = v - mean;
        float sq = d * d;
        for (int o = 32; o > 0; o >>= 1) sq += __shfl_xor(sq, o, 64);
        float inv = rsqrtf(sq * (1.f / 64.f) + BNEPS);
        float hv = d * inv * lg[lane] + lb[lane];
        h1[row * 64 + lane] = hv;
        Hs[lrow][lane] = f2b(hv);
    }
    __syncthreads();
    if (t < 128) {
        int kt = t >> 6, lane6 = t & 63;
        int q2 = (lane6 >> 4) & 3, r15 = lane6 & 15;
        union { ushort_t u[8]; uint4 v; } pk;
        #pragma unroll
        for (int j = 0; j < 8; j++) pk.u[j] = Hs[r15][kt * 32 + q2 * 8 + j];
        *(uint4*)&h1b[((size_t)blockIdx.x * 2 + kt) * 512 + lane6 * 8] = pk.v;
    }
}

// ================= FFN layer 1: fft = relu(h1 @ W1^T + b1), bf16 MFMA =================
__launch_bounds__(256)
__global__ void k_ffn1(const ushort_t* __restrict__ h1b, const ushort_t* __restrict__ W1b,
                       const float* __restrict__ b1, ushort_t* __restrict__ fft) {
    __shared__ ushort_t Xl[4096];
    __shared__ ushort_t Wl[4096];
    const int t = threadIdx.x;
    const int rowblock = blockIdx.x, colblock = blockIdx.y;
    const int cb = colblock * 64;
    const int lane = t & 63, w = t >> 6;
    const int l15 = lane & 15, quad = lane >> 4;
    #pragma unroll
    for (int kt = 0; kt < 2; kt++) {
        gld16(h1b + (size_t)(((rowblock * 4 + w) * 2 + kt) * 512 + lane * 8),
              &Xl[(w * 2 + kt) * 512 + lane * 8]);
        gld16(W1b + (size_t)((cb + w * 16 + l15) * 64 + kt * 32 + quad * 8),
              &Wl[(w * 2 + kt) * 512 + lane * 8]);
    }
    __syncthreads();
    sh8 xf0 = *(const sh8*)&Xl[(w * 2 + 0) * 512 + lane * 8];
    sh8 xf1 = *(const sh8*)&Xl[(w * 2 + 1) * 512 + lane * 8];
    #pragma unroll
    for (int c = 0; c < 4; c++) {
        sh8 wf0 = *(const sh8*)&Wl[(c * 2 + 0) * 512 + lane * 8];
        sh8 wf1 = *(const sh8*)&Wl[(c * 2 + 1) * 512 + lane * 8];
        f4 z = {0.f, 0.f, 0.f, 0.f};
        f4 acc = __builtin_amdgcn_mfma_f32_16x16x32_bf16(wf0, xf0, z, 0, 0, 0);
        acc = __builtin_amdgcn_mfma_f32_16x16x32_bf16(wf1, xf1, acc, 0, 0, 0);
        float4 bv = *(const float4*)&b1[cb + c * 16 + quad * 4];
        union { ushort_t u[4]; uint2 v; } pk;
        pk.u[0] = f2b(fmaxf(acc[0] + bv.x, 0.f));
        pk.u[1] = f2b(fmaxf(acc[1] + bv.y, 0.f));
        pk.u[2] = f2b(fmaxf(acc[2] + bv.z, 0.f));
        pk.u[3] = f2b(fmaxf(acc[3] + bv.w, 0.f));
        int kt512 = colblock * 2 + (c >> 1);
        int quadp = (c & 1) * 2 + (quad >> 1);
        int j0 = (quad & 1) * 4;
        size_t o = ((size_t)(((rowblock * 4 + w) * 16 + kt512) * 64 + quadp * 16 + l15)) * 8 + j0;
        *(uint2*)&fft[o] = pk.v;
    }
}

// ================= FFN layer 2 + LN2 + per-gene head + recon (fused final) =================
__launch_bounds__(256)
__global__ void k_ffn2(const ushort_t* __restrict__ fft, const ushort_t* __restrict__ W2b,
                       const float* __restrict__ b2, const float* __restrict__ h1,
                       const float* __restrict__ lg, const float* __restrict__ lb,
                       const float* __restrict__ indvw, const float* __restrict__ indvb,
                       const float* __restrict__ hdc, const float* __restrict__ d2w,
                       const float* __restrict__ d2b, const float* __restrict__ x,
                       float* __restrict__ outp) {
    __shared__ ushort_t Xl[2][4096];
    __shared__ ushort_t Wl[2][4096];
    const int t = threadIdx.x;
    const int rowblock = blockIdx.x;
    const int lane = t & 63, w = t >> 6;
    const int l15 = lane & 15, quad = lane >> 4;

    #pragma unroll
    for (int kt = 0; kt < 2; kt++) {
        gld16(fft + (size_t)((((rowblock * 4 + w) * 16) + kt) * 64 + lane) * 8,
              &Xl[0][(w * 2 + kt) * 512 + lane * 8]);
        gld16(W2b + (size_t)((w * 16 + l15) * 512 + kt * 32 + quad * 8),
              &Wl[0][(w * 2 + kt) * 512 + lane * 8]);
    }
    f4 acc[4];
    #pragma unroll
    for (int c = 0; c < 4; c++) acc[c] = f4{0.f, 0.f, 0.f, 0.f};

    for (int k0 = 0; k0 < 512; k0 += 64) {
        const int cur = (k0 >> 6) & 1;
        __syncthreads();
        if (k0 + 64 < 512) {
            const int nxt = cur ^ 1;
            const int ktb = (k0 + 64) >> 5;
            #pragma unroll
            for (int kt = 0; kt < 2; kt++) {
                gld16(fft + (size_t)((((rowblock * 4 + w) * 16) + ktb + kt) * 64 + lane) * 8,
                      &Xl[nxt][(w * 2 + kt) * 512 + lane * 8]);
                gld16(W2b + (size_t)((w * 16 + l15) * 512 + k0 + 64 + kt * 32 + quad * 8),
                      &Wl[nxt][(w * 2 + kt) * 512 + lane * 8]);
            }
        }
        #pragma unroll
        for (int kt = 0; kt < 2; kt++) {
            sh8 xf = *(const sh8*)&Xl[cur][(w * 2 + kt) * 512 + lane * 8];
            #pragma unroll
            for (int c = 0; c < 4; c++) {
                sh8 wf = *(const sh8*)&Wl[cur][(c * 2 + kt) * 512 + lane * 8];
                acc[c] = __builtin_amdgcn_mfma_f32_16x16x32_bf16(wf, xf, acc[c], 0, 0, 0);
            }
        }
    }
    const int row = rowblock * 64 + w * 16 + l15;
    const int b = row >> 12, g = row & 4095;
    float v[4][4];
    float s = 0.f, sq = 0.f;
    #pragma unroll
    for (int c = 0; c < 4; c++) {
        float4 bv = *(const float4*)&b2[c * 16 + quad * 4];
        float4 hv = *(const float4*)&h1[(size_t)row * 64 + c * 16 + quad * 4];
        v[c][0] = hv.x + acc[c][0] + bv.x;
        v[c][1] = hv.y + acc[c][1] + bv.y;
        v[c][2] = hv.z + acc[c][2] + bv.z;
        v[c][3] = hv.w + acc[c][3] + bv.w;
        #pragma unroll
        for (int i = 0; i < 4; i++) { s += v[c][i]; sq += v[c][i] * v[c][i]; }
    }
    s += __shfl_xor(s, 16, 64);  s += __shfl_xor(s, 32, 64);
    sq += __shfl_xor(sq, 16, 64); sq += __shfl_xor(sq, 32, 64);
    float mean = s * (1.f / 64.f);
    float inv = rsqrtf(sq * (1.f / 64.f) - mean * mean + BNEPS);
    float pd = 0.f;
    #pragma unroll
    for (int c = 0; c < 4; c++) {
        float4 lgv = *(const float4*)&lg[c * 16 + quad * 4];
        float4 lbv = *(const float4*)&lb[c * 16 + quad * 4];
        float4 iwv = *(const float4*)&indvw[(size_t)g * 64 + c * 16 + quad * 4];
        pd += ((v[c][0] - mean) * inv * lgv.x + lbv.x) * iwv.x;
        pd += ((v[c][1] - mean) * inv * lgv.y + lbv.y) * iwv.y;
        pd += ((v[c][2] - mean) * inv * lgv.z + lbv.z) * iwv.z;
        pd += ((v[c][3] - mean) * inv * lgv.w + lbv.w) * iwv.w;
    }
    float rc = 0.f;
    #pragma unroll
    for (int i = 0; i < 8; i++)
        rc += hdc[b * 32 + quad * 8 + i] * d2w[(size_t)g * 32 + quad * 8 + i];
    pd += __shfl_xor(pd, 16, 64); pd += __shfl_xor(pd, 32, 64);
    rc += __shfl_xor(rc, 16, 64); rc += __shfl_xor(rc, 32, 64);
    if (quad == 0) {
        float recon = rc + d2b[g];
        if (x[row] == 0.f) recon = 0.f;
        outp[row] = pd + indvb[g] + recon;
    }
}

extern "C" void kernel_launch(void* const* d_in, const int* in_sizes, int n_in,
                              void* d_out, int out_size, void* d_ws, size_t ws_size,
                              hipStream_t stream) {
    const float* x        = (const float*)d_in[0];
    const int*   pert_idx = (const int*)  d_in[1];
    const float* mask     = (const float*)d_in[2];
    const int*   ei_co    = (const int*)  d_in[3];
    const float* w_co     = (const float*)d_in[4];
    const int*   ei_go    = (const int*)  d_in[5];
    const float* w_go     = (const float*)d_in[6];
    const float* gene_emb = (const float*)d_in[7];
    const float* emb_pos  = (const float*)d_in[8];
    const float* pert_tbl = (const float*)d_in[9];
    const float* sg_co_w  = (const float*)d_in[10];
    const float* sg_co_b  = (const float*)d_in[11];
    const float* sg_go_w  = (const float*)d_in[12];
    const float* sg_go_b  = (const float*)d_in[13];
    const float* bn_emb_g = (const float*)d_in[14];
    const float* bn_emb_b = (const float*)d_in[15];
    const float* etv1_w   = (const float*)d_in[16];
    const float* etv1_b   = (const float*)d_in[17];
    const float* etv1_g   = (const float*)d_in[18];
    const float* etv1_be  = (const float*)d_in[19];
    const float* etv2_w   = (const float*)d_in[20];
    const float* etv2_b   = (const float*)d_in[21];
    const float* etv2_g   = (const float*)d_in[22];
    const float* etv2_be  = (const float*)d_in[23];
    const float* pf1_w    = (const float*)d_in[24];
    const float* pf1_b    = (const float*)d_in[25];
    const float* pf1_g    = (const float*)d_in[26];
    const float* pf1_be   = (const float*)d_in[27];
    const float* pf2_w    = (const float*)d_in[28];
    const float* pf2_b    = (const float*)d_in[29];
    const float* pf2_g    = (const float*)d_in[30];
    const float* pf2_be   = (const float*)d_in[31];
    const float* rw1_w    = (const float*)d_in[32];
    const float* rw1_b    = (const float*)d_in[33];
    const float* rw1_g    = (const float*)d_in[34];
    const float* rw1_be   = (const float*)d_in[35];
    const float* rw2_w    = (const float*)d_in[36];
    const float* rw2_b    = (const float*)d_in[37];
    const float* rw2_g    = (const float*)d_in[38];
    const float* rw2_be   = (const float*)d_in[39];
    const float* bnpb_g   = (const float*)d_in[40];
    const float* bnpb_b   = (const float*)d_in[41];
    const float* ain_w    = (const float*)d_in[42];
    const float* ain_b    = (const float*)d_in[43];
    const float* aout_w   = (const float*)d_in[44];
    const float* aout_b   = (const float*)d_in[45];
    const float* ln1_g    = (const float*)d_in[46];
    const float* ln1_b    = (const float*)d_in[47];
    const float* ff1_w    = (const float*)d_in[48];
    const float* ff1_b    = (const float*)d_in[49];
    const float* ff2_w    = (const float*)d_in[50];
    const float* ff2_b    = (const float*)d_in[51];
    const float* ln2_g    = (const float*)d_in[52];
    const float* ln2_b    = (const float*)d_in[53];
    const float* indv_w   = (const float*)d_in[54];
    const float* indv_b   = (const float*)d_in[55];
    const float* ve1_w    = (const float*)d_in[56];
    const float* ve1_b    = (const float*)d_in[57];
    const float* vmu_w    = (const float*)d_in[58];
    const float* vmu_b    = (const float*)d_in[59];
    const float* vlv_w    = (const float*)d_in[60];
    const float* vlv_b    = (const float*)d_in[61];
    const float* vd1_w    = (const float*)d_in[62];
    const float* vd1_b    = (const float*)d_in[63];
    const float* vd2_w    = (const float*)d_in[64];
    const float* vd2_b    = (const float*)d_in[65];
    const float* veps     = (const float*)d_in[66];

    float* ws   = (float*)d_ws;
    float* outp = (float*)d_out;

    float* stm1 = ws + OF_STATS + 1 * 256; float* sti1 = stm1 + 128;
    float* stm2 = ws + OF_STATS + 2 * 256; float* sti2 = stm2 + 128;
    float* stm3 = ws + OF_STATS + 3 * 256; float* sti3 = stm3 + 128;
    float* stm4 = ws + OF_STATS + 4 * 256; float* sti4 = stm4 + 128;
    float* stm5 = ws + OF_STATS + 5 * 256; float* sti5 = stm5 + 128;

    float* basein = ws + OF_BASEIN;
    float* y1     = ws + OF_Y1;
    float* y2     = ws + OF_Y2;
    float* flat   = ws + OF_FLAT;
    float* yrw1   = ws + OF_RW1;
    float* yrw2   = ws + OF_RW2;
    float* h1     = ws + OF_H1;
    float* opA    = ws + OF_OPA;
    float* opB    = ws + OF_OPB;
    float* Lp     = ws + OF_LP;
    ushort_t* Qb  = (ushort_t*)(ws + OF_QB);
    ushort_t* Kb  = (ushort_t*)(ws + OF_KB);
    ushort_t* Vf  = (ushort_t*)(ws + OF_VF);
    ushort_t* W1b = (ushort_t*)(ws + OF_W1B);
    ushort_t* W2b = (ushort_t*)(ws + OF_W2B);
    ushort_t* h1b = (ushort_t*)(ws + OF_H1B);
    ushort_t* fft = (ushort_t*)(ws + OF_FFT);

    const int NG = BB * GG; // 16384
    const float iG = 1.0f / (float)GG, iNG = 1.0f / (float)NG;

    // K1: zero ws regions (float4), deg=1, vae_he, FFN weight->bf16
    k_fat1<<<651, 256, 0, stream>>>(ws, x, ve1_w, ve1_b, ff1_w, ff2_w);
    // K2: edge degrees, gene_emb stats, vae_mid
    k_fat2<<<897, 256, 0, stream>>>(ws, ei_co, w_co, ei_go, w_go, gene_emb,
                                    vmu_w, vmu_b, vlv_w, vlv_b, vd1_w, vd1_b,
                                    veps, outp + NG);
    // K3: coalesced co edge aggregation + pert edge broadcast scan
    k_fat3<<<20800, 256, 0, stream>>>(ws, ei_co, w_co, emb_pos, pert_idx,
                                      ei_go, w_go, pert_tbl);
    // K4: base_combine + pert MLP
    k_fat4<<<1025, 256, 0, stream>>>(ws, gene_emb, emb_pos, sg_co_w, sg_co_b,
                                     bn_emb_g, bn_emb_b, pert_idx, pert_tbl,
                                     sg_go_w, sg_go_b,
                                     pf1_w, pf1_b, pf1_g, pf1_be,
                                     pf2_w, pf2_b, pf2_g, pf2_be);
    // etv MLP (stats fused into epilogues)
    k_gemm64<<<dim3(GG / 64, 1), 256, 0, stream>>>(basein, etv1_w, etv1_b, y1, 64, 64,
                                                   nullptr, nullptr, nullptr, nullptr, 0.f, 0,
                                                   stm1, sti1);
    k_gemm64<<<dim3(GG / 64, 1), 256, 0, stream>>>(y1, etv2_w, etv2_b, y2, 64, 64,
                                                   stm1, sti1, etv1_g, etv1_be, iG, 1,
                                                   stm2, sti2);
    // fuse + rw MLP
    k_flatpre<<<NG / 64, 256, 0, stream>>>(y2, ws + OF_ETOT, stm2, sti2, etv2_g, etv2_be,
                                           flat, stm3, sti3);
    k_gemm64<<<dim3(NG / 64, 2), 256, 0, stream>>>(flat, rw1_w, rw1_b, yrw1, 64, 128,
                                                   stm3, sti3, bnpb_g, bnpb_b, iNG, 1,
                                                   stm4, sti4);
    k_gemm64<<<dim3(NG / 64, 1), 256, 0, stream>>>(yrw1, rw2_w, rw2_b, yrw2, 128, 64,
                                                   stm4, sti4, rw1_g, rw1_be, iNG, 1,
                                                   stm5, sti5);
    // transformer
    k_gemm_qkv<<<dim3(NG / 64, 3), 256, 0, stream>>>(yrw2, ain_w, ain_b,
                                                     stm5, sti5, rw2_g, rw2_be,
                                                     Qb, Kb, Vf);
    k_attn_mfma<<<dim3(GG / 64, 4, 2), 512, 0, stream>>>(Qb, Kb, Vf, mask, opA, opB, Lp);
    k_attn_out_ln<<<NG / 16, 256, 0, stream>>>(opA, opB, Lp, yrw2, aout_w, aout_b,
                                               stm5, sti5, rw2_g, rw2_be,
                                               ln1_g, ln1_b, h1, h1b);
    // FFN (bf16 MFMA) + fused final
    k_ffn1<<<dim3(NG / 64, FFD / 64), 256, 0, stream>>>(h1b, W1b, ff1_b, fft);
    k_ffn2<<<NG / 64, 256, 0, stream>>>(fft, W2b, ff2_b, h1, ln2_g, ln2_b,
                                        indv_w, indv_b, ws + OF_HDC, vd2_w, vd2_b,
                                        x, outp);
}

// Round 12
// 522.725 us; speedup vs baseline: 1.2377x; 1.0093x over previous
//
#include <hip/hip_runtime.h>
#include <hip/hip_bf16.h>
#include <math.h>

#define GG 4096
#define PP 4096
#define HH 64
#define BB 4
#define E1N 81920
#define E2N 81920
#define FFD 512
#define BNEPS 1e-5f
#define LOG2E 1.44269504088896341f
#define QPRE (0.17677669529663687f * LOG2E)

typedef unsigned short ushort_t;
typedef unsigned int uint_t;
using sh8 = __attribute__((ext_vector_type(8))) short;
using sh4 = __attribute__((ext_vector_type(4))) short;
using f4  = __attribute__((ext_vector_type(4))) float;

#if __has_builtin(__builtin_amdgcn_mfma_f32_16x16x16bf16_1k)
#define MFMA16(a, b, c) __builtin_amdgcn_mfma_f32_16x16x16bf16_1k((a), (b), (c), 0, 0, 0)
#elif __has_builtin(__builtin_amdgcn_mfma_f32_16x16x16_bf16)
#define MFMA16(a, b, c) __builtin_amdgcn_mfma_f32_16x16x16_bf16((a), (b), (c), 0, 0, 0)
#else
static __device__ inline f4 mfma16_asm(sh4 a, sh4 b, f4 c) {
    f4 d;
    asm volatile("v_mfma_f32_16x16x16_bf16 %0, %1, %2, %3"
                 : "=v"(d) : "v"(a), "v"(b), "v"(c));
    return d;
}
#define MFMA16(a, b, c) mfma16_asm((a), (b), (c))
#endif

// ---------------- workspace layout (float offsets) ----------------
#define OF_STATS   0          // 6 slots x 256 (raw sum[128] + sumsq[128])
#define OF_DEGCO   2048
#define OF_DEGGO   6144
#define OF_PSLOT   10240
#define OF_ETOT    10752
#define OF_HDC     11008
#define OF_HE      11136
#define OF_AGGCO   12288      // 4096 x 64
#define OF_BASEIN  274432
#define OF_Y1      536576
#define OF_Y2      798720
#define OF_FLAT    1060864    // 16384 x 64
#define OF_RW1     2109440    // 16384 x 128
#define OF_RW2     4206592    // 16384 x 64
#define OF_OUT     5255168    // 16384 x 64   (attn split 3 partial)
#define OF_QKV     6303744    // (attn splits 0..2 partials; ends 9449472)
#define OF_H1      10498048   // 16384 x 64
// bf16 attention buffers (alias dead fp32 regions)
#define OF_QB      OF_AGGCO   // 8*4096*32 ushort = 524288 floats
#define OF_KB      (OF_AGGCO + 524288)
#define OF_VF      OF_FLAT    // 8*64*2048 ushort = 524288 floats (V frag-order)
// attention k-split partials
#define OF_OPA     OF_QKV
#define OF_OPB     OF_OUT
#define OF_LP      OF_RW1     // 4*8*4096 = 131072
#define OPS        1048576    // split stride in opA (8*4096*32)
// FFN bf16 buffers (dead FFO region 9449472..10498048)
#define OF_W1B     9449472    // 512*64 bf16 = 16384 floats
#define OF_W2B     9465856    // 64*512 bf16 = 16384 floats
#define OF_H1B     9482240    // 16384*64 bf16 = 524288 floats (A-frag order)
// fft bf16 (frag order): FLAT..RW2 region, dead post-attn
#define OF_FFT     OF_FLAT

#define AGGBLKS 1024          // edge_agg blocks (grid-stride)

__device__ inline ushort_t f2b(float f) {
    uint_t u = __builtin_bit_cast(uint_t, f);
    u += 0x7FFFu + ((u >> 16) & 1u);
    return (ushort_t)(u >> 16);
}

__device__ inline void gld16(const void* gptr, void* lptr) {
    __builtin_amdgcn_global_load_lds(
        (const __attribute__((address_space(1))) uint_t*)gptr,
        (__attribute__((address_space(3))) uint_t*)lptr, 16, 0, 0);
}

// ================= device sub-kernels for fat launches =================
__device__ void dev_vae_he(int bid, const float* __restrict__ x, const float* __restrict__ W,
                           const float* __restrict__ bias, float* he, float* sh) {
    int b = bid >> 5, i = bid & 31;
    float s = 0.f;
    for (int g = threadIdx.x; g < 4096; g += 256) s += x[b * 4096 + g] * W[i * 4096 + g];
    sh[threadIdx.x] = s;
    __syncthreads();
    for (int o = 128; o > 0; o >>= 1) {
        if (threadIdx.x < o) sh[threadIdx.x] += sh[threadIdx.x + o];
        __syncthreads();
    }
    if (threadIdx.x == 0) he[b * 32 + i] = fmaxf(sh[0] + bias[i], 0.f);
}

__device__ void dev_vae_mid(const float* __restrict__ he,
                            const float* __restrict__ muw, const float* __restrict__ mub,
                            const float* __restrict__ lvw, const float* __restrict__ lvb,
                            const float* __restrict__ d1w, const float* __restrict__ d1b,
                            const float* __restrict__ eps, float* hdc, float* klout, float* zs) {
    int t = threadIdx.x;
    if (t < 64) {
        int b = t >> 4, l = t & 15;
        float mu = mub[l], lv = lvb[l];
        for (int i = 0; i < 32; i++) {
            float hv = he[b * 32 + i];
            mu += hv * muw[l * 32 + i];
            lv += hv * lvw[l * 32 + i];
        }
        zs[t] = mu + eps[t] * expf(0.5f * lv);
        float kterm = 1.f + lv - mu * mu - expf(lv);
        for (int o = 32; o > 0; o >>= 1) kterm += __shfl_xor(kterm, o, 64);
        if (t == 0) klout[0] = -0.5f * kterm * 0.25f;
    }
    __syncthreads();
    if (t < 128) {
        int b = t >> 5, i = t & 31;
        float a = d1b[i];
        for (int l = 0; l < 16; l++) a += zs[b * 16 + l] * d1w[i * 16 + l];
        hdc[t] = fmaxf(a, 0.f);
    }
}

__device__ void dev_edge_deg(int bid, const int* __restrict__ ei, const float* __restrict__ w,
                             float* deg, int E) {
    int e = bid * 256 + threadIdx.x;
    if (e < E) atomicAdd(&deg[ei[E + e]], w[e]);
}

__device__ void dev_cs_part(int bid, const float* __restrict__ X, int N,
                            float* sum, float* sumsq, float* sh) {
    int t = threadIdx.x;
    int col = t & 63, ro = t >> 6;
    int rows = N >> 8;
    int r0 = bid * rows;
    float s = 0.f, q = 0.f;
    for (int r = r0 + ro; r < r0 + rows; r += 4) {
        float v = X[r * 64 + col];
        s += v; q += v * v;
    }
    float* ls = sh; float* lq = sh + 256;
    ls[t] = s; lq[t] = q;
    __syncthreads();
    if (t < 64) {
        for (int j = t + 64; j < 256; j += 64) { s += ls[j]; q += lq[j]; }
        atomicAdd(&sum[t], s);
        atomicAdd(&sumsq[t], q);
    }
}

// grid-stride 4-edge-batched aggregation: wave = 4 edges/iter, 64 lanes = 64 h
__device__ void dev_edge_agg(int bid, const int* __restrict__ ei, const float* __restrict__ w,
                             const float* __restrict__ deg, const float* __restrict__ x,
                             float* agg) {
    const int h = threadIdx.x & 63;
    const int wid = bid * 4 + (threadIdx.x >> 6);
    const int nw4 = AGGBLKS * 4 * 4;
    for (int e0 = wid * 4; e0 < E1N; e0 += nw4) {
        int srcs[4], dsts[4];
        float norms[4];
        #pragma unroll
        for (int j = 0; j < 4; j++) {
            int e = e0 + j;
            srcs[j] = ei[e];
            dsts[j] = ei[E1N + e];
            norms[j] = rsqrtf(deg[dsts[j]]) * w[e] * rsqrtf(deg[srcs[j]]);
        }
        float xv[4];
        #pragma unroll
        for (int j = 0; j < 4; j++) xv[j] = x[srcs[j] * HH + h];
        #pragma unroll
        for (int j = 0; j < 4; j++)
            atomicAdd(&agg[dsts[j] * HH + h], norms[j] * xv[j]);
    }
}

// 320-block broadcast scan: each thread owns one edge, compares dst vs 8 pidx
__device__ void dev_pert_edges(int bid, const int* __restrict__ pidx, const int* __restrict__ ei,
                               const float* __restrict__ w, const float* __restrict__ deg,
                               const float* __restrict__ tbl, float* pslot) {
    int e = bid * 256 + threadIdx.x;
    if (e >= E2N) return;
    int dst = ei[E2N + e];
    int src = ei[e];
    for (int s = 0; s < 8; s++) {
        if (pidx[s] == dst) {
            float norm = rsqrtf(deg[dst]) * w[e] * rsqrtf(deg[src]);
            for (int h = 0; h < 64; h++)
                atomicAdd(&pslot[s * 64 + h], norm * tbl[src * 64 + h]);
        }
    }
}

// base_in = relu(bn(gene_emb)) + 0.2*((agg + emb_pos/deg) @ Wco^T + bco)
__device__ void dev_base_combine(int bid, const float* __restrict__ gene_emb,
                                 const float* __restrict__ agg, const float* __restrict__ emb_pos,
                                 const float* __restrict__ deg,
                                 const float* __restrict__ W, const float* __restrict__ bias,
                                 const float* __restrict__ bsum, const float* __restrict__ bsq,
                                 const float* __restrict__ bg, const float* __restrict__ bb,
                                 float* out, float* sh) {
    float* Wt = sh;            // [64][65]
    float* a = sh + 4160;      // [4][64]
    int t = threadIdx.x;
    for (int i = t; i < 4096; i += 256) Wt[(i & 63) * 65 + (i >> 6)] = W[i];
    int rr = t >> 6, h = t & 63;
    int g = bid * 4 + rr;
    a[rr * 64 + h] = agg[g * 64 + h] + emb_pos[g * 64 + h] / deg[g];
    __syncthreads();
    float y = bias[h];
    const float* ar = a + rr * 64;
    #pragma unroll 8
    for (int k = 0; k < 64; k++) y += ar[k] * Wt[k * 65 + h];
    const float invN = 1.0f / (float)GG;
    float m = bsum[h] * invN;
    float is_ = rsqrtf(bsq[h] * invN - m * m + BNEPS);
    float v = gene_emb[g * 64 + h];
    v = (v - m) * is_ * bg[h] + bb[h];
    v = fmaxf(v, 0.f);
    out[g * 64 + h] = v + 0.2f * y;
}

__device__ void dev_pert_mlp(const float* __restrict__ pslot, const int* __restrict__ pidx,
                             const float* __restrict__ deg, const float* __restrict__ tbl,
                             const float* __restrict__ gw, const float* __restrict__ gb,
                             const float* __restrict__ w1, const float* __restrict__ b1,
                             const float* __restrict__ g1, const float* __restrict__ be1,
                             const float* __restrict__ w2, const float* __restrict__ b2,
                             const float* __restrict__ g2, const float* __restrict__ be2,
                             float* etot, float* sh) {
    float* pge = sh;
    float* psum = sh + 512;
    float* y = sh + 768;
    float* mh = sh + 1024;
    float* ih = sh + 1088;
    int t = threadIdx.x;
    for (int j = t; j < 512; j += 256) {
        int s = j >> 6, h = j & 63;
        int n = pidx[s];
        float invd = 1.0f / deg[n];
        float acc = gb[h];
        for (int k = 0; k < 64; k++)
            acc += (pslot[s * 64 + k] + tbl[n * 64 + k] * invd) * gw[h * 64 + k];
        pge[j] = acc;
    }
    __syncthreads();
    { int b = t >> 6, h = t & 63; psum[t] = pge[2 * b * 64 + h] + pge[(2 * b + 1) * 64 + h]; }
    __syncthreads();
    { int h = t & 63; int b = t >> 6;
      float acc = b1[h];
      for (int k = 0; k < 64; k++) acc += psum[b * 64 + k] * w1[h * 64 + k];
      y[t] = acc; }
    __syncthreads();
    if (t < 64) {
        float s = 0.f, sq = 0.f;
        for (int b = 0; b < 4; b++) { float v = y[b * 64 + t]; s += v; sq += v * v; }
        float m = s * 0.25f;
        mh[t] = m; ih[t] = rsqrtf(sq * 0.25f - m * m + BNEPS);
    }
    __syncthreads();
    { int h = t & 63;
      float v = (y[t] - mh[h]) * ih[h] * g1[h] + be1[h];
      psum[t] = fmaxf(v, 0.f); }
    __syncthreads();
    { int h = t & 63; int b = t >> 6;
      float acc = b2[h];
      for (int k = 0; k < 64; k++) acc += psum[b * 64 + k] * w2[h * 64 + k];
      y[t] = acc; }
    __syncthreads();
    if (t < 64) {
        float s = 0.f, sq = 0.f;
        for (int b = 0; b < 4; b++) { float v = y[b * 64 + t]; s += v; sq += v * v; }
        float m = s * 0.25f;
        mh[t] = m; ih[t] = rsqrtf(sq * 0.25f - m * m + BNEPS);
    }
    __syncthreads();
    { int h = t & 63;
      etot[t] = (y[t] - mh[h]) * ih[h] * g2[h] + be2[h]; }
}

// ================= fat kernels =================
// K1: zero aggco(256,f4) | zero stats+pslot(3,f4) | deg=1(8,f4) | vae_he(128) | W->bf16(256)
__global__ void k_fat1(float* ws, const float* __restrict__ x,
                       const float* __restrict__ ve1_w, const float* __restrict__ ve1_b,
                       const float* __restrict__ ff1_w, const float* __restrict__ ff2_w) {
    __shared__ float sh[256];
    const float4 z4 = {0.f, 0.f, 0.f, 0.f};
    const float4 o4 = {1.f, 1.f, 1.f, 1.f};
    int bid = blockIdx.x;
    if (bid < 256) {
        int i = bid * 256 + threadIdx.x;
        *(float4*)&ws[OF_AGGCO + i * 4] = z4;
    } else if (bid < 259) {
        int i = (bid - 256) * 256 + threadIdx.x;
        if (i < 512) *(float4*)&ws[OF_STATS + i * 4] = z4;
        else if (i < 640) *(float4*)&ws[OF_PSLOT + (i - 512) * 4] = z4;
    } else if (bid < 267) {
        int i = (bid - 259) * 256 + threadIdx.x;
        *(float4*)&ws[OF_DEGCO + i * 4] = o4;      // degco+deggo contiguous 8192
    } else if (bid < 395) {
        dev_vae_he(bid - 267, x, ve1_w, ve1_b, ws + OF_HE, sh);
    } else {
        int i = (bid - 395) * 256 + threadIdx.x;   // 256 blocks -> 65536
        ushort_t* W1b = (ushort_t*)(ws + OF_W1B);
        ushort_t* W2b = (ushort_t*)(ws + OF_W2B);
        if (i < 32768) W1b[i] = f2b(ff1_w[i]);
        else W2b[i - 32768] = f2b(ff2_w[i - 32768]);
    }
}

// K2: edge_deg co(320) | edge_deg go(320) | cs_part gene_emb(256) | vae_mid(1)
__global__ void k_fat2(float* ws, const int* __restrict__ ei_co, const float* __restrict__ w_co,
                       const int* __restrict__ ei_go, const float* __restrict__ w_go,
                       const float* __restrict__ gene_emb,
                       const float* __restrict__ vmu_w, const float* __restrict__ vmu_b,
                       const float* __restrict__ vlv_w, const float* __restrict__ vlv_b,
                       const float* __restrict__ vd1_w, const float* __restrict__ vd1_b,
                       const float* __restrict__ veps, float* klout) {
    __shared__ float sh[512];
    int bid = blockIdx.x;
    if (bid < 320) dev_edge_deg(bid, ei_co, w_co, ws + OF_DEGCO, E1N);
    else if (bid < 640) dev_edge_deg(bid - 320, ei_go, w_go, ws + OF_DEGGO, E2N);
    else if (bid < 896) dev_cs_part(bid - 640, gene_emb, GG, ws + OF_STATS, ws + OF_STATS + 128, sh);
    else dev_vae_mid(ws + OF_HE, vmu_w, vmu_b, vlv_w, vlv_b, vd1_w, vd1_b, veps,
                     ws + OF_HDC, klout, sh);
}

// K3: edge_agg grid-stride(AGGBLKS) | pert_edges(320)
__global__ void k_fat3(float* ws, const int* __restrict__ ei_co, const float* __restrict__ w_co,
                       const float* __restrict__ emb_pos, const int* __restrict__ pidx,
                       const int* __restrict__ ei_go, const float* __restrict__ w_go,
                       const float* __restrict__ pert_tbl) {
    int bid = blockIdx.x;
    if (bid < AGGBLKS) dev_edge_agg(bid, ei_co, w_co, ws + OF_DEGCO, emb_pos, ws + OF_AGGCO);
    else dev_pert_edges(bid - AGGBLKS, pidx, ei_go, w_go, ws + OF_DEGGO, pert_tbl, ws + OF_PSLOT);
}

// K4: base_combine(1024) | pert_mlp(1)
__global__ void k_fat4(float* ws, const float* __restrict__ gene_emb,
                       const float* __restrict__ emb_pos,
                       const float* __restrict__ sg_co_w, const float* __restrict__ sg_co_b,
                       const float* __restrict__ bn_emb_g, const float* __restrict__ bn_emb_b,
                       const int* __restrict__ pidx, const float* __restrict__ pert_tbl,
                       const float* __restrict__ gw, const float* __restrict__ gb,
                       const float* __restrict__ w1, const float* __restrict__ b1,
                       const float* __restrict__ g1, const float* __restrict__ be1,
                       const float* __restrict__ w2, const float* __restrict__ b2,
                       const float* __restrict__ g2, const float* __restrict__ be2) {
    __shared__ float sh[4416];
    int bid = blockIdx.x;
    if (bid < 1024)
        dev_base_combine(bid, gene_emb, ws + OF_AGGCO, emb_pos, ws + OF_DEGCO,
                         sg_co_w, sg_co_b, ws + OF_STATS, ws + OF_STATS + 128,
                         bn_emb_g, bn_emb_b, ws + OF_BASEIN, sh);
    else
        dev_pert_mlp(ws + OF_PSLOT, pidx, ws + OF_DEGGO, pert_tbl, gw, gb,
                     w1, b1, g1, be1, w2, b2, g2, be2, ws + OF_ETOT, sh);
}

// ================= gemm64 (fp32, for etv/rw chain) =================
__launch_bounds__(256)
__global__ void k_gemm64(const float* __restrict__ X, const float* __restrict__ W,
                         const float* __restrict__ bias, float* __restrict__ Y,
                         int Cin, int Cout,
                         const float* __restrict__ bnsum, const float* __restrict__ bnsq,
                         const float* __restrict__ bng, const float* __restrict__ bnb,
                         float invN, int relu_in,
                         float* __restrict__ outsum, float* __restrict__ outsq) {
    __shared__ float Xs[64][66];
    __shared__ float Ws[64][66];
    __shared__ float bsc[64], bsh[64];
    const int t = threadIdx.x;
    const int row0 = blockIdx.x * 64, cb = blockIdx.y * 64;
    const int tx = t & 15, ty = t >> 4;
    const int c0 = tx * 4, r0 = ty * 4;
    float acc[4][4];
    #pragma unroll
    for (int j = 0; j < 4; j++)
        #pragma unroll
        for (int i = 0; i < 4; i++) acc[j][i] = 0.f;

    for (int k0 = 0; k0 < Cin; k0 += 64) {
        __syncthreads();
        if (t < 64) {
            float sc = 1.f, sh = 0.f;
            if (bnsum) {
                int c = k0 + t;
                float m = bnsum[c] * invN;
                float is_ = rsqrtf(bnsq[c] * invN - m * m + BNEPS);
                sc = is_ * bng[c]; sh = bnb[c] - m * sc;
            }
            bsc[t] = sc; bsh[t] = sh;
        }
        __syncthreads();
        for (int i = t; i < 1024; i += 256) {
            int r = i >> 4, kq = (i & 15) * 4;
            float4 v = *(const float4*)&X[(size_t)(row0 + r) * Cin + k0 + kq];
            float e0 = v.x * bsc[kq] + bsh[kq];
            float e1 = v.y * bsc[kq + 1] + bsh[kq + 1];
            float e2 = v.z * bsc[kq + 2] + bsh[kq + 2];
            float e3 = v.w * bsc[kq + 3] + bsh[kq + 3];
            if (relu_in) {
                e0 = fmaxf(e0, 0.f); e1 = fmaxf(e1, 0.f);
                e2 = fmaxf(e2, 0.f); e3 = fmaxf(e3, 0.f);
            }
            Xs[r][kq] = e0; Xs[r][kq + 1] = e1; Xs[r][kq + 2] = e2; Xs[r][kq + 3] = e3;
            float4 wv = *(const float4*)&W[(size_t)(cb + r) * Cin + k0 + kq];
            Ws[r][kq] = wv.x; Ws[r][kq + 1] = wv.y; Ws[r][kq + 2] = wv.z; Ws[r][kq + 3] = wv.w;
        }
        __syncthreads();
        #pragma unroll 4
        for (int k = 0; k < 64; k += 2) {
            float2 a[4], b[4];
            #pragma unroll
            for (int j = 0; j < 4; j++) a[j] = *(const float2*)&Xs[r0 + j][k];
            #pragma unroll
            for (int i = 0; i < 4; i++) b[i] = *(const float2*)&Ws[c0 + i][k];
            #pragma unroll
            for (int j = 0; j < 4; j++)
                #pragma unroll
                for (int i = 0; i < 4; i++)
                    acc[j][i] += a[j].x * b[i].x + a[j].y * b[i].y;
        }
    }
    float4 bi = *(const float4*)&bias[cb + c0];
    float scol[4] = {0.f, 0.f, 0.f, 0.f}, qcol[4] = {0.f, 0.f, 0.f, 0.f};
    #pragma unroll
    for (int j = 0; j < 4; j++) {
        float4 o;
        o.x = acc[j][0] + bi.x; o.y = acc[j][1] + bi.y;
        o.z = acc[j][2] + bi.z; o.w = acc[j][3] + bi.w;
        *(float4*)&Y[(size_t)(row0 + r0 + j) * Cout + cb + c0] = o;
        scol[0] += o.x; scol[1] += o.y; scol[2] += o.z; scol[3] += o.w;
        qcol[0] += o.x * o.x; qcol[1] += o.y * o.y;
        qcol[2] += o.z * o.z; qcol[3] += o.w * o.w;
    }
    if (outsum) {
        __syncthreads();
        #pragma unroll
        for (int i = 0; i < 4; i++) { Xs[ty][c0 + i] = scol[i]; Ws[ty][c0 + i] = qcol[i]; }
        __syncthreads();
        if (t < 64) {
            float ss = 0.f, qq = 0.f;
            #pragma unroll
            for (int r = 0; r < 16; r++) { ss += Xs[r][t]; qq += Ws[r][t]; }
            atomicAdd(&outsum[cb + t], ss);
            atomicAdd(&outsq[cb + t], qq);
        }
    }
}

// ================= fused QKV gemm: BN(yrw2) @ ain_w^T + b -> bf16 Qb/Kb/Vf =================
__launch_bounds__(256)
__global__ void k_gemm_qkv(const float* __restrict__ X, const float* __restrict__ W,
                           const float* __restrict__ bias,
                           const float* __restrict__ bnsum, const float* __restrict__ bnsq,
                           const float* __restrict__ bng, const float* __restrict__ bnb,
                           ushort_t* __restrict__ Qb, ushort_t* __restrict__ Kb,
                           ushort_t* __restrict__ Vf) {
    __shared__ float Xs[64][66];
    __shared__ float Ws[64][66];
    __shared__ float bsc[64], bsh[64];
    const int t = threadIdx.x;
    const int row0 = blockIdx.x * 64, yb = blockIdx.y, cb = yb * 64;
    const int tx = t & 15, ty = t >> 4;
    const int c0 = tx * 4, r0 = ty * 4;
    const float invN = 1.0f / (float)(BB * GG);
    if (t < 64) {
        float m = bnsum[t] * invN;
        float is_ = rsqrtf(bnsq[t] * invN - m * m + BNEPS);
        float sc = is_ * bng[t];
        bsc[t] = sc; bsh[t] = bnb[t] - m * sc;
    }
    __syncthreads();
    for (int i = t; i < 1024; i += 256) {
        int r = i >> 4, kq = (i & 15) * 4;
        float4 v = *(const float4*)&X[(size_t)(row0 + r) * 64 + kq];
        Xs[r][kq] = v.x * bsc[kq] + bsh[kq];
        Xs[r][kq + 1] = v.y * bsc[kq + 1] + bsh[kq + 1];
        Xs[r][kq + 2] = v.z * bsc[kq + 2] + bsh[kq + 2];
        Xs[r][kq + 3] = v.w * bsc[kq + 3] + bsh[kq + 3];
        float4 wv = *(const float4*)&W[(size_t)(cb + r) * 64 + kq];
        Ws[r][kq] = wv.x; Ws[r][kq + 1] = wv.y; Ws[r][kq + 2] = wv.z; Ws[r][kq + 3] = wv.w;
    }
    __syncthreads();
    float acc[4][4];
    #pragma unroll
    for (int j = 0; j < 4; j++)
        #pragma unroll
        for (int i = 0; i < 4; i++) acc[j][i] = 0.f;
    #pragma unroll 4
    for (int k = 0; k < 64; k += 2) {
        float2 a[4], b[4];
        #pragma unroll
        for (int j = 0; j < 4; j++) a[j] = *(const float2*)&Xs[r0 + j][k];
        #pragma unroll
        for (int i = 0; i < 4; i++) b[i] = *(const float2*)&Ws[c0 + i][k];
        #pragma unroll
        for (int j = 0; j < 4; j++)
            #pragma unroll
            for (int i = 0; i < 4; i++)
                acc[j][i] += a[j].x * b[i].x + a[j].y * b[i].y;
    }
    float4 bi = *(const float4*)&bias[cb + c0];
    const int b2 = row0 >> 12, tile = (row0 & 4095) >> 6;
    if (yb < 2) {
        ushort_t* Dst = (yb == 0) ? Qb : Kb;
        const float sc2 = (yb == 0) ? QPRE : 1.0f;
        const int h = c0 >> 5, d = c0 & 31;
        #pragma unroll
        for (int j = 0; j < 4; j++) {
            union { ushort_t u[4]; uint2 v; } pk;
            pk.u[0] = f2b((acc[j][0] + bi.x) * sc2);
            pk.u[1] = f2b((acc[j][1] + bi.y) * sc2);
            pk.u[2] = f2b((acc[j][2] + bi.z) * sc2);
            pk.u[3] = f2b((acc[j][3] + bi.w) * sc2);
            int g = (row0 & 4095) + r0 + j;
            *(uint2*)&Dst[((size_t)(b2 * 2 + h) * GG + g) * 32 + d] = pk.v;
        }
    } else {
        __syncthreads();
        #pragma unroll
        for (int j = 0; j < 4; j++) {
            Xs[r0 + j][c0] = acc[j][0] + bi.x;
            Xs[r0 + j][c0 + 1] = acc[j][1] + bi.y;
            Xs[r0 + j][c0 + 2] = acc[j][2] + bi.z;
            Xs[r0 + j][c0 + 3] = acc[j][3] + bi.w;
        }
        __syncthreads();
        #pragma unroll
        for (int h = 0; h < 2; h++) {
            union { ushort_t u[8]; uint4 v; } pk;
            #pragma unroll
            for (int j = 0; j < 8; j++) {
                int idx = t * 8 + j;
                int g2 = idx >> 8, L = (idx >> 2) & 63, i = idx & 3;
                int key = (g2 >> 1) * 16 + ((L >> 4) << 2) + i;
                int d = ((g2 & 1) << 4) + (L & 15);
                pk.u[j] = f2b(Xs[key][h * 32 + d]);
            }
            *(uint4*)&Vf[((size_t)((b2 * 2 + h) * 64 + tile)) * 2048 + t * 8] = pk.v;
        }
    }
}

// flat_pre = bn(y2) + etot, fused column stats
__global__ void k_flatpre(const float* __restrict__ y2, const float* __restrict__ etot,
                          const float* __restrict__ bsum, const float* __restrict__ bsq,
                          const float* __restrict__ g2, const float* __restrict__ b2,
                          float* __restrict__ out,
                          float* __restrict__ osum, float* __restrict__ osq) {
    int t = threadIdx.x;
    int h = t & 63, ro = t >> 6;
    int row0 = blockIdx.x * 64;
    const float invN = 1.0f / (float)GG;
    float m = bsum[h] * invN;
    float is_ = rsqrtf(bsq[h] * invN - m * m + BNEPS);
    float sc = is_ * g2[h];
    float sh = b2[h] - m * sc;
    float s = 0.f, q = 0.f;
    for (int r = row0 + ro; r < row0 + 64; r += 4) {
        int b = r >> 12, gh = (r & 4095) * 64 + h;
        float v = y2[gh] * sc + sh + etot[b * 64 + h];
        out[r * 64 + h] = v;
        s += v; q += v * v;
    }
    __shared__ float ls[256], lq[256];
    ls[t] = s; lq[t] = q;
    __syncthreads();
    if (t < 64) {
        s = ls[t] + ls[t + 64] + ls[t + 128] + ls[t + 192];
        q = lq[t] + lq[t + 64] + lq[t + 128] + lq[t + 192];
        atomicAdd(&osum[t], s);
        atomicAdd(&osq[t], q);
    }
}

// ---- MFMA flash attention, 4-bh per block (mask register reuse, 2 blocks/CU) ----
__launch_bounds__(512, 4)
__global__ void k_attn_mfma(const ushort_t* __restrict__ Qb, const ushort_t* __restrict__ Kb,
                            const ushort_t* __restrict__ Vf, const float* __restrict__ mask,
                            float* __restrict__ opA, float* __restrict__ opB,
                            float* __restrict__ Lp) {
    __shared__ ushort_t Kl[2][4][2048];
    __shared__ ushort_t Vl[2][4][2048];
    const int split = blockIdx.y;
    const int bh0 = blockIdx.z * 4;
    const int q0 = blockIdx.x * 64;
    const int kstart = split * (GG / 4), kend = kstart + (GG / 4);
    const int t = threadIdx.x;
    const int lane = t & 63, w = t >> 6;
    const int qg = w >> 1, kh = w & 1;
    const int l15 = lane & 15, quad = lane >> 4;
    const int i2a = kh * 2, i2b = kh * 2 + 1;

    sh8 qf[4];
    #pragma unroll
    for (int bh = 0; bh < 4; bh++)
        qf[bh] = *(const sh8*)&Qb[((size_t)(bh0 + bh) * GG + q0 + qg * 16 + l15) * 32 + quad * 8];
    const float* mrow = mask + (size_t)(q0 + qg * 16 + l15) * GG + quad * 4;

    auto stage = [&](int buf, int k0) {
        #pragma unroll
        for (int s = 0; s < 2; s++) {
            int idx = s * 512 + t;
            int bh = idx >> 8, c = idx & 255;
            int key = ((c >> 6) << 4) + (c & 15);
            int chunk = (c >> 4) & 3;
            gld16(Kb + ((size_t)(bh0 + bh) * GG + k0 + key) * 32 + chunk * 8,
                  &Kl[buf][bh][c * 8]);
            gld16(Vf + ((size_t)((bh0 + bh) * 64 + (k0 >> 6))) * 2048 + c * 8,
                  &Vl[buf][bh][c * 8]);
        }
    };
    stage(0, kstart);

    f4 O0[4], O1[4];
    float ls[4];
    #pragma unroll
    for (int bh = 0; bh < 4; bh++) {
        O0[bh] = f4{0.f, 0.f, 0.f, 0.f};
        O1[bh] = f4{0.f, 0.f, 0.f, 0.f};
        ls[bh] = 0.f;
    }

    for (int k0 = kstart; k0 < kend; k0 += 64) {
        const int cur = ((k0 - kstart) >> 6) & 1;
        __syncthreads();
        if (k0 + 64 < kend) stage(cur ^ 1, k0 + 64);
        float4 mva = *(const float4*)&mrow[k0 + i2a * 16];
        float4 mvb = *(const float4*)&mrow[k0 + i2b * 16];
        #pragma unroll
        for (int bh = 0; bh < 4; bh++) {
            sh8 kfa = *(const sh8*)&Kl[cur][bh][(i2a * 64 + lane) * 8];
            sh8 kfb = *(const sh8*)&Kl[cur][bh][(i2b * 64 + lane) * 8];
            f4 z = {0.f, 0.f, 0.f, 0.f};
            f4 sa = __builtin_amdgcn_mfma_f32_16x16x32_bf16(kfa, qf[bh], z, 0, 0, 0);
            f4 sb = __builtin_amdgcn_mfma_f32_16x16x32_bf16(kfb, qf[bh], z, 0, 0, 0);
            {
                float p0 = exp2f(fmaf(mva.x, LOG2E, sa[0]));
                float p1 = exp2f(fmaf(mva.y, LOG2E, sa[1]));
                float p2 = exp2f(fmaf(mva.z, LOG2E, sa[2]));
                float p3 = exp2f(fmaf(mva.w, LOG2E, sa[3]));
                ls[bh] += (p0 + p1) + (p2 + p3);
                union { __hip_bfloat162 h2[2]; sh4 v; } pkp;
                pkp.h2[0] = __float22bfloat162_rn(float2{p0, p1});
                pkp.h2[1] = __float22bfloat162_rn(float2{p2, p3});
                sh4 vf0 = *(const sh4*)&Vl[cur][bh][((i2a * 2 + 0) * 64 + lane) * 4];
                sh4 vf1 = *(const sh4*)&Vl[cur][bh][((i2a * 2 + 1) * 64 + lane) * 4];
                O0[bh] = MFMA16(pkp.v, vf0, O0[bh]);
                O1[bh] = MFMA16(pkp.v, vf1, O1[bh]);
            }
            {
                float p0 = exp2f(fmaf(mvb.x, LOG2E, sb[0]));
                float p1 = exp2f(fmaf(mvb.y, LOG2E, sb[1]));
                float p2 = exp2f(fmaf(mvb.z, LOG2E, sb[2]));
                float p3 = exp2f(fmaf(mvb.w, LOG2E, sb[3]));
                ls[bh] += (p0 + p1) + (p2 + p3);
                union { __hip_bfloat162 h2[2]; sh4 v; } pkp;
                pkp.h2[0] = __float22bfloat162_rn(float2{p0, p1});
                pkp.h2[1] = __float22bfloat162_rn(float2{p2, p3});
                sh4 vf0 = *(const sh4*)&Vl[cur][bh][((i2b * 2 + 0) * 64 + lane) * 4];
                sh4 vf1 = *(const sh4*)&Vl[cur][bh][((i2b * 2 + 1) * 64 + lane) * 4];
                O0[bh] = MFMA16(pkp.v, vf0, O0[bh]);
                O1[bh] = MFMA16(pkp.v, vf1, O1[bh]);
            }
        }
    }
    #pragma unroll
    for (int bh = 0; bh < 4; bh++) {
        ls[bh] += __shfl_xor(ls[bh], 16, 64);
        ls[bh] += __shfl_xor(ls[bh], 32, 64);
    }
    __syncthreads();
    float* Ox = (float*)&Kl[0][0][0];
    float* Lx = (float*)&Vl[0][0][0];
    if (kh == 0) {
        #pragma unroll
        for (int bh = 0; bh < 4; bh++) {
            #pragma unroll
            for (int r = 0; r < 4; r++) {
                int ql = qg * 16 + quad * 4 + r;
                Ox[(bh * 64 + ql) * 32 + l15] = O0[bh][r];
                Ox[(bh * 64 + ql) * 32 + l15 + 16] = O1[bh][r];
            }
            if (quad == 0) Lx[bh * 64 + qg * 16 + l15] = ls[bh];
        }
    }
    __syncthreads();
    if (kh == 1) {
        float* op = (split < 3) ? (opA + (size_t)split * OPS) : opB;
        #pragma unroll
        for (int bh = 0; bh < 4; bh++) {
            int gbh = bh0 + bh;
            #pragma unroll
            for (int r = 0; r < 4; r++) {
                int ql = qg * 16 + quad * 4 + r;
                size_t o = ((size_t)gbh * GG + q0 + ql) * 32 + l15;
                op[o] = O0[bh][r] + Ox[(bh * 64 + ql) * 32 + l15];
                op[o + 16] = O1[bh][r] + Ox[(bh * 64 + ql) * 32 + l15 + 16];
            }
            if (quad == 0)
                Lp[split * 32768 + gbh * GG + q0 + qg * 16 + l15] =
                    ls[bh] + Lx[bh * 64 + qg * 16 + l15];
        }
    }
}

// combine splits + att = ctx @ Wout^T + b ; h1 = LN(bn(yrw2) + att); also emit h1b frag-bf16
__global__ void k_attn_out_ln(const float* __restrict__ opA, const float* __restrict__ opB,
                              const float* __restrict__ Lp, const float* __restrict__ yrw2,
                              const float* __restrict__ W, const float* __restrict__ bias,
                              const float* __restrict__ bsum, const float* __restrict__ bsq,
                              const float* __restrict__ bg, const float* __restrict__ bb,
                              const float* __restrict__ lg, const float* __restrict__ lb,
                              float* __restrict__ h1, ushort_t* __restrict__ h1b) {
    __shared__ float Wt[64][65];
    __shared__ float Cs[16][65];
    __shared__ ushort_t Hs[16][64];
    int t = threadIdx.x;
    int row0 = blockIdx.x * 16;
    for (int i = t; i < 4096; i += 256) Wt[i & 63][i >> 6] = W[i];
    {
        int col = t & 63, rl = t >> 6;
        int hh = col >> 5, d = col & 31;
        #pragma unroll
        for (int jj = 0; jj < 4; jj++) {
            int row = row0 + rl + jj * 4;
            int b = row >> 12, q = row & 4095;
            int bhq = (b * 2 + hh) * GG + q;
            size_t oi = (size_t)bhq * 32 + d;
            float num = opA[oi] + opA[OPS + oi] + opA[2 * OPS + oi] + opB[oi];
            float den = Lp[bhq] + Lp[32768 + bhq] + Lp[65536 + bhq] + Lp[98304 + bhq];
            Cs[rl + jj * 4][col] = num / den;
        }
    }
    __syncthreads();
    int rr = t >> 6, lane = t & 63;
    const float invN = 1.0f / (float)(BB * GG);
    float m = bsum[lane] * invN;
    float is_ = rsqrtf(bsq[lane] * invN - m * m + BNEPS);
    #pragma unroll
    for (int j = 0; j < 4; j++) {
        int lrow = rr * 4 + j;
        int row = row0 + lrow;
        float acc = bias[lane];
        const float* cr = Cs[lrow];
        #pragma unroll 8
        for (int k = 0; k < 64; k++) acc += cr[k] * Wt[k][lane];
        float ov = (yrw2[row * 64 + lane] - m) * is_ * bg[lane] + bb[lane];
        float v = ov + acc;
        float s = v;
        for (int o = 32; o > 0; o >>= 1) s += __shfl_xor(s, o, 64);
        float mean = s * (1.f / 64.f);
        float d = v - mean;
        float sq = d * d;
        for (int o = 32; o > 0; o >>= 1) sq += __shfl_xor(sq, o, 64);
        float inv = rsqrtf(sq * (1.f / 64.f) + BNEPS);
        float hv = d * inv * lg[lane] + lb[lane];
        h1[row * 64 + lane] = hv;
        Hs[lrow][lane] = f2b(hv);
    }
    __syncthreads();
    if (t < 128) {
        int kt = t >> 6, lane6 = t & 63;
        int q2 = (lane6 >> 4) & 3, r15 = lane6 & 15;
        union { ushort_t u[8]; uint4 v; } pk;
        #pragma unroll
        for (int j = 0; j < 8; j++) pk.u[j] = Hs[r15][kt * 32 + q2 * 8 + j];
        *(uint4*)&h1b[((size_t)blockIdx.x * 2 + kt) * 512 + lane6 * 8] = pk.v;
    }
}

// ================= FFN layer 1: fft = relu(h1 @ W1^T + b1), bf16 MFMA =================
__launch_bounds__(256)
__global__ void k_ffn1(const ushort_t* __restrict__ h1b, const ushort_t* __restrict__ W1b,
                       const float* __restrict__ b1, ushort_t* __restrict__ fft) {
    __shared__ ushort_t Xl[4096];
    __shared__ ushort_t Wl[4096];
    const int t = threadIdx.x;
    const int rowblock = blockIdx.x, colblock = blockIdx.y;
    const int cb = colblock * 64;
    const int lane = t & 63, w = t >> 6;
    const int l15 = lane & 15, quad = lane >> 4;
    #pragma unroll
    for (int kt = 0; kt < 2; kt++) {
        gld16(h1b + (size_t)(((rowblock * 4 + w) * 2 + kt) * 512 + lane * 8),
              &Xl[(w * 2 + kt) * 512 + lane * 8]);
        gld16(W1b + (size_t)((cb + w * 16 + l15) * 64 + kt * 32 + quad * 8),
              &Wl[(w * 2 + kt) * 512 + lane * 8]);
    }
    __syncthreads();
    sh8 xf0 = *(const sh8*)&Xl[(w * 2 + 0) * 512 + lane * 8];
    sh8 xf1 = *(const sh8*)&Xl[(w * 2 + 1) * 512 + lane * 8];
    #pragma unroll
    for (int c = 0; c < 4; c++) {
        sh8 wf0 = *(const sh8*)&Wl[(c * 2 + 0) * 512 + lane * 8];
        sh8 wf1 = *(const sh8*)&Wl[(c * 2 + 1) * 512 + lane * 8];
        f4 z = {0.f, 0.f, 0.f, 0.f};
        f4 acc = __builtin_amdgcn_mfma_f32_16x16x32_bf16(wf0, xf0, z, 0, 0, 0);
        acc = __builtin_amdgcn_mfma_f32_16x16x32_bf16(wf1, xf1, acc, 0, 0, 0);
        float4 bv = *(const float4*)&b1[cb + c * 16 + quad * 4];
        union { ushort_t u[4]; uint2 v; } pk;
        pk.u[0] = f2b(fmaxf(acc[0] + bv.x, 0.f));
        pk.u[1] = f2b(fmaxf(acc[1] + bv.y, 0.f));
        pk.u[2] = f2b(fmaxf(acc[2] + bv.z, 0.f));
        pk.u[3] = f2b(fmaxf(acc[3] + bv.w, 0.f));
        int kt512 = colblock * 2 + (c >> 1);
        int quadp = (c & 1) * 2 + (quad >> 1);
        int j0 = (quad & 1) * 4;
        size_t o = ((size_t)(((rowblock * 4 + w) * 16 + kt512) * 64 + quadp * 16 + l15)) * 8 + j0;
        *(uint2*)&fft[o] = pk.v;
    }
}

// ================= FFN layer 2 + LN2 + per-gene head + recon (fused final) =================
__launch_bounds__(256)
__global__ void k_ffn2(const ushort_t* __restrict__ fft, const ushort_t* __restrict__ W2b,
                       const float* __restrict__ b2, const float* __restrict__ h1,
                       const float* __restrict__ lg, const float* __restrict__ lb,
                       const float* __restrict__ indvw, const float* __restrict__ indvb,
                       const float* __restrict__ hdc, const float* __restrict__ d2w,
                       const float* __restrict__ d2b, const float* __restrict__ x,
                       float* __restrict__ outp) {
    __shared__ ushort_t Xl[2][4096];
    __shared__ ushort_t Wl[2][4096];
    const int t = threadIdx.x;
    const int rowblock = blockIdx.x;
    const int lane = t & 63, w = t >> 6;
    const int l15 = lane & 15, quad = lane >> 4;

    #pragma unroll
    for (int kt = 0; kt < 2; kt++) {
        gld16(fft + (size_t)((((rowblock * 4 + w) * 16) + kt) * 64 + lane) * 8,
              &Xl[0][(w * 2 + kt) * 512 + lane * 8]);
        gld16(W2b + (size_t)((w * 16 + l15) * 512 + kt * 32 + quad * 8),
              &Wl[0][(w * 2 + kt) * 512 + lane * 8]);
    }
    f4 acc[4];
    #pragma unroll
    for (int c = 0; c < 4; c++) acc[c] = f4{0.f, 0.f, 0.f, 0.f};

    for (int k0 = 0; k0 < 512; k0 += 64) {
        const int cur = (k0 >> 6) & 1;
        __syncthreads();
        if (k0 + 64 < 512) {
            const int nxt = cur ^ 1;
            const int ktb = (k0 + 64) >> 5;
            #pragma unroll
            for (int kt = 0; kt < 2; kt++) {
                gld16(fft + (size_t)((((rowblock * 4 + w) * 16) + ktb + kt) * 64 + lane) * 8,
                      &Xl[nxt][(w * 2 + kt) * 512 + lane * 8]);
                gld16(W2b + (size_t)((w * 16 + l15) * 512 + k0 + 64 + kt * 32 + quad * 8),
                      &Wl[nxt][(w * 2 + kt) * 512 + lane * 8]);
            }
        }
        #pragma unroll
        for (int kt = 0; kt < 2; kt++) {
            sh8 xf = *(const sh8*)&Xl[cur][(w * 2 + kt) * 512 + lane * 8];
            #pragma unroll
            for (int c = 0; c < 4; c++) {
                sh8 wf = *(const sh8*)&Wl[cur][(c * 2 + kt) * 512 + lane * 8];
                acc[c] = __builtin_amdgcn_mfma_f32_16x16x32_bf16(wf, xf, acc[c], 0, 0, 0);
            }
        }
    }
    const int row = rowblock * 64 + w * 16 + l15;
    const int b = row >> 12, g = row & 4095;
    float v[4][4];
    float s = 0.f, sq = 0.f;
    #pragma unroll
    for (int c = 0; c < 4; c++) {
        float4 bv = *(const float4*)&b2[c * 16 + quad * 4];
        float4 hv = *(const float4*)&h1[(size_t)row * 64 + c * 16 + quad * 4];
        v[c][0] = hv.x + acc[c][0] + bv.x;
        v[c][1] = hv.y + acc[c][1] + bv.y;
        v[c][2] = hv.z + acc[c][2] + bv.z;
        v[c][3] = hv.w + acc[c][3] + bv.w;
        #pragma unroll
        for (int i = 0; i < 4; i++) { s += v[c][i]; sq += v[c][i] * v[c][i]; }
    }
    s += __shfl_xor(s, 16, 64);  s += __shfl_xor(s, 32, 64);
    sq += __shfl_xor(sq, 16, 64); sq += __shfl_xor(sq, 32, 64);
    float mean = s * (1.f / 64.f);
    float inv = rsqrtf(sq * (1.f / 64.f) - mean * mean + BNEPS);
    float pd = 0.f;
    #pragma unroll
    for (int c = 0; c < 4; c++) {
        float4 lgv = *(const float4*)&lg[c * 16 + quad * 4];
        float4 lbv = *(const float4*)&lb[c * 16 + quad * 4];
        float4 iwv = *(const float4*)&indvw[(size_t)g * 64 + c * 16 + quad * 4];
        pd += ((v[c][0] - mean) * inv * lgv.x + lbv.x) * iwv.x;
        pd += ((v[c][1] - mean) * inv * lgv.y + lbv.y) * iwv.y;
        pd += ((v[c][2] - mean) * inv * lgv.z + lbv.z) * iwv.z;
        pd += ((v[c][3] - mean) * inv * lgv.w + lbv.w) * iwv.w;
    }
    float rc = 0.f;
    #pragma unroll
    for (int i = 0; i < 8; i++)
        rc += hdc[b * 32 + quad * 8 + i] * d2w[(size_t)g * 32 + quad * 8 + i];
    pd += __shfl_xor(pd, 16, 64); pd += __shfl_xor(pd, 32, 64);
    rc += __shfl_xor(rc, 16, 64); rc += __shfl_xor(rc, 32, 64);
    if (quad == 0) {
        float recon = rc + d2b[g];
        if (x[row] == 0.f) recon = 0.f;
        outp[row] = pd + indvb[g] + recon;
    }
}

extern "C" void kernel_launch(void* const* d_in, const int* in_sizes, int n_in,
                              void* d_out, int out_size, void* d_ws, size_t ws_size,
                              hipStream_t stream) {
    const float* x        = (const float*)d_in[0];
    const int*   pert_idx = (const int*)  d_in[1];
    const float* mask     = (const float*)d_in[2];
    const int*   ei_co    = (const int*)  d_in[3];
    const float* w_co     = (const float*)d_in[4];
    const int*   ei_go    = (const int*)  d_in[5];
    const float* w_go     = (const float*)d_in[6];
    const float* gene_emb = (const float*)d_in[7];
    const float* emb_pos  = (const float*)d_in[8];
    const float* pert_tbl = (const float*)d_in[9];
    const float* sg_co_w  = (const float*)d_in[10];
    const float* sg_co_b  = (const float*)d_in[11];
    const float* sg_go_w  = (const float*)d_in[12];
    const float* sg_go_b  = (const float*)d_in[13];
    const float* bn_emb_g = (const float*)d_in[14];
    const float* bn_emb_b = (const float*)d_in[15];
    const float* etv1_w   = (const float*)d_in[16];
    const float* etv1_b   = (const float*)d_in[17];
    const float* etv1_g   = (const float*)d_in[18];
    const float* etv1_be  = (const float*)d_in[19];
    const float* etv2_w   = (const float*)d_in[20];
    const float* etv2_b   = (const float*)d_in[21];
    const float* etv2_g   = (const float*)d_in[22];
    const float* etv2_be  = (const float*)d_in[23];
    const float* pf1_w    = (const float*)d_in[24];
    const float* pf1_b    = (const float*)d_in[25];
    const float* pf1_g    = (const float*)d_in[26];
    const float* pf1_be   = (const float*)d_in[27];
    const float* pf2_w    = (const float*)d_in[28];
    const float* pf2_b    = (const float*)d_in[29];
    const float* pf2_g    = (const float*)d_in[30];
    const float* pf2_be   = (const float*)d_in[31];
    const float* rw1_w    = (const float*)d_in[32];
    const float* rw1_b    = (const float*)d_in[33];
    const float* rw1_g    = (const float*)d_in[34];
    const float* rw1_be   = (const float*)d_in[35];
    const float* rw2_w    = (const float*)d_in[36];
    const float* rw2_b    = (const float*)d_in[37];
    const float* rw2_g    = (const float*)d_in[38];
    const float* rw2_be   = (const float*)d_in[39];
    const float* bnpb_g   = (const float*)d_in[40];
    const float* bnpb_b   = (const float*)d_in[41];
    const float* ain_w    = (const float*)d_in[42];
    const float* ain_b    = (const float*)d_in[43];
    const float* aout_w   = (const float*)d_in[44];
    const float* aout_b   = (const float*)d_in[45];
    const float* ln1_g    = (const float*)d_in[46];
    const float* ln1_b    = (const float*)d_in[47];
    const float* ff1_w    = (const float*)d_in[48];
    const float* ff1_b    = (const float*)d_in[49];
    const float* ff2_w    = (const float*)d_in[50];
    const float* ff2_b    = (const float*)d_in[51];
    const float* ln2_g    = (const float*)d_in[52];
    const float* ln2_b    = (const float*)d_in[53];
    const float* indv_w   = (const float*)d_in[54];
    const float* indv_b   = (const float*)d_in[55];
    const float* ve1_w    = (const float*)d_in[56];
    const float* ve1_b    = (const float*)d_in[57];
    const float* vmu_w    = (const float*)d_in[58];
    const float* vmu_b    = (const float*)d_in[59];
    const float* vlv_w    = (const float*)d_in[60];
    const float* vlv_b    = (const float*)d_in[61];
    const float* vd1_w    = (const float*)d_in[62];
    const float* vd1_b    = (const float*)d_in[63];
    const float* vd2_w    = (const float*)d_in[64];
    const float* vd2_b    = (const float*)d_in[65];
    const float* veps     = (const float*)d_in[66];

    float* ws   = (float*)d_ws;
    float* outp = (float*)d_out;

    float* stm1 = ws + OF_STATS + 1 * 256; float* sti1 = stm1 + 128;
    float* stm2 = ws + OF_STATS + 2 * 256; float* sti2 = stm2 + 128;
    float* stm3 = ws + OF_STATS + 3 * 256; float* sti3 = stm3 + 128;
    float* stm4 = ws + OF_STATS + 4 * 256; float* sti4 = stm4 + 128;
    float* stm5 = ws + OF_STATS + 5 * 256; float* sti5 = stm5 + 128;

    float* basein = ws + OF_BASEIN;
    float* y1     = ws + OF_Y1;
    float* y2     = ws + OF_Y2;
    float* flat   = ws + OF_FLAT;
    float* yrw1   = ws + OF_RW1;
    float* yrw2   = ws + OF_RW2;
    float* h1     = ws + OF_H1;
    float* opA    = ws + OF_OPA;
    float* opB    = ws + OF_OPB;
    float* Lp     = ws + OF_LP;
    ushort_t* Qb  = (ushort_t*)(ws + OF_QB);
    ushort_t* Kb  = (ushort_t*)(ws + OF_KB);
    ushort_t* Vf  = (ushort_t*)(ws + OF_VF);
    ushort_t* W1b = (ushort_t*)(ws + OF_W1B);
    ushort_t* W2b = (ushort_t*)(ws + OF_W2B);
    ushort_t* h1b = (ushort_t*)(ws + OF_H1B);
    ushort_t* fft = (ushort_t*)(ws + OF_FFT);

    const int NG = BB * GG; // 16384
    const float iG = 1.0f / (float)GG, iNG = 1.0f / (float)NG;

    // K1: zero ws regions (float4), deg=1, vae_he, FFN weight->bf16
    k_fat1<<<651, 256, 0, stream>>>(ws, x, ve1_w, ve1_b, ff1_w, ff2_w);
    // K2: edge degrees, gene_emb stats, vae_mid
    k_fat2<<<897, 256, 0, stream>>>(ws, ei_co, w_co, ei_go, w_go, gene_emb,
                                    vmu_w, vmu_b, vlv_w, vlv_b, vd1_w, vd1_b,
                                    veps, outp + NG);
    // K3: grid-stride batched edge aggregation + pert edge broadcast scan
    k_fat3<<<AGGBLKS + 320, 256, 0, stream>>>(ws, ei_co, w_co, emb_pos, pert_idx,
                                              ei_go, w_go, pert_tbl);
    // K4: base_combine + pert MLP
    k_fat4<<<1025, 256, 0, stream>>>(ws, gene_emb, emb_pos, sg_co_w, sg_co_b,
                                     bn_emb_g, bn_emb_b, pert_idx, pert_tbl,
                                     sg_go_w, sg_go_b,
                                     pf1_w, pf1_b, pf1_g, pf1_be,
                                     pf2_w, pf2_b, pf2_g, pf2_be);
    // etv MLP (stats fused into epilogues)
    k_gemm64<<<dim3(GG / 64, 1), 256, 0, stream>>>(basein, etv1_w, etv1_b, y1, 64, 64,
                                                   nullptr, nullptr, nullptr, nullptr, 0.f, 0,
                                                   stm1, sti1);
    k_gemm64<<<dim3(GG / 64, 1), 256, 0, stream>>>(y1, etv2_w, etv2_b, y2, 64, 64,
                                                   stm1, sti1, etv1_g, etv1_be, iG, 1,
                                                   stm2, sti2);
    // fuse + rw MLP
    k_flatpre<<<NG / 64, 256, 0, stream>>>(y2, ws + OF_ETOT, stm2, sti2, etv2_g, etv2_be,
                                           flat, stm3, sti3);
    k_gemm64<<<dim3(NG / 64, 2), 256, 0, stream>>>(flat, rw1_w, rw1_b, yrw1, 64, 128,
                                                   stm3, sti3, bnpb_g, bnpb_b, iNG, 1,
                                                   stm4, sti4);
    k_gemm64<<<dim3(NG / 64, 1), 256, 0, stream>>>(yrw1, rw2_w, rw2_b, yrw2, 128, 64,
                                                   stm4, sti4, rw1_g, rw1_be, iNG, 1,
                                                   stm5, sti5);
    // transformer
    k_gemm_qkv<<<dim3(NG / 64, 3), 256, 0, stream>>>(yrw2, ain_w, ain_b,
                                                     stm5, sti5, rw2_g, rw2_be,
                                                     Qb, Kb, Vf);
    k_attn_mfma<<<dim3(GG / 64, 4, 2), 512, 0, stream>>>(Qb, Kb, Vf, mask, opA, opB, Lp);
    k_attn_out_ln<<<NG / 16, 256, 0, stream>>>(opA, opB, Lp, yrw2, aout_w, aout_b,
                                               stm5, sti5, rw2_g, rw2_be,
                                               ln1_g, ln1_b, h1, h1b);
    // FFN (bf16 MFMA) + fused final
    k_ffn1<<<dim3(NG / 64, FFD / 64), 256, 0, stream>>>(h1b, W1b, ff1_b, fft);
    k_ffn2<<<NG / 64, 256, 0, stream>>>(fft, W2b, ff2_b, h1, ln2_g, ln2_b,
                                        indv_w, indv_b, ws + OF_HDC, vd2_w, vd2_b,
                                        x, outp);
}

// Round 13
// 501.768 us; speedup vs baseline: 1.2894x; 1.0418x over previous
//
#include <hip/hip_runtime.h>
#include <hip/hip_bf16.h>
#include <math.h>

#define GG 4096
#define PP 4096
#define HH 64
#define BB 4
#define E1N 81920
#define E2N 81920
#define FFD 512
#define BNEPS 1e-5f
#define LOG2E 1.44269504088896341f
#define QPRE (0.17677669529663687f * LOG2E)

typedef unsigned short ushort_t;
typedef unsigned int uint_t;
using sh8 = __attribute__((ext_vector_type(8))) short;
using sh4 = __attribute__((ext_vector_type(4))) short;
using f4  = __attribute__((ext_vector_type(4))) float;

#if __has_builtin(__builtin_amdgcn_mfma_f32_16x16x16bf16_1k)
#define MFMA16(a, b, c) __builtin_amdgcn_mfma_f32_16x16x16bf16_1k((a), (b), (c), 0, 0, 0)
#elif __has_builtin(__builtin_amdgcn_mfma_f32_16x16x16_bf16)
#define MFMA16(a, b, c) __builtin_amdgcn_mfma_f32_16x16x16_bf16((a), (b), (c), 0, 0, 0)
#else
static __device__ inline f4 mfma16_asm(sh4 a, sh4 b, f4 c) {
    f4 d;
    asm volatile("v_mfma_f32_16x16x16_bf16 %0, %1, %2, %3"
                 : "=v"(d) : "v"(a), "v"(b), "v"(c));
    return d;
}
#define MFMA16(a, b, c) mfma16_asm((a), (b), (c))
#endif

// ---------------- workspace layout (float offsets) ----------------
#define OF_STATS   0          // 6 slots x 256 (raw sum[128] + sumsq[128])
#define OF_DEGCO   2048
#define OF_DEGGO   6144
#define OF_PSLOT   10240
#define OF_ETOT    10752
#define OF_HDC     11008
#define OF_HE      11136
#define OF_AGGCO   12288      // 4096 x 64
#define OF_BASEIN  274432
#define OF_Y1      536576
#define OF_Y2      798720
#define OF_FLAT    1060864    // (Vf region)
#define OF_RW1     2109440    // 16384 x 128
#define OF_RW2     4206592    // 16384 x 64
#define OF_OUT     5255168    // attn split 3 partial
#define OF_QKV     6303744    // attn splits 0..2 partials
// bf16 attention buffers (alias dead fp32 regions)
#define OF_QB      OF_AGGCO   // 8*4096*32 ushort
#define OF_KB      (OF_AGGCO + 524288)
#define OF_VF      OF_FLAT    // 8*64*2048 ushort (V frag-order)
// attention k-split partials
#define OF_OPA     OF_QKV
#define OF_OPB     OF_OUT
#define OF_LP      OF_RW1     // 4*8*4096
#define OPS        1048576
// FFN bf16 weights (dead FFO region)
#define OF_W1B     9449472    // 512*64 bf16
#define OF_W2B     9465856    // 64*512 bf16

#define AGGBLKS 1024

__device__ inline ushort_t f2b(float f) {
    uint_t u = __builtin_bit_cast(uint_t, f);
    u += 0x7FFFu + ((u >> 16) & 1u);
    return (ushort_t)(u >> 16);
}

__device__ inline void gld16(const void* gptr, void* lptr) {
    __builtin_amdgcn_global_load_lds(
        (const __attribute__((address_space(1))) uint_t*)gptr,
        (__attribute__((address_space(3))) uint_t*)lptr, 16, 0, 0);
}

// ================= device sub-kernels =================
__device__ void dev_vae_he(int bid, const float* __restrict__ x, const float* __restrict__ W,
                           const float* __restrict__ bias, float* he, float* sh) {
    int b = bid >> 5, i = bid & 31;
    float s = 0.f;
    for (int g = threadIdx.x; g < 4096; g += 256) s += x[b * 4096 + g] * W[i * 4096 + g];
    sh[threadIdx.x] = s;
    __syncthreads();
    for (int o = 128; o > 0; o >>= 1) {
        if (threadIdx.x < o) sh[threadIdx.x] += sh[threadIdx.x + o];
        __syncthreads();
    }
    if (threadIdx.x == 0) he[b * 32 + i] = fmaxf(sh[0] + bias[i], 0.f);
}

__device__ void dev_vae_mid(const float* __restrict__ he,
                            const float* __restrict__ muw, const float* __restrict__ mub,
                            const float* __restrict__ lvw, const float* __restrict__ lvb,
                            const float* __restrict__ d1w, const float* __restrict__ d1b,
                            const float* __restrict__ eps, float* hdc, float* klout, float* zs) {
    int t = threadIdx.x;
    if (t < 64) {
        int b = t >> 4, l = t & 15;
        float mu = mub[l], lv = lvb[l];
        for (int i = 0; i < 32; i++) {
            float hv = he[b * 32 + i];
            mu += hv * muw[l * 32 + i];
            lv += hv * lvw[l * 32 + i];
        }
        zs[t] = mu + eps[t] * expf(0.5f * lv);
        float kterm = 1.f + lv - mu * mu - expf(lv);
        for (int o = 32; o > 0; o >>= 1) kterm += __shfl_xor(kterm, o, 64);
        if (t == 0) klout[0] = -0.5f * kterm * 0.25f;
    }
    __syncthreads();
    if (t < 128) {
        int b = t >> 5, i = t & 31;
        float a = d1b[i];
        for (int l = 0; l < 16; l++) a += zs[b * 16 + l] * d1w[i * 16 + l];
        hdc[t] = fmaxf(a, 0.f);
    }
}

__device__ void dev_edge_deg(int bid, const int* __restrict__ ei, const float* __restrict__ w,
                             float* deg, int E) {
    int e = bid * 256 + threadIdx.x;
    if (e < E) atomicAdd(&deg[ei[E + e]], w[e]);
}

__device__ void dev_cs_part(int bid, const float* __restrict__ X, int N,
                            float* sum, float* sumsq, float* sh) {
    int t = threadIdx.x;
    int col = t & 63, ro = t >> 6;
    int rows = N >> 8;
    int r0 = bid * rows;
    float s = 0.f, q = 0.f;
    for (int r = r0 + ro; r < r0 + rows; r += 4) {
        float v = X[r * 64 + col];
        s += v; q += v * v;
    }
    float* ls = sh; float* lq = sh + 256;
    ls[t] = s; lq[t] = q;
    __syncthreads();
    if (t < 64) {
        for (int j = t + 64; j < 256; j += 64) { s += ls[j]; q += lq[j]; }
        atomicAdd(&sum[t], s);
        atomicAdd(&sumsq[t], q);
    }
}

// grid-stride 4-edge-batched aggregation (deg starts at 0; +1 = self loop)
__device__ void dev_edge_agg(int bid, const int* __restrict__ ei, const float* __restrict__ w,
                             const float* __restrict__ deg, const float* __restrict__ x,
                             float* agg) {
    const int h = threadIdx.x & 63;
    const int wid = bid * 4 + (threadIdx.x >> 6);
    const int nw4 = AGGBLKS * 4 * 4;
    for (int e0 = wid * 4; e0 < E1N; e0 += nw4) {
        int srcs[4], dsts[4];
        float norms[4];
        #pragma unroll
        for (int j = 0; j < 4; j++) {
            int e = e0 + j;
            srcs[j] = ei[e];
            dsts[j] = ei[E1N + e];
            norms[j] = rsqrtf(deg[dsts[j]] + 1.f) * w[e] * rsqrtf(deg[srcs[j]] + 1.f);
        }
        float xv[4];
        #pragma unroll
        for (int j = 0; j < 4; j++) xv[j] = x[srcs[j] * HH + h];
        #pragma unroll
        for (int j = 0; j < 4; j++)
            atomicAdd(&agg[dsts[j] * HH + h], norms[j] * xv[j]);
    }
}

__device__ void dev_pert_edges(int bid, const int* __restrict__ pidx, const int* __restrict__ ei,
                               const float* __restrict__ w, const float* __restrict__ deg,
                               const float* __restrict__ tbl, float* pslot) {
    int e = bid * 256 + threadIdx.x;
    if (e >= E2N) return;
    int dst = ei[E2N + e];
    int src = ei[e];
    for (int s = 0; s < 8; s++) {
        if (pidx[s] == dst) {
            float norm = rsqrtf(deg[dst] + 1.f) * w[e] * rsqrtf(deg[src] + 1.f);
            for (int h = 0; h < 64; h++)
                atomicAdd(&pslot[s * 64 + h], norm * tbl[src * 64 + h]);
        }
    }
}

__device__ void dev_base_combine(int bid, const float* __restrict__ gene_emb,
                                 const float* __restrict__ agg, const float* __restrict__ emb_pos,
                                 const float* __restrict__ deg,
                                 const float* __restrict__ W, const float* __restrict__ bias,
                                 const float* __restrict__ bsum, const float* __restrict__ bsq,
                                 const float* __restrict__ bg, const float* __restrict__ bb,
                                 float* out, float* sh) {
    float* Wt = sh;            // [64][65]
    float* a = sh + 4160;      // [4][64]
    int t = threadIdx.x;
    for (int i = t; i < 4096; i += 256) Wt[(i & 63) * 65 + (i >> 6)] = W[i];
    int rr = t >> 6, h = t & 63;
    int g = bid * 4 + rr;
    a[rr * 64 + h] = agg[g * 64 + h] + emb_pos[g * 64 + h] / (deg[g] + 1.f);
    __syncthreads();
    float y = bias[h];
    const float* ar = a + rr * 64;
    #pragma unroll 8
    for (int k = 0; k < 64; k++) y += ar[k] * Wt[k * 65 + h];
    const float invN = 1.0f / (float)GG;
    float m = bsum[h] * invN;
    float is_ = rsqrtf(bsq[h] * invN - m * m + BNEPS);
    float v = gene_emb[g * 64 + h];
    v = (v - m) * is_ * bg[h] + bb[h];
    v = fmaxf(v, 0.f);
    out[g * 64 + h] = v + 0.2f * y;
}

__device__ void dev_pert_mlp(const float* __restrict__ pslot, const int* __restrict__ pidx,
                             const float* __restrict__ deg, const float* __restrict__ tbl,
                             const float* __restrict__ gw, const float* __restrict__ gb,
                             const float* __restrict__ w1, const float* __restrict__ b1,
                             const float* __restrict__ g1, const float* __restrict__ be1,
                             const float* __restrict__ w2, const float* __restrict__ b2,
                             const float* __restrict__ g2, const float* __restrict__ be2,
                             float* etot, float* sh) {
    float* pge = sh;
    float* psum = sh + 512;
    float* y = sh + 768;
    float* mh = sh + 1024;
    float* ih = sh + 1088;
    int t = threadIdx.x;
    for (int j = t; j < 512; j += 256) {
        int s = j >> 6, h = j & 63;
        int n = pidx[s];
        float invd = 1.0f / (deg[n] + 1.f);
        float acc = gb[h];
        for (int k = 0; k < 64; k++)
            acc += (pslot[s * 64 + k] + tbl[n * 64 + k] * invd) * gw[h * 64 + k];
        pge[j] = acc;
    }
    __syncthreads();
    { int b = t >> 6, h = t & 63; psum[t] = pge[2 * b * 64 + h] + pge[(2 * b + 1) * 64 + h]; }
    __syncthreads();
    { int h = t & 63; int b = t >> 6;
      float acc = b1[h];
      for (int k = 0; k < 64; k++) acc += psum[b * 64 + k] * w1[h * 64 + k];
      y[t] = acc; }
    __syncthreads();
    if (t < 64) {
        float s = 0.f, sq = 0.f;
        for (int b = 0; b < 4; b++) { float v = y[b * 64 + t]; s += v; sq += v * v; }
        float m = s * 0.25f;
        mh[t] = m; ih[t] = rsqrtf(sq * 0.25f - m * m + BNEPS);
    }
    __syncthreads();
    { int h = t & 63;
      float v = (y[t] - mh[h]) * ih[h] * g1[h] + be1[h];
      psum[t] = fmaxf(v, 0.f); }
    __syncthreads();
    { int h = t & 63; int b = t >> 6;
      float acc = b2[h];
      for (int k = 0; k < 64; k++) acc += psum[b * 64 + k] * w2[h * 64 + k];
      y[t] = acc; }
    __syncthreads();
    if (t < 64) {
        float s = 0.f, sq = 0.f;
        for (int b = 0; b < 4; b++) { float v = y[b * 64 + t]; s += v; sq += v * v; }
        float m = s * 0.25f;
        mh[t] = m; ih[t] = rsqrtf(sq * 0.25f - m * m + BNEPS);
    }
    __syncthreads();
    { int h = t & 63;
      etot[t] = (y[t] - mh[h]) * ih[h] * g2[h] + be2[h]; }
}

// ================= fat kernels =================
// K12: edge_deg co(320) | edge_deg go(320) | cs_part gene_emb(256) | vae_he(128) | W->bf16(256)
__global__ void k_fat12(float* ws, const int* __restrict__ ei_co, const float* __restrict__ w_co,
                        const int* __restrict__ ei_go, const float* __restrict__ w_go,
                        const float* __restrict__ gene_emb, const float* __restrict__ x,
                        const float* __restrict__ ve1_w, const float* __restrict__ ve1_b,
                        const float* __restrict__ ff1_w, const float* __restrict__ ff2_w) {
    __shared__ float sh[512];
    int bid = blockIdx.x;
    if (bid < 320) dev_edge_deg(bid, ei_co, w_co, ws + OF_DEGCO, E1N);
    else if (bid < 640) dev_edge_deg(bid - 320, ei_go, w_go, ws + OF_DEGGO, E2N);
    else if (bid < 896) dev_cs_part(bid - 640, gene_emb, GG, ws + OF_STATS, ws + OF_STATS + 128, sh);
    else if (bid < 1024) dev_vae_he(bid - 896, x, ve1_w, ve1_b, ws + OF_HE, sh);
    else {
        int i = (bid - 1024) * 256 + threadIdx.x;   // 256 blocks -> 65536
        ushort_t* W1b = (ushort_t*)(ws + OF_W1B);
        ushort_t* W2b = (ushort_t*)(ws + OF_W2B);
        if (i < 32768) W1b[i] = f2b(ff1_w[i]);
        else W2b[i - 32768] = f2b(ff2_w[i - 32768]);
    }
}

// K3: edge_agg(AGGBLKS) | pert_edges(320) | vae_mid(1)
__global__ void k_fat3(float* ws, const int* __restrict__ ei_co, const float* __restrict__ w_co,
                       const float* __restrict__ emb_pos, const int* __restrict__ pidx,
                       const int* __restrict__ ei_go, const float* __restrict__ w_go,
                       const float* __restrict__ pert_tbl,
                       const float* __restrict__ vmu_w, const float* __restrict__ vmu_b,
                       const float* __restrict__ vlv_w, const float* __restrict__ vlv_b,
                       const float* __restrict__ vd1_w, const float* __restrict__ vd1_b,
                       const float* __restrict__ veps, float* klout) {
    __shared__ float sh[512];
    int bid = blockIdx.x;
    if (bid < AGGBLKS) dev_edge_agg(bid, ei_co, w_co, ws + OF_DEGCO, emb_pos, ws + OF_AGGCO);
    else if (bid < AGGBLKS + 320)
        dev_pert_edges(bid - AGGBLKS, pidx, ei_go, w_go, ws + OF_DEGGO, pert_tbl, ws + OF_PSLOT);
    else dev_vae_mid(ws + OF_HE, vmu_w, vmu_b, vlv_w, vlv_b, vd1_w, vd1_b, veps,
                     ws + OF_HDC, klout, sh);
}

// K4: base_combine(1024) | pert_mlp(1)
__global__ void k_fat4(float* ws, const float* __restrict__ gene_emb,
                       const float* __restrict__ emb_pos,
                       const float* __restrict__ sg_co_w, const float* __restrict__ sg_co_b,
                       const float* __restrict__ bn_emb_g, const float* __restrict__ bn_emb_b,
                       const int* __restrict__ pidx, const float* __restrict__ pert_tbl,
                       const float* __restrict__ gw, const float* __restrict__ gb,
                       const float* __restrict__ w1, const float* __restrict__ b1,
                       const float* __restrict__ g1, const float* __restrict__ be1,
                       const float* __restrict__ w2, const float* __restrict__ b2,
                       const float* __restrict__ g2, const float* __restrict__ be2) {
    __shared__ float sh[4416];
    int bid = blockIdx.x;
    if (bid < 1024)
        dev_base_combine(bid, gene_emb, ws + OF_AGGCO, emb_pos, ws + OF_DEGCO,
                         sg_co_w, sg_co_b, ws + OF_STATS, ws + OF_STATS + 128,
                         bn_emb_g, bn_emb_b, ws + OF_BASEIN, sh);
    else
        dev_pert_mlp(ws + OF_PSLOT, pidx, ws + OF_DEGGO, pert_tbl, gw, gb,
                     w1, b1, g1, be1, w2, b2, g2, be2, ws + OF_ETOT, sh);
}

// ================= gemm64 (fp32, etv/rw chain) =================
__launch_bounds__(256)
__global__ void k_gemm64(const float* __restrict__ X, const float* __restrict__ W,
                         const float* __restrict__ bias, float* __restrict__ Y,
                         int Cin, int Cout,
                         const float* __restrict__ bnsum, const float* __restrict__ bnsq,
                         const float* __restrict__ bng, const float* __restrict__ bnb,
                         float invN, int relu_in,
                         float* __restrict__ outsum, float* __restrict__ outsq) {
    __shared__ float Xs[64][66];
    __shared__ float Ws[64][66];
    __shared__ float bsc[64], bsh[64];
    const int t = threadIdx.x;
    const int row0 = blockIdx.x * 64, cb = blockIdx.y * 64;
    const int tx = t & 15, ty = t >> 4;
    const int c0 = tx * 4, r0 = ty * 4;
    float acc[4][4];
    #pragma unroll
    for (int j = 0; j < 4; j++)
        #pragma unroll
        for (int i = 0; i < 4; i++) acc[j][i] = 0.f;

    for (int k0 = 0; k0 < Cin; k0 += 64) {
        __syncthreads();
        if (t < 64) {
            float sc = 1.f, sh = 0.f;
            if (bnsum) {
                int c = k0 + t;
                float m = bnsum[c] * invN;
                float is_ = rsqrtf(bnsq[c] * invN - m * m + BNEPS);
                sc = is_ * bng[c]; sh = bnb[c] - m * sc;
            }
            bsc[t] = sc; bsh[t] = sh;
        }
        __syncthreads();
        for (int i = t; i < 1024; i += 256) {
            int r = i >> 4, kq = (i & 15) * 4;
            float4 v = *(const float4*)&X[(size_t)(row0 + r) * Cin + k0 + kq];
            float e0 = v.x * bsc[kq] + bsh[kq];
            float e1 = v.y * bsc[kq + 1] + bsh[kq + 1];
            float e2 = v.z * bsc[kq + 2] + bsh[kq + 2];
            float e3 = v.w * bsc[kq + 3] + bsh[kq + 3];
            if (relu_in) {
                e0 = fmaxf(e0, 0.f); e1 = fmaxf(e1, 0.f);
                e2 = fmaxf(e2, 0.f); e3 = fmaxf(e3, 0.f);
            }
            Xs[r][kq] = e0; Xs[r][kq + 1] = e1; Xs[r][kq + 2] = e2; Xs[r][kq + 3] = e3;
            float4 wv = *(const float4*)&W[(size_t)(cb + r) * Cin + k0 + kq];
            Ws[r][kq] = wv.x; Ws[r][kq + 1] = wv.y; Ws[r][kq + 2] = wv.z; Ws[r][kq + 3] = wv.w;
        }
        __syncthreads();
        #pragma unroll 4
        for (int k = 0; k < 64; k += 2) {
            float2 a[4], b[4];
            #pragma unroll
            for (int j = 0; j < 4; j++) a[j] = *(const float2*)&Xs[r0 + j][k];
            #pragma unroll
            for (int i = 0; i < 4; i++) b[i] = *(const float2*)&Ws[c0 + i][k];
            #pragma unroll
            for (int j = 0; j < 4; j++)
                #pragma unroll
                for (int i = 0; i < 4; i++)
                    acc[j][i] += a[j].x * b[i].x + a[j].y * b[i].y;
        }
    }
    float4 bi = *(const float4*)&bias[cb + c0];
    float scol[4] = {0.f, 0.f, 0.f, 0.f}, qcol[4] = {0.f, 0.f, 0.f, 0.f};
    #pragma unroll
    for (int j = 0; j < 4; j++) {
        float4 o;
        o.x = acc[j][0] + bi.x; o.y = acc[j][1] + bi.y;
        o.z = acc[j][2] + bi.z; o.w = acc[j][3] + bi.w;
        *(float4*)&Y[(size_t)(row0 + r0 + j) * Cout + cb + c0] = o;
        scol[0] += o.x; scol[1] += o.y; scol[2] += o.z; scol[3] += o.w;
        qcol[0] += o.x * o.x; qcol[1] += o.y * o.y;
        qcol[2] += o.z * o.z; qcol[3] += o.w * o.w;
    }
    if (outsum) {
        __syncthreads();
        #pragma unroll
        for (int i = 0; i < 4; i++) { Xs[ty][c0 + i] = scol[i]; Ws[ty][c0 + i] = qcol[i]; }
        __syncthreads();
        if (t < 64) {
            float ss = 0.f, qq = 0.f;
            #pragma unroll
            for (int r = 0; r < 16; r++) { ss += Xs[r][t]; qq += Ws[r][t]; }
            atomicAdd(&outsum[cb + t], ss);
            atomicAdd(&outsq[cb + t], qq);
        }
    }
}

// ================= rw1 gemm with analytic flat stats (no flatpre) =================
__launch_bounds__(256)
__global__ void k_gemm_rw1(const float* __restrict__ y2, const float* __restrict__ etot,
                           const float* __restrict__ s2sum, const float* __restrict__ s2sq,
                           const float* __restrict__ g2e, const float* __restrict__ b2e,
                           const float* __restrict__ g3, const float* __restrict__ b3,
                           const float* __restrict__ W, const float* __restrict__ bias,
                           float* __restrict__ Y,
                           float* __restrict__ osum, float* __restrict__ osq) {
    __shared__ float Xs[64][66];
    __shared__ float Ws[64][66];
    __shared__ float bsc[64], bsh[64];
    const int t = threadIdx.x;
    const int row0 = blockIdx.x * 64, cb = blockIdx.y * 64;
    const int tx = t & 15, ty = t >> 4;
    const int c0 = tx * 4, r0 = ty * 4;
    const int bb = row0 >> 12;
    if (t < 64) {
        const float iG = 1.0f / 4096.f, iNG = 1.0f / 16384.f;
        float S1 = s2sum[t], S2 = s2sq[t];
        float m2 = S1 * iG;
        float is2 = rsqrtf(S2 * iG - m2 * m2 + BNEPS);
        float sc2 = is2 * g2e[t], sh2 = b2e[t] - m2 * sc2;
        float sz = sc2 * S1 + 4096.f * sh2;
        float szz = sc2 * sc2 * S2 + 2.f * sc2 * sh2 * S1 + 4096.f * sh2 * sh2;
        float e0 = etot[t], e1 = etot[64 + t], e2 = etot[128 + t], e3 = etot[192 + t];
        float se = e0 + e1 + e2 + e3;
        float see = e0 * e0 + e1 * e1 + e2 * e2 + e3 * e3;
        float sumF = 4.f * sz + 4096.f * se;
        float sqF = 4.f * szz + 2.f * sz * se + 4096.f * see;
        float m3 = sumF * iNG;
        float is3 = rsqrtf(sqF * iNG - m3 * m3 + BNEPS);
        float eb = etot[bb * 64 + t];
        bsc[t] = sc2 * is3 * g3[t];
        bsh[t] = (sh2 + eb - m3) * is3 * g3[t] + b3[t];
    }
    __syncthreads();
    for (int i = t; i < 1024; i += 256) {
        int r = i >> 4, kq = (i & 15) * 4;
        int g = (row0 + r) & 4095;
        float4 v = *(const float4*)&y2[(size_t)g * 64 + kq];
        Xs[r][kq] = fmaxf(v.x * bsc[kq] + bsh[kq], 0.f);
        Xs[r][kq + 1] = fmaxf(v.y * bsc[kq + 1] + bsh[kq + 1], 0.f);
        Xs[r][kq + 2] = fmaxf(v.z * bsc[kq + 2] + bsh[kq + 2], 0.f);
        Xs[r][kq + 3] = fmaxf(v.w * bsc[kq + 3] + bsh[kq + 3], 0.f);
        float4 wv = *(const float4*)&W[(size_t)(cb + r) * 64 + kq];
        Ws[r][kq] = wv.x; Ws[r][kq + 1] = wv.y; Ws[r][kq + 2] = wv.z; Ws[r][kq + 3] = wv.w;
    }
    __syncthreads();
    float acc[4][4];
    #pragma unroll
    for (int j = 0; j < 4; j++)
        #pragma unroll
        for (int i = 0; i < 4; i++) acc[j][i] = 0.f;
    #pragma unroll 4
    for (int k = 0; k < 64; k += 2) {
        float2 a[4], b[4];
        #pragma unroll
        for (int j = 0; j < 4; j++) a[j] = *(const float2*)&Xs[r0 + j][k];
        #pragma unroll
        for (int i = 0; i < 4; i++) b[i] = *(const float2*)&Ws[c0 + i][k];
        #pragma unroll
        for (int j = 0; j < 4; j++)
            #pragma unroll
            for (int i = 0; i < 4; i++)
                acc[j][i] += a[j].x * b[i].x + a[j].y * b[i].y;
    }
    float4 bi = *(const float4*)&bias[cb + c0];
    float scol[4] = {0.f, 0.f, 0.f, 0.f}, qcol[4] = {0.f, 0.f, 0.f, 0.f};
    #pragma unroll
    for (int j = 0; j < 4; j++) {
        float4 o;
        o.x = acc[j][0] + bi.x; o.y = acc[j][1] + bi.y;
        o.z = acc[j][2] + bi.z; o.w = acc[j][3] + bi.w;
        *(float4*)&Y[(size_t)(row0 + r0 + j) * 128 + cb + c0] = o;
        scol[0] += o.x; scol[1] += o.y; scol[2] += o.z; scol[3] += o.w;
        qcol[0] += o.x * o.x; qcol[1] += o.y * o.y;
        qcol[2] += o.z * o.z; qcol[3] += o.w * o.w;
    }
    __syncthreads();
    #pragma unroll
    for (int i = 0; i < 4; i++) { Xs[ty][c0 + i] = scol[i]; Ws[ty][c0 + i] = qcol[i]; }
    __syncthreads();
    if (t < 64) {
        float ss = 0.f, qq = 0.f;
        #pragma unroll
        for (int r = 0; r < 16; r++) { ss += Xs[r][t]; qq += Ws[r][t]; }
        atomicAdd(&osum[cb + t], ss);
        atomicAdd(&osq[cb + t], qq);
    }
}

// ================= fused QKV gemm =================
__launch_bounds__(256)
__global__ void k_gemm_qkv(const float* __restrict__ X, const float* __restrict__ W,
                           const float* __restrict__ bias,
                           const float* __restrict__ bnsum, const float* __restrict__ bnsq,
                           const float* __restrict__ bng, const float* __restrict__ bnb,
                           ushort_t* __restrict__ Qb, ushort_t* __restrict__ Kb,
                           ushort_t* __restrict__ Vf) {
    __shared__ float Xs[64][66];
    __shared__ float Ws[64][66];
    __shared__ float bsc[64], bsh[64];
    const int t = threadIdx.x;
    const int row0 = blockIdx.x * 64, yb = blockIdx.y, cb = yb * 64;
    const int tx = t & 15, ty = t >> 4;
    const int c0 = tx * 4, r0 = ty * 4;
    const float invN = 1.0f / (float)(BB * GG);
    if (t < 64) {
        float m = bnsum[t] * invN;
        float is_ = rsqrtf(bnsq[t] * invN - m * m + BNEPS);
        float sc = is_ * bng[t];
        bsc[t] = sc; bsh[t] = bnb[t] - m * sc;
    }
    __syncthreads();
    for (int i = t; i < 1024; i += 256) {
        int r = i >> 4, kq = (i & 15) * 4;
        float4 v = *(const float4*)&X[(size_t)(row0 + r) * 64 + kq];
        Xs[r][kq] = v.x * bsc[kq] + bsh[kq];
        Xs[r][kq + 1] = v.y * bsc[kq + 1] + bsh[kq + 1];
        Xs[r][kq + 2] = v.z * bsc[kq + 2] + bsh[kq + 2];
        Xs[r][kq + 3] = v.w * bsc[kq + 3] + bsh[kq + 3];
        float4 wv = *(const float4*)&W[(size_t)(cb + r) * 64 + kq];
        Ws[r][kq] = wv.x; Ws[r][kq + 1] = wv.y; Ws[r][kq + 2] = wv.z; Ws[r][kq + 3] = wv.w;
    }
    __syncthreads();
    float acc[4][4];
    #pragma unroll
    for (int j = 0; j < 4; j++)
        #pragma unroll
        for (int i = 0; i < 4; i++) acc[j][i] = 0.f;
    #pragma unroll 4
    for (int k = 0; k < 64; k += 2) {
        float2 a[4], b[4];
        #pragma unroll
        for (int j = 0; j < 4; j++) a[j] = *(const float2*)&Xs[r0 + j][k];
        #pragma unroll
        for (int i = 0; i < 4; i++) b[i] = *(const float2*)&Ws[c0 + i][k];
        #pragma unroll
        for (int j = 0; j < 4; j++)
            #pragma unroll
            for (int i = 0; i < 4; i++)
                acc[j][i] += a[j].x * b[i].x + a[j].y * b[i].y;
    }
    float4 bi = *(const float4*)&bias[cb + c0];
    const int b2 = row0 >> 12, tile = (row0 & 4095) >> 6;
    if (yb < 2) {
        ushort_t* Dst = (yb == 0) ? Qb : Kb;
        const float sc2 = (yb == 0) ? QPRE : 1.0f;
        const int h = c0 >> 5, d = c0 & 31;
        #pragma unroll
        for (int j = 0; j < 4; j++) {
            union { ushort_t u[4]; uint2 v; } pk;
            pk.u[0] = f2b((acc[j][0] + bi.x) * sc2);
            pk.u[1] = f2b((acc[j][1] + bi.y) * sc2);
            pk.u[2] = f2b((acc[j][2] + bi.z) * sc2);
            pk.u[3] = f2b((acc[j][3] + bi.w) * sc2);
            int g = (row0 & 4095) + r0 + j;
            *(uint2*)&Dst[((size_t)(b2 * 2 + h) * GG + g) * 32 + d] = pk.v;
        }
    } else {
        __syncthreads();
        #pragma unroll
        for (int j = 0; j < 4; j++) {
            Xs[r0 + j][c0] = acc[j][0] + bi.x;
            Xs[r0 + j][c0 + 1] = acc[j][1] + bi.y;
            Xs[r0 + j][c0 + 2] = acc[j][2] + bi.z;
            Xs[r0 + j][c0 + 3] = acc[j][3] + bi.w;
        }
        __syncthreads();
        #pragma unroll
        for (int h = 0; h < 2; h++) {
            union { ushort_t u[8]; uint4 v; } pk;
            #pragma unroll
            for (int j = 0; j < 8; j++) {
                int idx = t * 8 + j;
                int g2 = idx >> 8, L = (idx >> 2) & 63, i = idx & 3;
                int key = (g2 >> 1) * 16 + ((L >> 4) << 2) + i;
                int d = ((g2 & 1) << 4) + (L & 15);
                pk.u[j] = f2b(Xs[key][h * 32 + d]);
            }
            *(uint4*)&Vf[((size_t)((b2 * 2 + h) * 64 + tile)) * 2048 + t * 8] = pk.v;
        }
    }
}

// ---- MFMA flash attention, 4-bh per block ----
__launch_bounds__(512, 4)
__global__ void k_attn_mfma(const ushort_t* __restrict__ Qb, const ushort_t* __restrict__ Kb,
                            const ushort_t* __restrict__ Vf, const float* __restrict__ mask,
                            float* __restrict__ opA, float* __restrict__ opB,
                            float* __restrict__ Lp) {
    __shared__ ushort_t Kl[2][4][2048];
    __shared__ ushort_t Vl[2][4][2048];
    const int split = blockIdx.y;
    const int bh0 = blockIdx.z * 4;
    const int q0 = blockIdx.x * 64;
    const int kstart = split * (GG / 4), kend = kstart + (GG / 4);
    const int t = threadIdx.x;
    const int lane = t & 63, w = t >> 6;
    const int qg = w >> 1, kh = w & 1;
    const int l15 = lane & 15, quad = lane >> 4;
    const int i2a = kh * 2, i2b = kh * 2 + 1;

    sh8 qf[4];
    #pragma unroll
    for (int bh = 0; bh < 4; bh++)
        qf[bh] = *(const sh8*)&Qb[((size_t)(bh0 + bh) * GG + q0 + qg * 16 + l15) * 32 + quad * 8];
    const float* mrow = mask + (size_t)(q0 + qg * 16 + l15) * GG + quad * 4;

    auto stage = [&](int buf, int k0) {
        #pragma unroll
        for (int s = 0; s < 2; s++) {
            int idx = s * 512 + t;
            int bh = idx >> 8, c = idx & 255;
            int key = ((c >> 6) << 4) + (c & 15);
            int chunk = (c >> 4) & 3;
            gld16(Kb + ((size_t)(bh0 + bh) * GG + k0 + key) * 32 + chunk * 8,
                  &Kl[buf][bh][c * 8]);
            gld16(Vf + ((size_t)((bh0 + bh) * 64 + (k0 >> 6))) * 2048 + c * 8,
                  &Vl[buf][bh][c * 8]);
        }
    };
    stage(0, kstart);

    f4 O0[4], O1[4];
    float ls[4];
    #pragma unroll
    for (int bh = 0; bh < 4; bh++) {
        O0[bh] = f4{0.f, 0.f, 0.f, 0.f};
        O1[bh] = f4{0.f, 0.f, 0.f, 0.f};
        ls[bh] = 0.f;
    }

    for (int k0 = kstart; k0 < kend; k0 += 64) {
        const int cur = ((k0 - kstart) >> 6) & 1;
        __syncthreads();
        if (k0 + 64 < kend) stage(cur ^ 1, k0 + 64);
        float4 mva = *(const float4*)&mrow[k0 + i2a * 16];
        float4 mvb = *(const float4*)&mrow[k0 + i2b * 16];
        #pragma unroll
        for (int bh = 0; bh < 4; bh++) {
            sh8 kfa = *(const sh8*)&Kl[cur][bh][(i2a * 64 + lane) * 8];
            sh8 kfb = *(const sh8*)&Kl[cur][bh][(i2b * 64 + lane) * 8];
            f4 z = {0.f, 0.f, 0.f, 0.f};
            f4 sa = __builtin_amdgcn_mfma_f32_16x16x32_bf16(kfa, qf[bh], z, 0, 0, 0);
            f4 sb = __builtin_amdgcn_mfma_f32_16x16x32_bf16(kfb, qf[bh], z, 0, 0, 0);
            {
                float p0 = exp2f(fmaf(mva.x, LOG2E, sa[0]));
                float p1 = exp2f(fmaf(mva.y, LOG2E, sa[1]));
                float p2 = exp2f(fmaf(mva.z, LOG2E, sa[2]));
                float p3 = exp2f(fmaf(mva.w, LOG2E, sa[3]));
                ls[bh] += (p0 + p1) + (p2 + p3);
                union { __hip_bfloat162 h2[2]; sh4 v; } pkp;
                pkp.h2[0] = __float22bfloat162_rn(float2{p0, p1});
                pkp.h2[1] = __float22bfloat162_rn(float2{p2, p3});
                sh4 vf0 = *(const sh4*)&Vl[cur][bh][((i2a * 2 + 0) * 64 + lane) * 4];
                sh4 vf1 = *(const sh4*)&Vl[cur][bh][((i2a * 2 + 1) * 64 + lane) * 4];
                O0[bh] = MFMA16(pkp.v, vf0, O0[bh]);
                O1[bh] = MFMA16(pkp.v, vf1, O1[bh]);
            }
            {
                float p0 = exp2f(fmaf(mvb.x, LOG2E, sb[0]));
                float p1 = exp2f(fmaf(mvb.y, LOG2E, sb[1]));
                float p2 = exp2f(fmaf(mvb.z, LOG2E, sb[2]));
                float p3 = exp2f(fmaf(mvb.w, LOG2E, sb[3]));
                ls[bh] += (p0 + p1) + (p2 + p3);
                union { __hip_bfloat162 h2[2]; sh4 v; } pkp;
                pkp.h2[0] = __float22bfloat162_rn(float2{p0, p1});
                pkp.h2[1] = __float22bfloat162_rn(float2{p2, p3});
                sh4 vf0 = *(const sh4*)&Vl[cur][bh][((i2b * 2 + 0) * 64 + lane) * 4];
                sh4 vf1 = *(const sh4*)&Vl[cur][bh][((i2b * 2 + 1) * 64 + lane) * 4];
                O0[bh] = MFMA16(pkp.v, vf0, O0[bh]);
                O1[bh] = MFMA16(pkp.v, vf1, O1[bh]);
            }
        }
    }
    #pragma unroll
    for (int bh = 0; bh < 4; bh++) {
        ls[bh] += __shfl_xor(ls[bh], 16, 64);
        ls[bh] += __shfl_xor(ls[bh], 32, 64);
    }
    __syncthreads();
    float* Ox = (float*)&Kl[0][0][0];
    float* Lx = (float*)&Vl[0][0][0];
    if (kh == 0) {
        #pragma unroll
        for (int bh = 0; bh < 4; bh++) {
            #pragma unroll
            for (int r = 0; r < 4; r++) {
                int ql = qg * 16 + quad * 4 + r;
                Ox[(bh * 64 + ql) * 32 + l15] = O0[bh][r];
                Ox[(bh * 64 + ql) * 32 + l15 + 16] = O1[bh][r];
            }
            if (quad == 0) Lx[bh * 64 + qg * 16 + l15] = ls[bh];
        }
    }
    __syncthreads();
    if (kh == 1) {
        float* op = (split < 3) ? (opA + (size_t)split * OPS) : opB;
        #pragma unroll
        for (int bh = 0; bh < 4; bh++) {
            int gbh = bh0 + bh;
            #pragma unroll
            for (int r = 0; r < 4; r++) {
                int ql = qg * 16 + quad * 4 + r;
                size_t o = ((size_t)gbh * GG + q0 + ql) * 32 + l15;
                op[o] = O0[bh][r] + Ox[(bh * 64 + ql) * 32 + l15];
                op[o + 16] = O1[bh][r] + Ox[(bh * 64 + ql) * 32 + l15 + 16];
            }
            if (quad == 0)
                Lp[split * 32768 + gbh * GG + q0 + qg * 16 + l15] =
                    ls[bh] + Lx[bh * 64 + qg * 16 + l15];
        }
    }
}

// ===== fused tail: combine + attn-out + LN1 + FFN1 + FFN2 + LN2 + heads (256 blocks) =====
__launch_bounds__(256)
__global__ void k_tail(const float* __restrict__ opA, const float* __restrict__ opB,
                       const float* __restrict__ Lp, const float* __restrict__ yrw2,
                       const float* __restrict__ Waout, const float* __restrict__ baout,
                       const float* __restrict__ bsum5, const float* __restrict__ bsq5,
                       const float* __restrict__ bg5, const float* __restrict__ bb5,
                       const float* __restrict__ lg1, const float* __restrict__ lb1,
                       const ushort_t* __restrict__ W1b, const float* __restrict__ b1f,
                       const ushort_t* __restrict__ W2b, const float* __restrict__ b2f,
                       const float* __restrict__ lg2, const float* __restrict__ lb2,
                       const float* __restrict__ indvw, const float* __restrict__ indvb,
                       const float* __restrict__ hdc, const float* __restrict__ d2w,
                       const float* __restrict__ d2b, const float* __restrict__ x,
                       float* __restrict__ outp) {
    __shared__ float Wt[4160];      // aout_w^T; reused as h1f[64][65]
    __shared__ float Cs[4160];      // ctx [64][65]
    __shared__ ushort_t Hb[4096];   // h1 bf16 frags
    __shared__ ushort_t FT[32768];  // fft tile [w][16][64][8]
    __shared__ ushort_t WS[2][4096];
    const int t = threadIdx.x;
    const int r0b = blockIdx.x * 64;
    const int lane = t & 63, w = t >> 6;
    const int l15 = lane & 15, quad = lane >> 4;

    // stage aout_w^T + combine ctx
    for (int i = t; i < 4096; i += 256) Wt[(i & 63) * 65 + (i >> 6)] = Waout[i];
    {
        int col = t & 63, rl = t >> 6;
        int hh = col >> 5, d = col & 31;
        for (int jj = 0; jj < 16; jj++) {
            int lrow = rl + jj * 4;
            int row = r0b + lrow;
            int b = row >> 12, q = row & 4095;
            int bhq = (b * 2 + hh) * GG + q;
            size_t oi = (size_t)bhq * 32 + d;
            float num = opA[oi] + opA[OPS + oi] + opA[2 * OPS + oi] + opB[oi];
            float den = Lp[bhq] + Lp[32768 + bhq] + Lp[65536 + bhq] + Lp[98304 + bhq];
            Cs[lrow * 65 + col] = num / den;
        }
    }
    __syncthreads();
    // attn-out gemm + LN1; group w handles rows w*16..+15
    const float invN = 1.0f / (float)(BB * GG);
    float m5 = bsum5[lane] * invN;
    float is5 = rsqrtf(bsq5[lane] * invN - m5 * m5 + BNEPS);
    float h1v[16];
    for (int j = 0; j < 16; j++) {
        int lrow = w * 16 + j;
        int row = r0b + lrow;
        float acc = baout[lane];
        const float* cr = Cs + lrow * 65;
        #pragma unroll 8
        for (int k = 0; k < 64; k++) acc += cr[k] * Wt[k * 65 + lane];
        float ov = (yrw2[(size_t)row * 64 + lane] - m5) * is5 * bg5[lane] + bb5[lane];
        float v = ov + acc;
        float s = v;
        for (int o = 32; o > 0; o >>= 1) s += __shfl_xor(s, o, 64);
        float mean = s * (1.f / 64.f);
        float d = v - mean;
        float sq = d * d;
        for (int o = 32; o > 0; o >>= 1) sq += __shfl_xor(sq, o, 64);
        float inv = rsqrtf(sq * (1.f / 64.f) + BNEPS);
        h1v[j] = d * inv * lg1[lane] + lb1[lane];
    }
    __syncthreads();               // done reading Wt/Cs
    float* h1f = Wt;               // reuse as [64][65]
    for (int j = 0; j < 16; j++) h1f[(w * 16 + j) * 65 + lane] = h1v[j];
    __syncthreads();
    // pack h1 bf16 frags
    if (t < 128) {
        int kt = t >> 6, lane6 = t & 63;
        int q2 = (lane6 >> 4) & 3, r15 = lane6 & 15;
        for (int rg = 0; rg < 4; rg++) {
            union { ushort_t u[8]; uint4 v4; } pk;
            #pragma unroll
            for (int j = 0; j < 8; j++)
                pk.u[j] = f2b(h1f[(rg * 16 + r15) * 65 + kt * 32 + q2 * 8 + j]);
            *(uint4*)&Hb[(rg * 2 + kt) * 512 + lane6 * 8] = pk.v4;
        }
    }
    // FFN1: 8 colblocks, double-buffered weight staging
    auto stage1 = [&](int buf, int cb8) {
        int cb = cb8 * 64;
        #pragma unroll
        for (int kt = 0; kt < 2; kt++)
            gld16(W1b + (size_t)((cb + w * 16 + l15) * 64 + kt * 32 + quad * 8),
                  &WS[buf][(w * 2 + kt) * 512 + lane * 8]);
    };
    stage1(0, 0);
    for (int cb8 = 0; cb8 < 8; cb8++) {
        const int cur = cb8 & 1;
        __syncthreads();           // WS[cur] DMA done (+ Hb writes on first iter)
        if (cb8 + 1 < 8) stage1(cur ^ 1, cb8 + 1);
        sh8 xf0 = *(const sh8*)&Hb[(w * 2 + 0) * 512 + lane * 8];
        sh8 xf1 = *(const sh8*)&Hb[(w * 2 + 1) * 512 + lane * 8];
        const int cb = cb8 * 64;
        #pragma unroll
        for (int c = 0; c < 4; c++) {
            sh8 wf0 = *(const sh8*)&WS[cur][(c * 2 + 0) * 512 + lane * 8];
            sh8 wf1 = *(const sh8*)&WS[cur][(c * 2 + 1) * 512 + lane * 8];
            f4 z = {0.f, 0.f, 0.f, 0.f};
            f4 acc = __builtin_amdgcn_mfma_f32_16x16x32_bf16(wf0, xf0, z, 0, 0, 0);
            acc = __builtin_amdgcn_mfma_f32_16x16x32_bf16(wf1, xf1, acc, 0, 0, 0);
            float4 bv = *(const float4*)&b1f[cb + c * 16 + quad * 4];
            union { ushort_t u[4]; uint2 v2; } pk;
            pk.u[0] = f2b(fmaxf(acc[0] + bv.x, 0.f));
            pk.u[1] = f2b(fmaxf(acc[1] + bv.y, 0.f));
            pk.u[2] = f2b(fmaxf(acc[2] + bv.z, 0.f));
            pk.u[3] = f2b(fmaxf(acc[3] + bv.w, 0.f));
            int kt512 = cb8 * 2 + (c >> 1);
            int quadp = (c & 1) * 2 + (quad >> 1);
            int j0 = (quad & 1) * 4;
            *(uint2*)&FT[((w * 16 + kt512) * 64 + quadp * 16 + l15) * 8 + j0] = pk.v2;
        }
    }
    // FFN2: K=512, double-buffered weight staging, x-frags from FT
    auto stage2 = [&](int buf, int k0) {
        #pragma unroll
        for (int kt = 0; kt < 2; kt++)
            gld16(W2b + (size_t)((w * 16 + l15) * 512 + k0 + kt * 32 + quad * 8),
                  &WS[buf][(w * 2 + kt) * 512 + lane * 8]);
    };
    stage2(0, 0);
    f4 acc2[4];
    #pragma unroll
    for (int c = 0; c < 4; c++) acc2[c] = f4{0.f, 0.f, 0.f, 0.f};
    for (int k0 = 0; k0 < 512; k0 += 64) {
        const int cur = (k0 >> 6) & 1;
        __syncthreads();           // WS[cur] DMA done + (first iter) FT writes visible
        if (k0 + 64 < 512) stage2(cur ^ 1, k0 + 64);
        const int ktb = k0 >> 5;
        #pragma unroll
        for (int kt = 0; kt < 2; kt++) {
            sh8 xf = *(const sh8*)&FT[((w * 16 + ktb + kt) * 64 + lane) * 8];
            #pragma unroll
            for (int c = 0; c < 4; c++) {
                sh8 wf = *(const sh8*)&WS[cur][(c * 2 + kt) * 512 + lane * 8];
                acc2[c] = __builtin_amdgcn_mfma_f32_16x16x32_bf16(wf, xf, acc2[c], 0, 0, 0);
            }
        }
    }
    // epilogue: LN2 + per-gene head + recon
    const int row = r0b + w * 16 + l15;
    const int b = row >> 12, g = row & 4095;
    float v[4][4];
    float s = 0.f, sq = 0.f;
    #pragma unroll
    for (int c = 0; c < 4; c++) {
        float4 bv = *(const float4*)&b2f[c * 16 + quad * 4];
        #pragma unroll
        for (int i = 0; i < 4; i++) {
            float hv = h1f[(w * 16 + l15) * 65 + c * 16 + quad * 4 + i];
            float bvi = (i == 0) ? bv.x : (i == 1) ? bv.y : (i == 2) ? bv.z : bv.w;
            v[c][i] = hv + acc2[c][i] + bvi;
            s += v[c][i]; sq += v[c][i] * v[c][i];
        }
    }
    s += __shfl_xor(s, 16, 64);  s += __shfl_xor(s, 32, 64);
    sq += __shfl_xor(sq, 16, 64); sq += __shfl_xor(sq, 32, 64);
    float mean = s * (1.f / 64.f);
    float inv = rsqrtf(sq * (1.f / 64.f) - mean * mean + BNEPS);
    float pd = 0.f;
    #pragma unroll
    for (int c = 0; c < 4; c++) {
        float4 lgv = *(const float4*)&lg2[c * 16 + quad * 4];
        float4 lbv = *(const float4*)&lb2[c * 16 + quad * 4];
        float4 iwv = *(const float4*)&indvw[(size_t)g * 64 + c * 16 + quad * 4];
        pd += ((v[c][0] - mean) * inv * lgv.x + lbv.x) * iwv.x;
        pd += ((v[c][1] - mean) * inv * lgv.y + lbv.y) * iwv.y;
        pd += ((v[c][2] - mean) * inv * lgv.z + lbv.z) * iwv.z;
        pd += ((v[c][3] - mean) * inv * lgv.w + lbv.w) * iwv.w;
    }
    float rc = 0.f;
    #pragma unroll
    for (int i = 0; i < 8; i++)
        rc += hdc[b * 32 + quad * 8 + i] * d2w[(size_t)g * 32 + quad * 8 + i];
    pd += __shfl_xor(pd, 16, 64); pd += __shfl_xor(pd, 32, 64);
    rc += __shfl_xor(rc, 16, 64); rc += __shfl_xor(rc, 32, 64);
    if (quad == 0) {
        float recon = rc + d2b[g];
        if (x[row] == 0.f) recon = 0.f;
        outp[row] = pd + indvb[g] + recon;
    }
}

extern "C" void kernel_launch(void* const* d_in, const int* in_sizes, int n_in,
                              void* d_out, int out_size, void* d_ws, size_t ws_size,
                              hipStream_t stream) {
    const float* x        = (const float*)d_in[0];
    const int*   pert_idx = (const int*)  d_in[1];
    const float* mask     = (const float*)d_in[2];
    const int*   ei_co    = (const int*)  d_in[3];
    const float* w_co     = (const float*)d_in[4];
    const int*   ei_go    = (const int*)  d_in[5];
    const float* w_go     = (const float*)d_in[6];
    const float* gene_emb = (const float*)d_in[7];
    const float* emb_pos  = (const float*)d_in[8];
    const float* pert_tbl = (const float*)d_in[9];
    const float* sg_co_w  = (const float*)d_in[10];
    const float* sg_co_b  = (const float*)d_in[11];
    const float* sg_go_w  = (const float*)d_in[12];
    const float* sg_go_b  = (const float*)d_in[13];
    const float* bn_emb_g = (const float*)d_in[14];
    const float* bn_emb_b = (const float*)d_in[15];
    const float* etv1_w   = (const float*)d_in[16];
    const float* etv1_b   = (const float*)d_in[17];
    const float* etv1_g   = (const float*)d_in[18];
    const float* etv1_be  = (const float*)d_in[19];
    const float* etv2_w   = (const float*)d_in[20];
    const float* etv2_b   = (const float*)d_in[21];
    const float* etv2_g   = (const float*)d_in[22];
    const float* etv2_be  = (const float*)d_in[23];
    const float* pf1_w    = (const float*)d_in[24];
    const float* pf1_b    = (const float*)d_in[25];
    const float* pf1_g    = (const float*)d_in[26];
    const float* pf1_be   = (const float*)d_in[27];
    const float* pf2_w    = (const float*)d_in[28];
    const float* pf2_b    = (const float*)d_in[29];
    const float* pf2_g    = (const float*)d_in[30];
    const float* pf2_be   = (const float*)d_in[31];
    const float* rw1_w    = (const float*)d_in[32];
    const float* rw1_b    = (const float*)d_in[33];
    const float* rw1_g    = (const float*)d_in[34];
    const float* rw1_be   = (const float*)d_in[35];
    const float* rw2_w    = (const float*)d_in[36];
    const float* rw2_b    = (const float*)d_in[37];
    const float* rw2_g    = (const float*)d_in[38];
    const float* rw2_be   = (const float*)d_in[39];
    const float* bnpb_g   = (const float*)d_in[40];
    const float* bnpb_b   = (const float*)d_in[41];
    const float* ain_w    = (const float*)d_in[42];
    const float* ain_b    = (const float*)d_in[43];
    const float* aout_w   = (const float*)d_in[44];
    const float* aout_b   = (const float*)d_in[45];
    const float* ln1_g    = (const float*)d_in[46];
    const float* ln1_b    = (const float*)d_in[47];
    const float* ff1_w    = (const float*)d_in[48];
    const float* ff1_b    = (const float*)d_in[49];
    const float* ff2_w    = (const float*)d_in[50];
    const float* ff2_b    = (const float*)d_in[51];
    const float* ln2_g    = (const float*)d_in[52];
    const float* ln2_b    = (const float*)d_in[53];
    const float* indv_w   = (const float*)d_in[54];
    const float* indv_b   = (const float*)d_in[55];
    const float* ve1_w    = (const float*)d_in[56];
    const float* ve1_b    = (const float*)d_in[57];
    const float* vmu_w    = (const float*)d_in[58];
    const float* vmu_b    = (const float*)d_in[59];
    const float* vlv_w    = (const float*)d_in[60];
    const float* vlv_b    = (const float*)d_in[61];
    const float* vd1_w    = (const float*)d_in[62];
    const float* vd1_b    = (const float*)d_in[63];
    const float* vd2_w    = (const float*)d_in[64];
    const float* vd2_b    = (const float*)d_in[65];
    const float* veps     = (const float*)d_in[66];

    float* ws   = (float*)d_ws;
    float* outp = (float*)d_out;

    float* stm1 = ws + OF_STATS + 1 * 256; float* sti1 = stm1 + 128;
    float* stm2 = ws + OF_STATS + 2 * 256; float* sti2 = stm2 + 128;
    float* stm4 = ws + OF_STATS + 4 * 256; float* sti4 = stm4 + 128;
    float* stm5 = ws + OF_STATS + 5 * 256; float* sti5 = stm5 + 128;

    float* basein = ws + OF_BASEIN;
    float* y1     = ws + OF_Y1;
    float* y2     = ws + OF_Y2;
    float* yrw1   = ws + OF_RW1;
    float* yrw2   = ws + OF_RW2;
    float* opA    = ws + OF_OPA;
    float* opB    = ws + OF_OPB;
    float* Lp     = ws + OF_LP;
    ushort_t* Qb  = (ushort_t*)(ws + OF_QB);
    ushort_t* Kb  = (ushort_t*)(ws + OF_KB);
    ushort_t* Vf  = (ushort_t*)(ws + OF_VF);
    ushort_t* W1b = (ushort_t*)(ws + OF_W1B);
    ushort_t* W2b = (ushort_t*)(ws + OF_W2B);

    const int NG = BB * GG; // 16384
    const float iG = 1.0f / (float)GG, iNG = 1.0f / (float)NG;

    // zero stats+deg+pslot (contiguous) and aggco via memset nodes
    hipMemsetAsync(ws, 0, 10752 * sizeof(float), stream);
    hipMemsetAsync(ws + OF_AGGCO, 0, (size_t)GG * HH * sizeof(float), stream);

    // K12: degrees, gene_emb stats, vae_he, FFN weight->bf16
    k_fat12<<<1280, 256, 0, stream>>>(ws, ei_co, w_co, ei_go, w_go, gene_emb,
                                      x, ve1_w, ve1_b, ff1_w, ff2_w);
    // K3: edge aggregation + pert edge scan + vae_mid
    k_fat3<<<AGGBLKS + 321, 256, 0, stream>>>(ws, ei_co, w_co, emb_pos, pert_idx,
                                              ei_go, w_go, pert_tbl,
                                              vmu_w, vmu_b, vlv_w, vlv_b, vd1_w, vd1_b,
                                              veps, outp + NG);
    // K4: base_combine + pert MLP
    k_fat4<<<1025, 256, 0, stream>>>(ws, gene_emb, emb_pos, sg_co_w, sg_co_b,
                                     bn_emb_g, bn_emb_b, pert_idx, pert_tbl,
                                     sg_go_w, sg_go_b,
                                     pf1_w, pf1_b, pf1_g, pf1_be,
                                     pf2_w, pf2_b, pf2_g, pf2_be);
    // etv MLP
    k_gemm64<<<dim3(GG / 64, 1), 256, 0, stream>>>(basein, etv1_w, etv1_b, y1, 64, 64,
                                                   nullptr, nullptr, nullptr, nullptr, 0.f, 0,
                                                   stm1, sti1);
    k_gemm64<<<dim3(GG / 64, 1), 256, 0, stream>>>(y1, etv2_w, etv2_b, y2, 64, 64,
                                                   stm1, sti1, etv1_g, etv1_be, iG, 1,
                                                   stm2, sti2);
    // rw MLP (analytic flat stats; no flatpre)
    k_gemm_rw1<<<dim3(NG / 64, 2), 256, 0, stream>>>(y2, ws + OF_ETOT, stm2, sti2,
                                                     etv2_g, etv2_be, bnpb_g, bnpb_b,
                                                     rw1_w, rw1_b, yrw1, stm4, sti4);
    k_gemm64<<<dim3(NG / 64, 1), 256, 0, stream>>>(yrw1, rw2_w, rw2_b, yrw2, 128, 64,
                                                   stm4, sti4, rw1_g, rw1_be, iNG, 1,
                                                   stm5, sti5);
    // transformer
    k_gemm_qkv<<<dim3(NG / 64, 3), 256, 0, stream>>>(yrw2, ain_w, ain_b,
                                                     stm5, sti5, rw2_g, rw2_be,
                                                     Qb, Kb, Vf);
    k_attn_mfma<<<dim3(GG / 64, 4, 2), 512, 0, stream>>>(Qb, Kb, Vf, mask, opA, opB, Lp);
    // fused tail
    k_tail<<<NG / 64, 256, 0, stream>>>(opA, opB, Lp, yrw2, aout_w, aout_b,
                                        stm5, sti5, rw2_g, rw2_be, ln1_g, ln1_b,
                                        W1b, ff1_b, W2b, ff2_b, ln2_g, ln2_b,
                                        indv_w, indv_b, ws + OF_HDC, vd2_w, vd2_b,
                                        x, outp);
}